// Round 10
// baseline (1971.358 us; speedup 1.0000x reference)
//
#include <hip/hip_runtime.h>

// ---------------------------------------------------------------------------
// LRA_GNN: random-walk -> 8-head GAT -> 12-layer residual GCN -> FC.
// Round 10: SORTED adjacency lists (per-node insertion sort in k_bucket).
// Concurrent waves then gather from a moving band of the feature table
// (order statistics of sorted neighbor lists), turning ~50% L2 hit into
// ~85% — attacks the 3.35 TB/s L2-miss-fill plateau seen in r8/r9.
// Aggregation/GEMM kernels unchanged from round 9.
// ---------------------------------------------------------------------------

typedef unsigned int u32;

#define BSH 7              // bucket shift: 128 nodes per bucket
#define RNGB 128           // nodes per bucket
#define GEB 256            // edge-pass blocks

__device__ __forceinline__ float lrelu(float v) { return v > 0.f ? v : 0.2f * v; }
__device__ __forceinline__ float bf_lo(u32 w) { return __uint_as_float(w << 16); }
__device__ __forceinline__ float bf_hi(u32 w) { return __uint_as_float(w & 0xffff0000u); }
__device__ __forceinline__ u32 pack_bf16(float a, float b) {
  u32 ua = __float_as_uint(a); ua = ua + 0x7fffu + ((ua >> 16) & 1u);
  u32 ub = __float_as_uint(b); ub = ub + 0x7fffu + ((ub >> 16) & 1u);
  return (ua >> 16) | (ub & 0xffff0000u);
}
__device__ __forceinline__ void acc8(float* acc, uint4 q) {
  acc[0] += bf_lo(q.x); acc[1] += bf_hi(q.x);
  acc[2] += bf_lo(q.y); acc[3] += bf_hi(q.y);
  acc[4] += bf_lo(q.z); acc[5] += bf_hi(q.z);
  acc[6] += bf_lo(q.w); acc[7] += bf_hi(q.w);
}
__device__ __forceinline__ void fma8(float* acc, float p, uint4 q) {
  acc[0] = fmaf(p, bf_lo(q.x), acc[0]); acc[1] = fmaf(p, bf_hi(q.x), acc[1]);
  acc[2] = fmaf(p, bf_lo(q.y), acc[2]); acc[3] = fmaf(p, bf_hi(q.y), acc[3]);
  acc[4] = fmaf(p, bf_lo(q.z), acc[4]); acc[5] = fmaf(p, bf_hi(q.z), acc[5]);
  acc[6] = fmaf(p, bf_lo(q.w), acc[6]); acc[7] = fmaf(p, bf_hi(q.w), acc[7]);
}

// --------------------- CSR build via bucketed counting sort ----------------

__global__ __launch_bounds__(256) void k_hist(
    const int* __restrict__ ei, int E, int NB, int chunk,
    int* __restrict__ gHistA, int* __restrict__ gHistB) {
  __shared__ int hA[1024], hB[1024];
  for (int i = threadIdx.x; i < NB; i += 256) { hA[i] = 0; hB[i] = 0; }
  __syncthreads();
  int e0 = blockIdx.x * chunk;
  int e1 = min(E, e0 + chunk);
  for (int e = e0 + threadIdx.x; e < e1; e += 256) {
    int s = ei[e], d = ei[E + e];
    atomicAdd(&hA[s >> BSH], 1);
    atomicAdd(&hB[d >> BSH], 1);
  }
  __syncthreads();
  for (int i = threadIdx.x; i < NB; i += 256) {
    gHistA[blockIdx.x * NB + i] = hA[i];
    gHistB[blockIdx.x * NB + i] = hB[i];
  }
}

__global__ __launch_bounds__(256) void k_colscan(
    int* __restrict__ gHist, int* __restrict__ tot, int NB) {
  __shared__ int s[GEB];
  int b = blockIdx.x;
  int t = threadIdx.x;
  int v = gHist[t * NB + b];
  s[t] = v;
  __syncthreads();
  for (int d = 1; d < GEB; d <<= 1) {
    int u = (t >= d) ? s[t - d] : 0;
    __syncthreads();
    s[t] += u;
    __syncthreads();
  }
  gHist[t * NB + b] = s[t] - v;
  if (t == GEB - 1) tot[b] = s[t];
}

__global__ __launch_bounds__(1024) void k_bscan(
    const int* __restrict__ totA, const int* __restrict__ totB,
    int* __restrict__ baseA, int* __restrict__ baseB,
    int* __restrict__ offA, int* __restrict__ offB, int NB, int N, int E) {
  __shared__ int sa[1024], sb[1024];
  int t = threadIdx.x;
  int va = (t < NB) ? totA[t] : 0;
  int vb = (t < NB) ? totB[t] : 0;
  sa[t] = va; sb[t] = vb;
  __syncthreads();
  for (int d = 1; d < 1024; d <<= 1) {
    int ua = (t >= d) ? sa[t - d] : 0;
    int ub = (t >= d) ? sb[t - d] : 0;
    __syncthreads();
    sa[t] += ua; sb[t] += ub;
    __syncthreads();
  }
  if (t < NB) { baseA[t] = sa[t] - va; baseB[t] = sb[t] - vb; }
  if (t == 0) { offA[N] = E; offB[N] = E; }
}

__global__ __launch_bounds__(256) void k_scatter(
    const int* __restrict__ ei, int E, int NB, int chunk,
    const int* __restrict__ gHistA, const int* __restrict__ gHistB,
    const int* __restrict__ baseA, const int* __restrict__ baseB,
    int2* __restrict__ pairsA, int2* __restrict__ pairsB) {
  __shared__ int cA[1024], cB[1024];
  int g = blockIdx.x;
  for (int i = threadIdx.x; i < NB; i += 256) {
    cA[i] = baseA[i] + gHistA[g * NB + i];
    cB[i] = baseB[i] + gHistB[g * NB + i];
  }
  __syncthreads();
  int e0 = g * chunk;
  int e1 = min(E, e0 + chunk);
  for (int e = e0 + threadIdx.x; e < e1; e += 256) {
    int s = ei[e], d = ei[E + e];
    int pa = atomicAdd(&cA[s >> BSH], 1);
    pairsA[pa] = {s, d};
    int pb = atomicAdd(&cB[d >> BSH], 1);
    pairsB[pb] = {s, d};
  }
}

template <int KEY>
__global__ __launch_bounds__(256) void k_bucket(
    const int2* __restrict__ pairs, const int* __restrict__ base,
    const int* __restrict__ tot, int* __restrict__ off,
    int* __restrict__ idx, float* __restrict__ dis, int N) {
  __shared__ int cnt[RNGB], pfx[RNGB];
  int b = blockIdx.x;
  int node0 = b << BSH;
  int rng = min(RNGB, N - node0);
  int bstart = base[b], bcount = tot[b];
  for (int i = threadIdx.x; i < rng; i += 256) cnt[i] = 0;
  __syncthreads();
  for (int i = threadIdx.x; i < bcount; i += 256) {
    int2 p = pairs[bstart + i];
    int loc = (KEY == 0 ? p.x : p.y) - node0;
    atomicAdd(&cnt[loc], 1);
  }
  __syncthreads();
  if (threadIdx.x == 0) {
    int run = 0;
    for (int i = 0; i < rng; ++i) { pfx[i] = run; run += cnt[i]; }
  }
  __syncthreads();
  for (int i = threadIdx.x; i < rng; i += 256) {
    off[node0 + i] = bstart + pfx[i];
    if (KEY == 1) dis[node0 + i] = rsqrtf((float)(cnt[i] + 1));
  }
  __syncthreads();
  for (int i = threadIdx.x; i < bcount; i += 256) {
    int2 p = pairs[bstart + i];
    int loc = (KEY == 0 ? p.x : p.y) - node0;
    int pos = bstart + atomicAdd(&pfx[loc], 1);
    idx[pos] = (KEY == 0 ? p.y : p.x);
  }
  __syncthreads();
  // Sort each node's neighbor list ascending (insertion sort; deg ~16).
  // Creates cross-wave temporal locality in the aggregation gathers.
  for (int i = threadIdx.x; i < rng; i += 256) {
    int b0 = off[node0 + i];
    int c = cnt[i];
    for (int a = 1; a < c; ++a) {
      int v = idx[b0 + a];
      int q = a - 1;
      while (q >= 0 && idx[b0 + q] > v) { idx[b0 + q + 1] = idx[b0 + q]; --q; }
      idx[b0 + q + 1] = v;
    }
  }
}

// --------------------------------- GEMMs -----------------------------------

__global__ __launch_bounds__(256) void k_gemm64(
    const float* __restrict__ X, const float* __restrict__ W,
    const float* __restrict__ dis, u32* __restrict__ Hb, int n) {
  __shared__ float Xs[64 * 65];
  int row0 = blockIdx.x * 64;
  for (int t = threadIdx.x; t < 1024; t += 256) {
    int r = t >> 4, k4 = t & 15;
    int row = row0 + r;
    float4 v = (row < n) ? ((const float4*)X)[(size_t)row * 16 + k4]
                         : float4{0.f, 0.f, 0.f, 0.f};
    float* dst = &Xs[r * 65 + k4 * 4];
    dst[0] = v.x; dst[1] = v.y; dst[2] = v.z; dst[3] = v.w;
  }
  __syncthreads();
  int lane = threadIdx.x & 63;
  int w = __builtin_amdgcn_readfirstlane(threadIdx.x >> 6);
  int c0 = w * 16;
  int row = row0 + lane;
  float acc[16];
#pragma unroll
  for (int c = 0; c < 16; ++c) acc[c] = 0.f;
#pragma unroll 4
  for (int k = 0; k < 64; ++k) {
    float xk = Xs[lane * 65 + k];
#pragma unroll
    for (int c = 0; c < 16; ++c)
      acc[c] = fmaf(xk, W[k * 64 + c0 + c], acc[c]);
  }
  if (row >= n) return;
  float sc = dis[row];
  uint4* H4 = (uint4*)Hb;
  uint4 o0 = {pack_bf16(acc[0] * sc, acc[1] * sc), pack_bf16(acc[2] * sc, acc[3] * sc),
              pack_bf16(acc[4] * sc, acc[5] * sc), pack_bf16(acc[6] * sc, acc[7] * sc)};
  uint4 o1 = {pack_bf16(acc[8] * sc, acc[9] * sc), pack_bf16(acc[10] * sc, acc[11] * sc),
              pack_bf16(acc[12] * sc, acc[13] * sc), pack_bf16(acc[14] * sc, acc[15] * sc)};
  H4[(size_t)row * 8 + w * 2] = o0;
  H4[(size_t)row * 8 + w * 2 + 1] = o1;
}

__global__ __launch_bounds__(256) void k_gat_gemm(
    const u32* __restrict__ Xb, const float* __restrict__ W,
    const float* __restrict__ asrc, const float* __restrict__ adst,
    u32* __restrict__ Hgb, float* __restrict__ al, int n) {
  __shared__ float Xs[64 * 65];
  int row0 = blockIdx.x * 64;
  for (int t = threadIdx.x; t < 512; t += 256) {
    int r = t >> 3, k8 = t & 7;
    int row = row0 + r;
    uint4 xw = (row < n) ? ((const uint4*)Xb)[(size_t)row * 8 + k8]
                         : uint4{0u, 0u, 0u, 0u};
    float* dst = &Xs[r * 65 + k8 * 8];
    dst[0] = bf_lo(xw.x); dst[1] = bf_hi(xw.x);
    dst[2] = bf_lo(xw.y); dst[3] = bf_hi(xw.y);
    dst[4] = bf_lo(xw.z); dst[5] = bf_hi(xw.z);
    dst[6] = bf_lo(xw.w); dst[7] = bf_hi(xw.w);
  }
  __syncthreads();
  int lane = threadIdx.x & 63;
  int w = __builtin_amdgcn_readfirstlane(threadIdx.x >> 6);
  int c0 = w * 16;
  int row = row0 + lane;
  float acc[16];
#pragma unroll
  for (int c = 0; c < 16; ++c) acc[c] = 0.f;
#pragma unroll 4
  for (int k = 0; k < 64; ++k) {
    float xk = Xs[lane * 65 + k];
#pragma unroll
    for (int c = 0; c < 16; ++c) {
      int gc = c0 + c;
      acc[c] = fmaf(xk, W[(gc >> 3) * 512 + k * 8 + (gc & 7)], acc[c]);
    }
  }
  if (row >= n) return;
  float s1a = 0.f, s2a = 0.f, s1b = 0.f, s2b = 0.f;
#pragma unroll
  for (int cc = 0; cc < 8; ++cc) {
    s1a = fmaf(acc[cc], asrc[c0 + cc], s1a);
    s2a = fmaf(acc[cc], adst[c0 + cc], s2a);
    s1b = fmaf(acc[8 + cc], asrc[c0 + 8 + cc], s1b);
    s2b = fmaf(acc[8 + cc], adst[c0 + 8 + cc], s2b);
  }
  float2* al2 = (float2*)al;
  al2[(size_t)row * 8 + w] = {s1a, s1b};
  al2[(size_t)row * 8 + 4 + w] = {s2a, s2b};
  uint4* H4 = (uint4*)Hgb;
  uint4 o0 = {pack_bf16(acc[0], acc[1]), pack_bf16(acc[2], acc[3]),
              pack_bf16(acc[4], acc[5]), pack_bf16(acc[6], acc[7])};
  uint4 o1 = {pack_bf16(acc[8], acc[9]), pack_bf16(acc[10], acc[11]),
              pack_bf16(acc[12], acc[13]), pack_bf16(acc[14], acc[15])};
  H4[(size_t)row * 8 + w * 2] = o0;
  H4[(size_t)row * 8 + w * 2 + 1] = o1;
}

// ------------------------------ aggregations -------------------------------

enum { MODE_RW1 = 0, MODE_RW = 1, MODE_G0 = 2, MODE_GR = 3, MODE_GD = 4 };

// Two destination nodes per wave (d0=even, d1=odd). lane = (rg 0..7, cg 0..7).
template <int MODE>
__global__ __launch_bounds__(256) void k_agg(
    const int* __restrict__ off, const int* __restrict__ idx,
    const float* __restrict__ Hf, const u32* __restrict__ Hb,
    const float* __restrict__ dis, const float* __restrict__ bias,
    float* __restrict__ R, float* __restrict__ Xf, u32* __restrict__ Xb,
    int n) {
  int lane = threadIdx.x & 63;
  int wid = threadIdx.x >> 6;
  int d0 = blockIdx.x * 8 + wid * 2;
  if (d0 >= n) return;
  int d1 = d0 + 1;
  bool has1 = d1 < n;
  int rg = lane >> 3, cg = lane & 7;
  const uint4* H4b = (const uint4*)Hb;
  const float4* H4f = (const float4*)Hf;
  int beg0 = off[d0], end0 = off[d0 + 1];
  int beg1 = has1 ? off[d1] : 0, end1 = has1 ? off[d1 + 1] : 0;
  int cnt0 = end0 - beg0, cnt1 = end1 - beg1;
  int cmax = cnt0 > cnt1 ? cnt0 : cnt1;
  float acc0[8], acc1[8];
#pragma unroll
  for (int i = 0; i < 8; ++i) { acc0[i] = 0.f; acc1[i] = 0.f; }
  for (int base = 0; base < cmax; base += 64) {
    int c0 = cnt0 - base; if (c0 > 64) c0 = 64;
    int c1 = cnt1 - base; if (c1 > 64) c1 = 64;
    int sidx0 = (lane < c0) ? idx[beg0 + base + lane] : -1;
    int sidx1 = (lane < c1) ? idx[beg1 + base + lane] : -1;
    int hi = c0 > c1 ? c0 : c1;
    int nI = (hi + 7) >> 3;
    int j = 0;
    for (; j + 2 <= nI; j += 2) {
      int s00 = __shfl(sidx0, j * 8 + rg, 64);
      int s01 = __shfl(sidx0, j * 8 + 8 + rg, 64);
      int s10 = __shfl(sidx1, j * 8 + rg, 64);
      int s11 = __shfl(sidx1, j * 8 + 8 + rg, 64);
      size_t a00 = (size_t)(s00 >= 0 ? s00 : 0);
      size_t a01 = (size_t)(s01 >= 0 ? s01 : 0);
      size_t a10 = (size_t)(s10 >= 0 ? s10 : 0);
      size_t a11 = (size_t)(s11 >= 0 ? s11 : 0);
      if (MODE == MODE_RW1) {
        float4 x00 = H4f[a00 * 16 + cg * 2], y00 = H4f[a00 * 16 + cg * 2 + 1];
        float4 x01 = H4f[a01 * 16 + cg * 2], y01 = H4f[a01 * 16 + cg * 2 + 1];
        float4 x10 = H4f[a10 * 16 + cg * 2], y10 = H4f[a10 * 16 + cg * 2 + 1];
        float4 x11 = H4f[a11 * 16 + cg * 2], y11 = H4f[a11 * 16 + cg * 2 + 1];
        if (s00 < 0) { x00 = {0,0,0,0}; y00 = {0,0,0,0}; }
        if (s01 < 0) { x01 = {0,0,0,0}; y01 = {0,0,0,0}; }
        if (s10 < 0) { x10 = {0,0,0,0}; y10 = {0,0,0,0}; }
        if (s11 < 0) { x11 = {0,0,0,0}; y11 = {0,0,0,0}; }
        acc0[0] += x00.x; acc0[1] += x00.y; acc0[2] += x00.z; acc0[3] += x00.w;
        acc0[4] += y00.x; acc0[5] += y00.y; acc0[6] += y00.z; acc0[7] += y00.w;
        acc0[0] += x01.x; acc0[1] += x01.y; acc0[2] += x01.z; acc0[3] += x01.w;
        acc0[4] += y01.x; acc0[5] += y01.y; acc0[6] += y01.z; acc0[7] += y01.w;
        acc1[0] += x10.x; acc1[1] += x10.y; acc1[2] += x10.z; acc1[3] += x10.w;
        acc1[4] += y10.x; acc1[5] += y10.y; acc1[6] += y10.z; acc1[7] += y10.w;
        acc1[0] += x11.x; acc1[1] += x11.y; acc1[2] += x11.z; acc1[3] += x11.w;
        acc1[4] += y11.x; acc1[5] += y11.y; acc1[6] += y11.z; acc1[7] += y11.w;
      } else {
        uint4 q00 = H4b[a00 * 8 + cg];
        uint4 q01 = H4b[a01 * 8 + cg];
        uint4 q10 = H4b[a10 * 8 + cg];
        uint4 q11 = H4b[a11 * 8 + cg];
        if (s00 < 0) q00 = {0u,0u,0u,0u};
        if (s01 < 0) q01 = {0u,0u,0u,0u};
        if (s10 < 0) q10 = {0u,0u,0u,0u};
        if (s11 < 0) q11 = {0u,0u,0u,0u};
        acc8(acc0, q00);
        acc8(acc0, q01);
        acc8(acc1, q10);
        acc8(acc1, q11);
      }
    }
    if (j < nI) {
      int s00 = __shfl(sidx0, j * 8 + rg, 64);
      int s10 = __shfl(sidx1, j * 8 + rg, 64);
      size_t a00 = (size_t)(s00 >= 0 ? s00 : 0);
      size_t a10 = (size_t)(s10 >= 0 ? s10 : 0);
      if (MODE == MODE_RW1) {
        float4 x00 = H4f[a00 * 16 + cg * 2], y00 = H4f[a00 * 16 + cg * 2 + 1];
        float4 x10 = H4f[a10 * 16 + cg * 2], y10 = H4f[a10 * 16 + cg * 2 + 1];
        if (s00 < 0) { x00 = {0,0,0,0}; y00 = {0,0,0,0}; }
        if (s10 < 0) { x10 = {0,0,0,0}; y10 = {0,0,0,0}; }
        acc0[0] += x00.x; acc0[1] += x00.y; acc0[2] += x00.z; acc0[3] += x00.w;
        acc0[4] += y00.x; acc0[5] += y00.y; acc0[6] += y00.z; acc0[7] += y00.w;
        acc1[0] += x10.x; acc1[1] += x10.y; acc1[2] += x10.z; acc1[3] += x10.w;
        acc1[4] += y10.x; acc1[5] += y10.y; acc1[6] += y10.z; acc1[7] += y10.w;
      } else {
        uint4 q00 = H4b[a00 * 8 + cg];
        uint4 q10 = H4b[a10 * 8 + cg];
        if (s00 < 0) q00 = {0u,0u,0u,0u};
        if (s10 < 0) q10 = {0u,0u,0u,0u};
        acc8(acc0, q00);
        acc8(acc1, q10);
      }
    }
  }
#pragma unroll
  for (int m = 8; m < 64; m <<= 1)
#pragma unroll
    for (int i = 0; i < 8; ++i) {
      acc0[i] += __shfl_xor(acc0[i], m, 64);
      acc1[i] += __shfl_xor(acc1[i], m, 64);
    }
  if (rg != 0) return;
#pragma unroll
  for (int nd = 0; nd < 2; ++nd) {
    int d = nd == 0 ? d0 : d1;
    if (nd == 1 && !has1) break;
    float* acc = nd == 0 ? acc0 : acc1;
    if (MODE == MODE_RW1 || MODE == MODE_RW) {
      uint4 o = {pack_bf16(acc[0], acc[1]), pack_bf16(acc[2], acc[3]),
                 pack_bf16(acc[4], acc[5]), pack_bf16(acc[6], acc[7])};
      ((uint4*)Xb)[(size_t)d * 8 + cg] = o;
      continue;
    }
    float ddv = dis[d];
    uint4 hw = H4b[(size_t)d * 8 + cg];
    float hs[8] = {bf_lo(hw.x), bf_hi(hw.x), bf_lo(hw.y), bf_hi(hw.y),
                   bf_lo(hw.z), bf_hi(hw.z), bf_lo(hw.w), bf_hi(hw.w)};
    float4 b0 = ((const float4*)bias)[cg * 2];
    float4 b1 = ((const float4*)bias)[cg * 2 + 1];
    float bv[8] = {b0.x, b0.y, b0.z, b0.w, b1.x, b1.y, b1.z, b1.w};
    float v[8];
#pragma unroll
    for (int i = 0; i < 8; ++i) v[i] = ddv * (acc[i] + hs[i]) + bv[i];
    float4* X4 = (float4*)Xf;
    size_t o0 = (size_t)d * 16 + cg * 2;
    if (MODE == MODE_GR) {
      float4* R4 = (float4*)R;
      float4 r0 = R4[o0], r1 = R4[o0 + 1];
      v[0] += r0.x; v[1] += r0.y; v[2] += r0.z; v[3] += r0.w;
      v[4] += r1.x; v[5] += r1.y; v[6] += r1.z; v[7] += r1.w;
      R4[o0] = {v[0], v[1], v[2], v[3]};
      R4[o0 + 1] = {v[4], v[5], v[6], v[7]};
      X4[o0] = {fmaxf(v[0], 0.f), fmaxf(v[1], 0.f), fmaxf(v[2], 0.f), fmaxf(v[3], 0.f)};
      X4[o0 + 1] = {fmaxf(v[4], 0.f), fmaxf(v[5], 0.f), fmaxf(v[6], 0.f), fmaxf(v[7], 0.f)};
    } else if (MODE == MODE_GD) {
      float4 x0 = X4[o0], x1 = X4[o0 + 1];
      X4[o0] = {x0.x + v[0], x0.y + v[1], x0.z + v[2], x0.w + v[3]};
      X4[o0 + 1] = {x1.x + v[4], x1.y + v[5], x1.z + v[6], x1.w + v[7]};
    } else {  // MODE_G0
      X4[o0] = {fmaxf(v[0], 0.f), fmaxf(v[1], 0.f), fmaxf(v[2], 0.f), fmaxf(v[3], 0.f)};
      X4[o0 + 1] = {fmaxf(v[4], 0.f), fmaxf(v[5], 0.f), fmaxf(v[6], 0.f), fmaxf(v[7], 0.f)};
    }
  }
}

// GAT softmax aggregation, two nodes per wave, both passes pipelined.
__global__ __launch_bounds__(256) void k_gat_agg(
    const int* __restrict__ off, const int* __restrict__ idx,
    const u32* __restrict__ Hgb, const float* __restrict__ al,
    const float* __restrict__ bias, float* __restrict__ X,
    float* __restrict__ R, int n) {
  int lane = threadIdx.x & 63;
  int wid = threadIdx.x >> 6;
  int d0 = blockIdx.x * 8 + wid * 2;
  if (d0 >= n) return;
  int d1 = d0 + 1;
  bool has1 = d1 < n;
  int rg = lane >> 3, cg = lane & 7;
  const uint4* H4b = (const uint4*)Hgb;
  float ald0 = al[(size_t)d0 * 16 + 8 + cg];
  float es0 = lrelu(al[(size_t)d0 * 16 + cg] + ald0);
  float ald1 = has1 ? al[(size_t)d1 * 16 + 8 + cg] : 0.f;
  float es1 = has1 ? lrelu(al[(size_t)d1 * 16 + cg] + ald1) : 0.f;
  int beg0 = off[d0], end0 = off[d0 + 1];
  int beg1 = has1 ? off[d1] : 0, end1 = has1 ? off[d1 + 1] : 0;
  int cnt0 = end0 - beg0, cnt1 = end1 - beg1;
  int cmax = cnt0 > cnt1 ? cnt0 : cnt1;
  float m0 = es0, m1 = es1;
  for (int base = 0; base < cmax; base += 64) {
    int c0 = cnt0 - base; if (c0 > 64) c0 = 64;
    int c1 = cnt1 - base; if (c1 > 64) c1 = 64;
    int sidx0 = (lane < c0) ? idx[beg0 + base + lane] : -1;
    int sidx1 = (lane < c1) ? idx[beg1 + base + lane] : -1;
    int hi = c0 > c1 ? c0 : c1;
    int nI = (hi + 7) >> 3;
    int j = 0;
    for (; j + 2 <= nI; j += 2) {
      int s00 = __shfl(sidx0, j * 8 + rg, 64);
      int s01 = __shfl(sidx0, j * 8 + 8 + rg, 64);
      int s10 = __shfl(sidx1, j * 8 + rg, 64);
      int s11 = __shfl(sidx1, j * 8 + 8 + rg, 64);
      float a00 = al[(size_t)(s00 >= 0 ? s00 : 0) * 16 + cg];
      float a01 = al[(size_t)(s01 >= 0 ? s01 : 0) * 16 + cg];
      float a10 = al[(size_t)(s10 >= 0 ? s10 : 0) * 16 + cg];
      float a11 = al[(size_t)(s11 >= 0 ? s11 : 0) * 16 + cg];
      if (s00 >= 0) m0 = fmaxf(m0, lrelu(a00 + ald0));
      if (s01 >= 0) m0 = fmaxf(m0, lrelu(a01 + ald0));
      if (s10 >= 0) m1 = fmaxf(m1, lrelu(a10 + ald1));
      if (s11 >= 0) m1 = fmaxf(m1, lrelu(a11 + ald1));
    }
    if (j < nI) {
      int s00 = __shfl(sidx0, j * 8 + rg, 64);
      int s10 = __shfl(sidx1, j * 8 + rg, 64);
      float a00 = al[(size_t)(s00 >= 0 ? s00 : 0) * 16 + cg];
      float a10 = al[(size_t)(s10 >= 0 ? s10 : 0) * 16 + cg];
      if (s00 >= 0) m0 = fmaxf(m0, lrelu(a00 + ald0));
      if (s10 >= 0) m1 = fmaxf(m1, lrelu(a10 + ald1));
    }
  }
#pragma unroll
  for (int mm = 8; mm < 64; mm <<= 1) {
    m0 = fmaxf(m0, __shfl_xor(m0, mm, 64));
    m1 = fmaxf(m1, __shfl_xor(m1, mm, 64));
  }
  float den0 = 0.f, den1 = 0.f;
  float acc0[8], acc1[8];
#pragma unroll
  for (int i = 0; i < 8; ++i) { acc0[i] = 0.f; acc1[i] = 0.f; }
  for (int base = 0; base < cmax; base += 64) {
    int c0 = cnt0 - base; if (c0 > 64) c0 = 64;
    int c1 = cnt1 - base; if (c1 > 64) c1 = 64;
    int sidx0 = (lane < c0) ? idx[beg0 + base + lane] : -1;
    int sidx1 = (lane < c1) ? idx[beg1 + base + lane] : -1;
    int hi = c0 > c1 ? c0 : c1;
    int nI = (hi + 7) >> 3;
    int j = 0;
    for (; j + 2 <= nI; j += 2) {
      int s00 = __shfl(sidx0, j * 8 + rg, 64);
      int s01 = __shfl(sidx0, j * 8 + 8 + rg, 64);
      int s10 = __shfl(sidx1, j * 8 + rg, 64);
      int s11 = __shfl(sidx1, j * 8 + 8 + rg, 64);
      size_t a00 = (size_t)(s00 >= 0 ? s00 : 0);
      size_t a01 = (size_t)(s01 >= 0 ? s01 : 0);
      size_t a10 = (size_t)(s10 >= 0 ? s10 : 0);
      size_t a11 = (size_t)(s11 >= 0 ? s11 : 0);
      float l00 = al[a00 * 16 + cg];
      float l01 = al[a01 * 16 + cg];
      float l10 = al[a10 * 16 + cg];
      float l11 = al[a11 * 16 + cg];
      uint4 q00 = H4b[a00 * 8 + cg];
      uint4 q01 = H4b[a01 * 8 + cg];
      uint4 q10 = H4b[a10 * 8 + cg];
      uint4 q11 = H4b[a11 * 8 + cg];
      float p00 = (s00 >= 0) ? __expf(lrelu(l00 + ald0) - m0) : 0.f;
      float p01 = (s01 >= 0) ? __expf(lrelu(l01 + ald0) - m0) : 0.f;
      float p10 = (s10 >= 0) ? __expf(lrelu(l10 + ald1) - m1) : 0.f;
      float p11 = (s11 >= 0) ? __expf(lrelu(l11 + ald1) - m1) : 0.f;
      den0 += p00; fma8(acc0, p00, q00);
      den0 += p01; fma8(acc0, p01, q01);
      den1 += p10; fma8(acc1, p10, q10);
      den1 += p11; fma8(acc1, p11, q11);
    }
    if (j < nI) {
      int s00 = __shfl(sidx0, j * 8 + rg, 64);
      int s10 = __shfl(sidx1, j * 8 + rg, 64);
      size_t a00 = (size_t)(s00 >= 0 ? s00 : 0);
      size_t a10 = (size_t)(s10 >= 0 ? s10 : 0);
      float l00 = al[a00 * 16 + cg];
      float l10 = al[a10 * 16 + cg];
      uint4 q00 = H4b[a00 * 8 + cg];
      uint4 q10 = H4b[a10 * 8 + cg];
      float p00 = (s00 >= 0) ? __expf(lrelu(l00 + ald0) - m0) : 0.f;
      float p10 = (s10 >= 0) ? __expf(lrelu(l10 + ald1) - m1) : 0.f;
      den0 += p00; fma8(acc0, p00, q00);
      den1 += p10; fma8(acc1, p10, q10);
    }
  }
#pragma unroll
  for (int mm = 8; mm < 64; mm <<= 1) {
#pragma unroll
    for (int i = 0; i < 8; ++i) {
      acc0[i] += __shfl_xor(acc0[i], mm, 64);
      acc1[i] += __shfl_xor(acc1[i], mm, 64);
    }
    den0 += __shfl_xor(den0, mm, 64);
    den1 += __shfl_xor(den1, mm, 64);
  }
  if (rg != 0) return;
#pragma unroll
  for (int nd = 0; nd < 2; ++nd) {
    if (nd == 1 && !has1) break;
    int d = nd == 0 ? d0 : d1;
    float* acc = nd == 0 ? acc0 : acc1;
    float es = nd == 0 ? es0 : es1;
    float m = nd == 0 ? m0 : m1;
    float den = nd == 0 ? den0 : den1;
    float pself = __expf(es - m);
    uint4 hw = H4b[(size_t)d * 8 + cg];
    float hs[8] = {bf_lo(hw.x), bf_hi(hw.x), bf_lo(hw.y), bf_hi(hw.y),
                   bf_lo(hw.z), bf_hi(hw.z), bf_lo(hw.w), bf_hi(hw.w)};
#pragma unroll
    for (int i = 0; i < 8; ++i) acc[i] = fmaf(pself, hs[i], acc[i]);
    den += pself;
    float inv = 1.f / den;
    float4 b0 = ((const float4*)bias)[cg * 2];
    float4 b1 = ((const float4*)bias)[cg * 2 + 1];
    float bv[8] = {b0.x, b0.y, b0.z, b0.w, b1.x, b1.y, b1.z, b1.w};
    float v[8];
#pragma unroll
    for (int i = 0; i < 8; ++i) v[i] = acc[i] * inv + bv[i];
    size_t o0 = (size_t)d * 16 + cg * 2;
    ((float4*)X)[o0] = {v[0], v[1], v[2], v[3]};
    ((float4*)X)[o0 + 1] = {v[4], v[5], v[6], v[7]};
    ((float4*)R)[o0] = {v[0], v[1], v[2], v[3]};
    ((float4*)R)[o0 + 1] = {v[4], v[5], v[6], v[7]};
  }
}

// ------------------------------- final linear ------------------------------

__global__ __launch_bounds__(256) void k_fc(
    const float* __restrict__ X, const float* __restrict__ W,
    const float* __restrict__ b, float* __restrict__ out, int n) {
  __shared__ float Wl[640];
  __shared__ float bl[10];
  for (int i = threadIdx.x; i < 640; i += 256) Wl[i] = W[i];
  if (threadIdx.x < 10) bl[threadIdx.x] = b[threadIdx.x];
  __syncthreads();
  int r = blockIdx.x * blockDim.x + threadIdx.x;
  if (r >= n) return;
  float acc[10];
#pragma unroll
  for (int c = 0; c < 10; ++c) acc[c] = bl[c];
#pragma unroll
  for (int k = 0; k < 64; ++k) {
    float xv = X[(size_t)r * 64 + k];
#pragma unroll
    for (int c = 0; c < 10; ++c) acc[c] = fmaf(xv, Wl[k * 10 + c], acc[c]);
  }
#pragma unroll
  for (int c = 0; c < 10; ++c) out[(size_t)r * 10 + c] = acc[c];
}

// --------------------------------- launch ----------------------------------

extern "C" void kernel_launch(void* const* d_in, const int* in_sizes, int n_in,
                              void* d_out, int out_size, void* d_ws, size_t ws_size,
                              hipStream_t stream) {
  const float* x_in  = (const float*)d_in[0];
  const int*   ei    = (const int*)d_in[1];
  const float* gatW  = (const float*)d_in[2];
  const float* gatAs = (const float*)d_in[3];
  const float* gatAd = (const float*)d_in[4];
  const float* gatB  = (const float*)d_in[5];
  const float* gcnW  = (const float*)d_in[6];
  const float* gcnB  = (const float*)d_in[7];
  const float* fcW   = (const float*)d_in[8];
  const float* fcB   = (const float*)d_in[9];
  float* out = (float*)d_out;

  const int N = in_sizes[0] / 64;
  const int E = in_sizes[1] / 2;
  const int NB = (N + RNGB - 1) >> BSH;
  const int chunk = (E + GEB - 1) / GEB;

  char* ws = (char*)d_ws;
  size_t o = 0;
  auto alloc = [&](size_t bytes) -> char* {
    char* p = ws + o;
    o = (o + bytes + 255) & ~(size_t)255;
    return p;
  };
  int* offA    = (int*)alloc((size_t)(N + 1) * 4);
  int* offB    = (int*)alloc((size_t)(N + 1) * 4);
  float* dis   = (float*)alloc((size_t)N * 4);
  int* idxA    = (int*)alloc((size_t)E * 4);
  int* idxB    = (int*)alloc((size_t)E * 4);
  int2* pairsA = (int2*)alloc((size_t)E * 8);
  int2* pairsB = (int2*)alloc((size_t)E * 8);
  int* gHistA  = (int*)alloc((size_t)GEB * NB * 4);
  int* gHistB  = (int*)alloc((size_t)GEB * NB * 4);
  int* totA    = (int*)alloc((size_t)NB * 4);
  int* totB    = (int*)alloc((size_t)NB * 4);
  int* baseA   = (int*)alloc((size_t)NB * 4);
  int* baseB   = (int*)alloc((size_t)NB * 4);
  float* al    = (float*)alloc((size_t)N * 16 * 4);
  u32* B0      = (u32*)alloc((size_t)N * 32 * 4);
  u32* B1      = (u32*)alloc((size_t)N * 32 * 4);
  float* X     = (float*)alloc((size_t)N * 64 * 4);
  float* R     = (float*)alloc((size_t)N * 64 * 4);

  int nbN = (N + 255) / 256;
  int nbAgg = (N + 7) / 8;
  int nbG = (N + 63) / 64;

  // ---- CSR build: bucketed counting sort (+ per-node neighbor sort) ----
  k_hist<<<GEB, 256, 0, stream>>>(ei, E, NB, chunk, gHistA, gHistB);
  k_colscan<<<NB, GEB, 0, stream>>>(gHistA, totA, NB);
  k_colscan<<<NB, GEB, 0, stream>>>(gHistB, totB, NB);
  k_bscan<<<1, 1024, 0, stream>>>(totA, totB, baseA, baseB, offA, offB, NB, N, E);
  k_scatter<<<GEB, 256, 0, stream>>>(ei, E, NB, chunk, gHistA, gHistB,
                                     baseA, baseB, pairsA, pairsB);
  k_bucket<0><<<NB, 256, 0, stream>>>(pairsA, baseA, totA, offA, idxA, nullptr, N);
  k_bucket<1><<<NB, 256, 0, stream>>>(pairsB, baseB, totB, offB, idxB, dis, N);

  // ---- random walk: 5 steps (fp32 in -> bf16 ping-pong) ----
  k_agg<MODE_RW1><<<nbAgg, 256, 0, stream>>>(offA, idxA, x_in, nullptr, nullptr, nullptr, nullptr, nullptr, B0, N);
  k_agg<MODE_RW><<<nbAgg, 256, 0, stream>>>(offA, idxA, nullptr, B0, nullptr, nullptr, nullptr, nullptr, B1, N);
  k_agg<MODE_RW><<<nbAgg, 256, 0, stream>>>(offA, idxA, nullptr, B1, nullptr, nullptr, nullptr, nullptr, B0, N);
  k_agg<MODE_RW><<<nbAgg, 256, 0, stream>>>(offA, idxA, nullptr, B0, nullptr, nullptr, nullptr, nullptr, B1, N);
  k_agg<MODE_RW><<<nbAgg, 256, 0, stream>>>(offA, idxA, nullptr, B1, nullptr, nullptr, nullptr, nullptr, B0, N);

  // ---- GAT ----
  k_gat_gemm<<<nbG, 256, 0, stream>>>(B0, gatW, gatAs, gatAd, B1, al, N);
  k_gat_agg<<<nbAgg, 256, 0, stream>>>(offB, idxB, B1, al, gatB, X, R, N);

  // ---- residual GCN ----
  for (int i = 0; i < 12; ++i) {
    k_gemm64<<<nbG, 256, 0, stream>>>(X, gcnW + i * 4096, dis, B0, N);
    if (i == 0)
      k_agg<MODE_G0><<<nbAgg, 256, 0, stream>>>(offB, idxB, nullptr, B0, dis, gcnB + i * 64, nullptr, X, nullptr, N);
    else
      k_agg<MODE_GR><<<nbAgg, 256, 0, stream>>>(offB, idxB, nullptr, B0, dis, gcnB + i * 64, R, X, nullptr, N);
    if (i < 11) {
      int j = (i == 0) ? 11 : i - 1;
      k_gemm64<<<nbG, 256, 0, stream>>>(X, gcnW + j * 4096, dis, B0, N);
      k_agg<MODE_GD><<<nbAgg, 256, 0, stream>>>(offB, idxB, nullptr, B0, dis, gcnB + j * 64, nullptr, X, nullptr, N);
    }
  }

  // ---- final linear ----
  k_fc<<<nbN, 256, 0, stream>>>(X, fcW, fcB, out, N);
}

// Round 11
// 1895.182 us; speedup vs baseline: 1.0402x; 1.0402x over previous
//
#include <hip/hip_runtime.h>

// ---------------------------------------------------------------------------
// LRA_GNN: random-walk -> 8-head GAT -> 12-layer residual GCN -> FC.
// Round 11: (a) revert r10's neighbor sort (cost 230us, gained 0).
// (b) FUSED GCN conv: A_norm(XW) == (A_norm X)W, so each conv is ONE kernel:
//     gather bf16 table T=bf16(dis*x), reduce, in-kernel 64x64 W-multiply
//     (z via per-wave LDS, lane=output channel), fused bias/residual/relu,
//     direct T_next emission. Removes all 23 standalone GEMMs; the W-multiply
//     hides under gather latency (aggs had 40% VALU slack).
// ---------------------------------------------------------------------------

typedef unsigned int u32;

#define BSH 7              // bucket shift: 128 nodes per bucket
#define RNGB 128           // nodes per bucket
#define GEB 256            // edge-pass blocks

__device__ __forceinline__ float lrelu(float v) { return v > 0.f ? v : 0.2f * v; }
__device__ __forceinline__ float bf_lo(u32 w) { return __uint_as_float(w << 16); }
__device__ __forceinline__ float bf_hi(u32 w) { return __uint_as_float(w & 0xffff0000u); }
__device__ __forceinline__ u32 pack_bf16(float a, float b) {
  u32 ua = __float_as_uint(a); ua = ua + 0x7fffu + ((ua >> 16) & 1u);
  u32 ub = __float_as_uint(b); ub = ub + 0x7fffu + ((ub >> 16) & 1u);
  return (ua >> 16) | (ub & 0xffff0000u);
}
__device__ __forceinline__ void acc8(float* acc, uint4 q) {
  acc[0] += bf_lo(q.x); acc[1] += bf_hi(q.x);
  acc[2] += bf_lo(q.y); acc[3] += bf_hi(q.y);
  acc[4] += bf_lo(q.z); acc[5] += bf_hi(q.z);
  acc[6] += bf_lo(q.w); acc[7] += bf_hi(q.w);
}
__device__ __forceinline__ void fma8(float* acc, float p, uint4 q) {
  acc[0] = fmaf(p, bf_lo(q.x), acc[0]); acc[1] = fmaf(p, bf_hi(q.x), acc[1]);
  acc[2] = fmaf(p, bf_lo(q.y), acc[2]); acc[3] = fmaf(p, bf_hi(q.y), acc[3]);
  acc[4] = fmaf(p, bf_lo(q.z), acc[4]); acc[5] = fmaf(p, bf_hi(q.z), acc[5]);
  acc[6] = fmaf(p, bf_lo(q.w), acc[6]); acc[7] = fmaf(p, bf_hi(q.w), acc[7]);
}

// --------------------- CSR build via bucketed counting sort ----------------

__global__ __launch_bounds__(256) void k_hist(
    const int* __restrict__ ei, int E, int NB, int chunk,
    int* __restrict__ gHistA, int* __restrict__ gHistB) {
  __shared__ int hA[1024], hB[1024];
  for (int i = threadIdx.x; i < NB; i += 256) { hA[i] = 0; hB[i] = 0; }
  __syncthreads();
  int e0 = blockIdx.x * chunk;
  int e1 = min(E, e0 + chunk);
  for (int e = e0 + threadIdx.x; e < e1; e += 256) {
    int s = ei[e], d = ei[E + e];
    atomicAdd(&hA[s >> BSH], 1);
    atomicAdd(&hB[d >> BSH], 1);
  }
  __syncthreads();
  for (int i = threadIdx.x; i < NB; i += 256) {
    gHistA[blockIdx.x * NB + i] = hA[i];
    gHistB[blockIdx.x * NB + i] = hB[i];
  }
}

__global__ __launch_bounds__(256) void k_colscan(
    int* __restrict__ gHist, int* __restrict__ tot, int NB) {
  __shared__ int s[GEB];
  int b = blockIdx.x;
  int t = threadIdx.x;
  int v = gHist[t * NB + b];
  s[t] = v;
  __syncthreads();
  for (int d = 1; d < GEB; d <<= 1) {
    int u = (t >= d) ? s[t - d] : 0;
    __syncthreads();
    s[t] += u;
    __syncthreads();
  }
  gHist[t * NB + b] = s[t] - v;
  if (t == GEB - 1) tot[b] = s[t];
}

__global__ __launch_bounds__(1024) void k_bscan(
    const int* __restrict__ totA, const int* __restrict__ totB,
    int* __restrict__ baseA, int* __restrict__ baseB,
    int* __restrict__ offA, int* __restrict__ offB, int NB, int N, int E) {
  __shared__ int sa[1024], sb[1024];
  int t = threadIdx.x;
  int va = (t < NB) ? totA[t] : 0;
  int vb = (t < NB) ? totB[t] : 0;
  sa[t] = va; sb[t] = vb;
  __syncthreads();
  for (int d = 1; d < 1024; d <<= 1) {
    int ua = (t >= d) ? sa[t - d] : 0;
    int ub = (t >= d) ? sb[t - d] : 0;
    __syncthreads();
    sa[t] += ua; sb[t] += ub;
    __syncthreads();
  }
  if (t < NB) { baseA[t] = sa[t] - va; baseB[t] = sb[t] - vb; }
  if (t == 0) { offA[N] = E; offB[N] = E; }
}

__global__ __launch_bounds__(256) void k_scatter(
    const int* __restrict__ ei, int E, int NB, int chunk,
    const int* __restrict__ gHistA, const int* __restrict__ gHistB,
    const int* __restrict__ baseA, const int* __restrict__ baseB,
    int2* __restrict__ pairsA, int2* __restrict__ pairsB) {
  __shared__ int cA[1024], cB[1024];
  int g = blockIdx.x;
  for (int i = threadIdx.x; i < NB; i += 256) {
    cA[i] = baseA[i] + gHistA[g * NB + i];
    cB[i] = baseB[i] + gHistB[g * NB + i];
  }
  __syncthreads();
  int e0 = g * chunk;
  int e1 = min(E, e0 + chunk);
  for (int e = e0 + threadIdx.x; e < e1; e += 256) {
    int s = ei[e], d = ei[E + e];
    int pa = atomicAdd(&cA[s >> BSH], 1);
    pairsA[pa] = {s, d};
    int pb = atomicAdd(&cB[d >> BSH], 1);
    pairsB[pb] = {s, d};
  }
}

template <int KEY>
__global__ __launch_bounds__(256) void k_bucket(
    const int2* __restrict__ pairs, const int* __restrict__ base,
    const int* __restrict__ tot, int* __restrict__ off,
    int* __restrict__ idx, float* __restrict__ dis, int N) {
  __shared__ int cnt[RNGB], pfx[RNGB];
  int b = blockIdx.x;
  int node0 = b << BSH;
  int rng = min(RNGB, N - node0);
  int bstart = base[b], bcount = tot[b];
  for (int i = threadIdx.x; i < rng; i += 256) cnt[i] = 0;
  __syncthreads();
  for (int i = threadIdx.x; i < bcount; i += 256) {
    int2 p = pairs[bstart + i];
    int loc = (KEY == 0 ? p.x : p.y) - node0;
    atomicAdd(&cnt[loc], 1);
  }
  __syncthreads();
  if (threadIdx.x == 0) {
    int run = 0;
    for (int i = 0; i < rng; ++i) { pfx[i] = run; run += cnt[i]; }
  }
  __syncthreads();
  for (int i = threadIdx.x; i < rng; i += 256) {
    off[node0 + i] = bstart + pfx[i];
    if (KEY == 1) dis[node0 + i] = rsqrtf((float)(cnt[i] + 1));
  }
  __syncthreads();
  for (int i = threadIdx.x; i < bcount; i += 256) {
    int2 p = pairs[bstart + i];
    int loc = (KEY == 0 ? p.x : p.y) - node0;
    int pos = bstart + atomicAdd(&pfx[loc], 1);
    idx[pos] = (KEY == 0 ? p.y : p.x);
  }
}

// ------------------------- random-walk aggregation -------------------------

// Two destination nodes per wave. FIRST: gather fp32 x_in; else bf16 table.
template <int FIRST>
__global__ __launch_bounds__(256) void k_rw(
    const int* __restrict__ off, const int* __restrict__ idx,
    const float* __restrict__ Hf, const u32* __restrict__ Hb,
    u32* __restrict__ Xb, int n) {
  int lane = threadIdx.x & 63;
  int wid = threadIdx.x >> 6;
  int d0 = blockIdx.x * 8 + wid * 2;
  if (d0 >= n) return;
  int d1 = d0 + 1;
  bool has1 = d1 < n;
  int rg = lane >> 3, cg = lane & 7;
  const uint4* H4b = (const uint4*)Hb;
  const float4* H4f = (const float4*)Hf;
  int beg0 = off[d0], end0 = off[d0 + 1];
  int beg1 = has1 ? off[d1] : 0, end1 = has1 ? off[d1 + 1] : 0;
  int cnt0 = end0 - beg0, cnt1 = end1 - beg1;
  int cmax = cnt0 > cnt1 ? cnt0 : cnt1;
  float acc0[8], acc1[8];
#pragma unroll
  for (int i = 0; i < 8; ++i) { acc0[i] = 0.f; acc1[i] = 0.f; }
  for (int base = 0; base < cmax; base += 64) {
    int c0 = cnt0 - base; if (c0 > 64) c0 = 64;
    int c1 = cnt1 - base; if (c1 > 64) c1 = 64;
    int sidx0 = (lane < c0) ? idx[beg0 + base + lane] : -1;
    int sidx1 = (lane < c1) ? idx[beg1 + base + lane] : -1;
    int hi = c0 > c1 ? c0 : c1;
    int nI = (hi + 7) >> 3;
    int j = 0;
    for (; j + 2 <= nI; j += 2) {
      int s00 = __shfl(sidx0, j * 8 + rg, 64);
      int s01 = __shfl(sidx0, j * 8 + 8 + rg, 64);
      int s10 = __shfl(sidx1, j * 8 + rg, 64);
      int s11 = __shfl(sidx1, j * 8 + 8 + rg, 64);
      size_t a00 = (size_t)(s00 >= 0 ? s00 : 0);
      size_t a01 = (size_t)(s01 >= 0 ? s01 : 0);
      size_t a10 = (size_t)(s10 >= 0 ? s10 : 0);
      size_t a11 = (size_t)(s11 >= 0 ? s11 : 0);
      if (FIRST) {
        float4 x00 = H4f[a00 * 16 + cg * 2], y00 = H4f[a00 * 16 + cg * 2 + 1];
        float4 x01 = H4f[a01 * 16 + cg * 2], y01 = H4f[a01 * 16 + cg * 2 + 1];
        float4 x10 = H4f[a10 * 16 + cg * 2], y10 = H4f[a10 * 16 + cg * 2 + 1];
        float4 x11 = H4f[a11 * 16 + cg * 2], y11 = H4f[a11 * 16 + cg * 2 + 1];
        if (s00 < 0) { x00 = {0,0,0,0}; y00 = {0,0,0,0}; }
        if (s01 < 0) { x01 = {0,0,0,0}; y01 = {0,0,0,0}; }
        if (s10 < 0) { x10 = {0,0,0,0}; y10 = {0,0,0,0}; }
        if (s11 < 0) { x11 = {0,0,0,0}; y11 = {0,0,0,0}; }
        acc0[0] += x00.x; acc0[1] += x00.y; acc0[2] += x00.z; acc0[3] += x00.w;
        acc0[4] += y00.x; acc0[5] += y00.y; acc0[6] += y00.z; acc0[7] += y00.w;
        acc0[0] += x01.x; acc0[1] += x01.y; acc0[2] += x01.z; acc0[3] += x01.w;
        acc0[4] += y01.x; acc0[5] += y01.y; acc0[6] += y01.z; acc0[7] += y01.w;
        acc1[0] += x10.x; acc1[1] += x10.y; acc1[2] += x10.z; acc1[3] += x10.w;
        acc1[4] += y10.x; acc1[5] += y10.y; acc1[6] += y10.z; acc1[7] += y10.w;
        acc1[0] += x11.x; acc1[1] += x11.y; acc1[2] += x11.z; acc1[3] += x11.w;
        acc1[4] += y11.x; acc1[5] += y11.y; acc1[6] += y11.z; acc1[7] += y11.w;
      } else {
        uint4 q00 = H4b[a00 * 8 + cg];
        uint4 q01 = H4b[a01 * 8 + cg];
        uint4 q10 = H4b[a10 * 8 + cg];
        uint4 q11 = H4b[a11 * 8 + cg];
        if (s00 < 0) q00 = {0u,0u,0u,0u};
        if (s01 < 0) q01 = {0u,0u,0u,0u};
        if (s10 < 0) q10 = {0u,0u,0u,0u};
        if (s11 < 0) q11 = {0u,0u,0u,0u};
        acc8(acc0, q00);
        acc8(acc0, q01);
        acc8(acc1, q10);
        acc8(acc1, q11);
      }
    }
    if (j < nI) {
      int s00 = __shfl(sidx0, j * 8 + rg, 64);
      int s10 = __shfl(sidx1, j * 8 + rg, 64);
      size_t a00 = (size_t)(s00 >= 0 ? s00 : 0);
      size_t a10 = (size_t)(s10 >= 0 ? s10 : 0);
      if (FIRST) {
        float4 x00 = H4f[a00 * 16 + cg * 2], y00 = H4f[a00 * 16 + cg * 2 + 1];
        float4 x10 = H4f[a10 * 16 + cg * 2], y10 = H4f[a10 * 16 + cg * 2 + 1];
        if (s00 < 0) { x00 = {0,0,0,0}; y00 = {0,0,0,0}; }
        if (s10 < 0) { x10 = {0,0,0,0}; y10 = {0,0,0,0}; }
        acc0[0] += x00.x; acc0[1] += x00.y; acc0[2] += x00.z; acc0[3] += x00.w;
        acc0[4] += y00.x; acc0[5] += y00.y; acc0[6] += y00.z; acc0[7] += y00.w;
        acc1[0] += x10.x; acc1[1] += x10.y; acc1[2] += x10.z; acc1[3] += x10.w;
        acc1[4] += y10.x; acc1[5] += y10.y; acc1[6] += y10.z; acc1[7] += y10.w;
      } else {
        uint4 q00 = H4b[a00 * 8 + cg];
        uint4 q10 = H4b[a10 * 8 + cg];
        if (s00 < 0) q00 = {0u,0u,0u,0u};
        if (s10 < 0) q10 = {0u,0u,0u,0u};
        acc8(acc0, q00);
        acc8(acc1, q10);
      }
    }
  }
#pragma unroll
  for (int m = 8; m < 64; m <<= 1)
#pragma unroll
    for (int i = 0; i < 8; ++i) {
      acc0[i] += __shfl_xor(acc0[i], m, 64);
      acc1[i] += __shfl_xor(acc1[i], m, 64);
    }
  if (rg != 0) return;
  uint4 o0 = {pack_bf16(acc0[0], acc0[1]), pack_bf16(acc0[2], acc0[3]),
              pack_bf16(acc0[4], acc0[5]), pack_bf16(acc0[6], acc0[7])};
  ((uint4*)Xb)[(size_t)d0 * 8 + cg] = o0;
  if (has1) {
    uint4 o1 = {pack_bf16(acc1[0], acc1[1]), pack_bf16(acc1[2], acc1[3]),
                pack_bf16(acc1[4], acc1[5]), pack_bf16(acc1[6], acc1[7])};
    ((uint4*)Xb)[(size_t)d1 * 8 + cg] = o1;
  }
}

// ------------------------------- GAT kernels -------------------------------

__global__ __launch_bounds__(256) void k_gat_gemm(
    const u32* __restrict__ Xb, const float* __restrict__ W,
    const float* __restrict__ asrc, const float* __restrict__ adst,
    u32* __restrict__ Hgb, float* __restrict__ al, int n) {
  __shared__ float Xs[64 * 65];
  int row0 = blockIdx.x * 64;
  for (int t = threadIdx.x; t < 512; t += 256) {
    int r = t >> 3, k8 = t & 7;
    int row = row0 + r;
    uint4 xw = (row < n) ? ((const uint4*)Xb)[(size_t)row * 8 + k8]
                         : uint4{0u, 0u, 0u, 0u};
    float* dst = &Xs[r * 65 + k8 * 8];
    dst[0] = bf_lo(xw.x); dst[1] = bf_hi(xw.x);
    dst[2] = bf_lo(xw.y); dst[3] = bf_hi(xw.y);
    dst[4] = bf_lo(xw.z); dst[5] = bf_hi(xw.z);
    dst[6] = bf_lo(xw.w); dst[7] = bf_hi(xw.w);
  }
  __syncthreads();
  int lane = threadIdx.x & 63;
  int w = __builtin_amdgcn_readfirstlane(threadIdx.x >> 6);
  int c0 = w * 16;
  int row = row0 + lane;
  float acc[16];
#pragma unroll
  for (int c = 0; c < 16; ++c) acc[c] = 0.f;
#pragma unroll 4
  for (int k = 0; k < 64; ++k) {
    float xk = Xs[lane * 65 + k];
#pragma unroll
    for (int c = 0; c < 16; ++c) {
      int gc = c0 + c;
      acc[c] = fmaf(xk, W[(gc >> 3) * 512 + k * 8 + (gc & 7)], acc[c]);
    }
  }
  if (row >= n) return;
  float s1a = 0.f, s2a = 0.f, s1b = 0.f, s2b = 0.f;
#pragma unroll
  for (int cc = 0; cc < 8; ++cc) {
    s1a = fmaf(acc[cc], asrc[c0 + cc], s1a);
    s2a = fmaf(acc[cc], adst[c0 + cc], s2a);
    s1b = fmaf(acc[8 + cc], asrc[c0 + 8 + cc], s1b);
    s2b = fmaf(acc[8 + cc], adst[c0 + 8 + cc], s2b);
  }
  float2* al2 = (float2*)al;
  al2[(size_t)row * 8 + w] = {s1a, s1b};
  al2[(size_t)row * 8 + 4 + w] = {s2a, s2b};
  uint4* H4 = (uint4*)Hgb;
  uint4 o0 = {pack_bf16(acc[0], acc[1]), pack_bf16(acc[2], acc[3]),
              pack_bf16(acc[4], acc[5]), pack_bf16(acc[6], acc[7])};
  uint4 o1 = {pack_bf16(acc[8], acc[9]), pack_bf16(acc[10], acc[11]),
              pack_bf16(acc[12], acc[13]), pack_bf16(acc[14], acc[15])};
  H4[(size_t)row * 8 + w * 2] = o0;
  H4[(size_t)row * 8 + w * 2 + 1] = o1;
}

// GAT softmax aggregation, two nodes per wave; writes R (fp32) and the first
// GCN table T0 = bf16(dis * x_gat).
__global__ __launch_bounds__(256) void k_gat_agg(
    const int* __restrict__ off, const int* __restrict__ idx,
    const u32* __restrict__ Hgb, const float* __restrict__ al,
    const float* __restrict__ bias, const float* __restrict__ dis,
    u32* __restrict__ Tout, float* __restrict__ R, int n) {
  int lane = threadIdx.x & 63;
  int wid = threadIdx.x >> 6;
  int d0 = blockIdx.x * 8 + wid * 2;
  if (d0 >= n) return;
  int d1 = d0 + 1;
  bool has1 = d1 < n;
  int rg = lane >> 3, cg = lane & 7;
  const uint4* H4b = (const uint4*)Hgb;
  float ald0 = al[(size_t)d0 * 16 + 8 + cg];
  float es0 = lrelu(al[(size_t)d0 * 16 + cg] + ald0);
  float ald1 = has1 ? al[(size_t)d1 * 16 + 8 + cg] : 0.f;
  float es1 = has1 ? lrelu(al[(size_t)d1 * 16 + cg] + ald1) : 0.f;
  int beg0 = off[d0], end0 = off[d0 + 1];
  int beg1 = has1 ? off[d1] : 0, end1 = has1 ? off[d1 + 1] : 0;
  int cnt0 = end0 - beg0, cnt1 = end1 - beg1;
  int cmax = cnt0 > cnt1 ? cnt0 : cnt1;
  float m0 = es0, m1 = es1;
  for (int base = 0; base < cmax; base += 64) {
    int c0 = cnt0 - base; if (c0 > 64) c0 = 64;
    int c1 = cnt1 - base; if (c1 > 64) c1 = 64;
    int sidx0 = (lane < c0) ? idx[beg0 + base + lane] : -1;
    int sidx1 = (lane < c1) ? idx[beg1 + base + lane] : -1;
    int hi = c0 > c1 ? c0 : c1;
    int nI = (hi + 7) >> 3;
    int j = 0;
    for (; j + 2 <= nI; j += 2) {
      int s00 = __shfl(sidx0, j * 8 + rg, 64);
      int s01 = __shfl(sidx0, j * 8 + 8 + rg, 64);
      int s10 = __shfl(sidx1, j * 8 + rg, 64);
      int s11 = __shfl(sidx1, j * 8 + 8 + rg, 64);
      float a00 = al[(size_t)(s00 >= 0 ? s00 : 0) * 16 + cg];
      float a01 = al[(size_t)(s01 >= 0 ? s01 : 0) * 16 + cg];
      float a10 = al[(size_t)(s10 >= 0 ? s10 : 0) * 16 + cg];
      float a11 = al[(size_t)(s11 >= 0 ? s11 : 0) * 16 + cg];
      if (s00 >= 0) m0 = fmaxf(m0, lrelu(a00 + ald0));
      if (s01 >= 0) m0 = fmaxf(m0, lrelu(a01 + ald0));
      if (s10 >= 0) m1 = fmaxf(m1, lrelu(a10 + ald1));
      if (s11 >= 0) m1 = fmaxf(m1, lrelu(a11 + ald1));
    }
    if (j < nI) {
      int s00 = __shfl(sidx0, j * 8 + rg, 64);
      int s10 = __shfl(sidx1, j * 8 + rg, 64);
      float a00 = al[(size_t)(s00 >= 0 ? s00 : 0) * 16 + cg];
      float a10 = al[(size_t)(s10 >= 0 ? s10 : 0) * 16 + cg];
      if (s00 >= 0) m0 = fmaxf(m0, lrelu(a00 + ald0));
      if (s10 >= 0) m1 = fmaxf(m1, lrelu(a10 + ald1));
    }
  }
#pragma unroll
  for (int mm = 8; mm < 64; mm <<= 1) {
    m0 = fmaxf(m0, __shfl_xor(m0, mm, 64));
    m1 = fmaxf(m1, __shfl_xor(m1, mm, 64));
  }
  float den0 = 0.f, den1 = 0.f;
  float acc0[8], acc1[8];
#pragma unroll
  for (int i = 0; i < 8; ++i) { acc0[i] = 0.f; acc1[i] = 0.f; }
  for (int base = 0; base < cmax; base += 64) {
    int c0 = cnt0 - base; if (c0 > 64) c0 = 64;
    int c1 = cnt1 - base; if (c1 > 64) c1 = 64;
    int sidx0 = (lane < c0) ? idx[beg0 + base + lane] : -1;
    int sidx1 = (lane < c1) ? idx[beg1 + base + lane] : -1;
    int hi = c0 > c1 ? c0 : c1;
    int nI = (hi + 7) >> 3;
    int j = 0;
    for (; j + 2 <= nI; j += 2) {
      int s00 = __shfl(sidx0, j * 8 + rg, 64);
      int s01 = __shfl(sidx0, j * 8 + 8 + rg, 64);
      int s10 = __shfl(sidx1, j * 8 + rg, 64);
      int s11 = __shfl(sidx1, j * 8 + 8 + rg, 64);
      size_t a00 = (size_t)(s00 >= 0 ? s00 : 0);
      size_t a01 = (size_t)(s01 >= 0 ? s01 : 0);
      size_t a10 = (size_t)(s10 >= 0 ? s10 : 0);
      size_t a11 = (size_t)(s11 >= 0 ? s11 : 0);
      float l00 = al[a00 * 16 + cg];
      float l01 = al[a01 * 16 + cg];
      float l10 = al[a10 * 16 + cg];
      float l11 = al[a11 * 16 + cg];
      uint4 q00 = H4b[a00 * 8 + cg];
      uint4 q01 = H4b[a01 * 8 + cg];
      uint4 q10 = H4b[a10 * 8 + cg];
      uint4 q11 = H4b[a11 * 8 + cg];
      float p00 = (s00 >= 0) ? __expf(lrelu(l00 + ald0) - m0) : 0.f;
      float p01 = (s01 >= 0) ? __expf(lrelu(l01 + ald0) - m0) : 0.f;
      float p10 = (s10 >= 0) ? __expf(lrelu(l10 + ald1) - m1) : 0.f;
      float p11 = (s11 >= 0) ? __expf(lrelu(l11 + ald1) - m1) : 0.f;
      den0 += p00; fma8(acc0, p00, q00);
      den0 += p01; fma8(acc0, p01, q01);
      den1 += p10; fma8(acc1, p10, q10);
      den1 += p11; fma8(acc1, p11, q11);
    }
    if (j < nI) {
      int s00 = __shfl(sidx0, j * 8 + rg, 64);
      int s10 = __shfl(sidx1, j * 8 + rg, 64);
      size_t a00 = (size_t)(s00 >= 0 ? s00 : 0);
      size_t a10 = (size_t)(s10 >= 0 ? s10 : 0);
      float l00 = al[a00 * 16 + cg];
      float l10 = al[a10 * 16 + cg];
      uint4 q00 = H4b[a00 * 8 + cg];
      uint4 q10 = H4b[a10 * 8 + cg];
      float p00 = (s00 >= 0) ? __expf(lrelu(l00 + ald0) - m0) : 0.f;
      float p10 = (s10 >= 0) ? __expf(lrelu(l10 + ald1) - m1) : 0.f;
      den0 += p00; fma8(acc0, p00, q00);
      den1 += p10; fma8(acc1, p10, q10);
    }
  }
#pragma unroll
  for (int mm = 8; mm < 64; mm <<= 1) {
#pragma unroll
    for (int i = 0; i < 8; ++i) {
      acc0[i] += __shfl_xor(acc0[i], mm, 64);
      acc1[i] += __shfl_xor(acc1[i], mm, 64);
    }
    den0 += __shfl_xor(den0, mm, 64);
    den1 += __shfl_xor(den1, mm, 64);
  }
  if (rg != 0) return;
#pragma unroll
  for (int nd = 0; nd < 2; ++nd) {
    if (nd == 1 && !has1) break;
    int d = nd == 0 ? d0 : d1;
    float* acc = nd == 0 ? acc0 : acc1;
    float es = nd == 0 ? es0 : es1;
    float m = nd == 0 ? m0 : m1;
    float den = nd == 0 ? den0 : den1;
    float pself = __expf(es - m);
    uint4 hw = H4b[(size_t)d * 8 + cg];
    float hs[8] = {bf_lo(hw.x), bf_hi(hw.x), bf_lo(hw.y), bf_hi(hw.y),
                   bf_lo(hw.z), bf_hi(hw.z), bf_lo(hw.w), bf_hi(hw.w)};
#pragma unroll
    for (int i = 0; i < 8; ++i) acc[i] = fmaf(pself, hs[i], acc[i]);
    den += pself;
    float inv = 1.f / den;
    float4 b0 = ((const float4*)bias)[cg * 2];
    float4 b1 = ((const float4*)bias)[cg * 2 + 1];
    float bv[8] = {b0.x, b0.y, b0.z, b0.w, b1.x, b1.y, b1.z, b1.w};
    float v[8];
#pragma unroll
    for (int i = 0; i < 8; ++i) v[i] = acc[i] * inv + bv[i];
    size_t o0 = (size_t)d * 16 + cg * 2;
    ((float4*)R)[o0] = {v[0], v[1], v[2], v[3]};
    ((float4*)R)[o0 + 1] = {v[4], v[5], v[6], v[7]};
    float dd = dis[d];
    uint4 tw = {pack_bf16(dd * v[0], dd * v[1]), pack_bf16(dd * v[2], dd * v[3]),
                pack_bf16(dd * v[4], dd * v[5]), pack_bf16(dd * v[6], dd * v[7])};
    ((uint4*)Tout)[(size_t)d * 8 + cg] = tw;
  }
}

// --------------------------- fused GCN conv kernel -------------------------
// out = (A_norm x) W + b computed as: gather T=bf16(dis*x), z=dis_d(sum+self),
// per-node 64x64 W-multiply via per-wave LDS (lane = output channel), fused
// epilogue per mode, emits next table T' = bf16(dis * x_new).

enum { CG0 = 0, CGR = 1, CGRL = 2, CGD = 3 };

template <int MODE>
__global__ __launch_bounds__(256) void k_conv(
    const int* __restrict__ off, const int* __restrict__ idx,
    const u32* __restrict__ Tin, u32* __restrict__ Tout,
    const float* __restrict__ dis, const float* __restrict__ W,
    const float* __restrict__ bias, float* __restrict__ R,
    float* __restrict__ X, int n) {
  __shared__ float zs[4][128];
  int lane = threadIdx.x & 63;
  int wid = threadIdx.x >> 6;
  int d0 = blockIdx.x * 8 + wid * 2;
  if (d0 >= n) return;
  int d1 = d0 + 1;
  bool has1 = d1 < n;
  int rg = lane >> 3, cg = lane & 7;
  const uint4* T4 = (const uint4*)Tin;
  int beg0 = off[d0], end0 = off[d0 + 1];
  int beg1 = has1 ? off[d1] : 0, end1 = has1 ? off[d1 + 1] : 0;
  int cnt0 = end0 - beg0, cnt1 = end1 - beg1;
  int cmax = cnt0 > cnt1 ? cnt0 : cnt1;
  float acc0[8], acc1[8];
#pragma unroll
  for (int i = 0; i < 8; ++i) { acc0[i] = 0.f; acc1[i] = 0.f; }
  for (int base = 0; base < cmax; base += 64) {
    int c0 = cnt0 - base; if (c0 > 64) c0 = 64;
    int c1 = cnt1 - base; if (c1 > 64) c1 = 64;
    int sidx0 = (lane < c0) ? idx[beg0 + base + lane] : -1;
    int sidx1 = (lane < c1) ? idx[beg1 + base + lane] : -1;
    int hi = c0 > c1 ? c0 : c1;
    int nI = (hi + 7) >> 3;
    int j = 0;
    for (; j + 2 <= nI; j += 2) {
      int s00 = __shfl(sidx0, j * 8 + rg, 64);
      int s01 = __shfl(sidx0, j * 8 + 8 + rg, 64);
      int s10 = __shfl(sidx1, j * 8 + rg, 64);
      int s11 = __shfl(sidx1, j * 8 + 8 + rg, 64);
      size_t a00 = (size_t)(s00 >= 0 ? s00 : 0);
      size_t a01 = (size_t)(s01 >= 0 ? s01 : 0);
      size_t a10 = (size_t)(s10 >= 0 ? s10 : 0);
      size_t a11 = (size_t)(s11 >= 0 ? s11 : 0);
      uint4 q00 = T4[a00 * 8 + cg];
      uint4 q01 = T4[a01 * 8 + cg];
      uint4 q10 = T4[a10 * 8 + cg];
      uint4 q11 = T4[a11 * 8 + cg];
      if (s00 < 0) q00 = {0u,0u,0u,0u};
      if (s01 < 0) q01 = {0u,0u,0u,0u};
      if (s10 < 0) q10 = {0u,0u,0u,0u};
      if (s11 < 0) q11 = {0u,0u,0u,0u};
      acc8(acc0, q00);
      acc8(acc0, q01);
      acc8(acc1, q10);
      acc8(acc1, q11);
    }
    if (j < nI) {
      int s00 = __shfl(sidx0, j * 8 + rg, 64);
      int s10 = __shfl(sidx1, j * 8 + rg, 64);
      size_t a00 = (size_t)(s00 >= 0 ? s00 : 0);
      size_t a10 = (size_t)(s10 >= 0 ? s10 : 0);
      uint4 q00 = T4[a00 * 8 + cg];
      uint4 q10 = T4[a10 * 8 + cg];
      if (s00 < 0) q00 = {0u,0u,0u,0u};
      if (s10 < 0) q10 = {0u,0u,0u,0u};
      acc8(acc0, q00);
      acc8(acc1, q10);
    }
  }
#pragma unroll
  for (int m = 8; m < 64; m <<= 1)
#pragma unroll
    for (int i = 0; i < 8; ++i) {
      acc0[i] += __shfl_xor(acc0[i], m, 64);
      acc1[i] += __shfl_xor(acc1[i], m, 64);
    }
  // z = dis_d * (sum + self); all lanes hold full sums; rg==0 stages to LDS.
  float dd0 = dis[d0];
  uint4 ts0 = T4[(size_t)d0 * 8 + cg];
  float z0[8] = {dd0 * (acc0[0] + bf_lo(ts0.x)), dd0 * (acc0[1] + bf_hi(ts0.x)),
                 dd0 * (acc0[2] + bf_lo(ts0.y)), dd0 * (acc0[3] + bf_hi(ts0.y)),
                 dd0 * (acc0[4] + bf_lo(ts0.z)), dd0 * (acc0[5] + bf_hi(ts0.z)),
                 dd0 * (acc0[6] + bf_lo(ts0.w)), dd0 * (acc0[7] + bf_hi(ts0.w))};
  float dd1 = has1 ? dis[d1] : 0.f;
  uint4 ts1 = T4[(size_t)(has1 ? d1 : d0) * 8 + cg];
  float z1[8] = {dd1 * (acc1[0] + bf_lo(ts1.x)), dd1 * (acc1[1] + bf_hi(ts1.x)),
                 dd1 * (acc1[2] + bf_lo(ts1.y)), dd1 * (acc1[3] + bf_hi(ts1.y)),
                 dd1 * (acc1[4] + bf_lo(ts1.z)), dd1 * (acc1[5] + bf_hi(ts1.z)),
                 dd1 * (acc1[6] + bf_lo(ts1.w)), dd1 * (acc1[7] + bf_hi(ts1.w))};
  if (rg == 0) {
    float4* zp = (float4*)&zs[wid][cg * 8];
    zp[0] = {z0[0], z0[1], z0[2], z0[3]};
    zp[1] = {z0[4], z0[5], z0[6], z0[7]};
    float4* zq = (float4*)&zs[wid][64 + cg * 8];
    zq[0] = {z1[0], z1[1], z1[2], z1[3]};
    zq[1] = {z1[4], z1[5], z1[6], z1[7]};
  }
  asm volatile("s_waitcnt lgkmcnt(0)" ::: "memory");
  // 64x64 W-multiply: lane = output channel c.
  float outc0 = bias[lane];
  float outc1 = outc0;
  const float4* za = (const float4*)&zs[wid][0];
  const float4* zb = (const float4*)&zs[wid][64];
#pragma unroll 4
  for (int k4 = 0; k4 < 16; ++k4) {
    float4 a = za[k4];
    float4 b = zb[k4];
    int k = k4 * 4;
    float w0 = W[(k + 0) * 64 + lane];
    float w1 = W[(k + 1) * 64 + lane];
    float w2 = W[(k + 2) * 64 + lane];
    float w3 = W[(k + 3) * 64 + lane];
    outc0 = fmaf(a.x, w0, outc0); outc1 = fmaf(b.x, w0, outc1);
    outc0 = fmaf(a.y, w1, outc0); outc1 = fmaf(b.y, w1, outc1);
    outc0 = fmaf(a.z, w2, outc0); outc1 = fmaf(b.z, w2, outc1);
    outc0 = fmaf(a.w, w3, outc0); outc1 = fmaf(b.w, w3, outc1);
  }
  // epilogue per node
#pragma unroll
  for (int nd = 0; nd < 2; ++nd) {
    if (nd == 1 && !has1) break;
    int d = nd == 0 ? d0 : d1;
    float outv = nd == 0 ? outc0 : outc1;
    size_t o = (size_t)d * 64 + lane;
    float res;
    if (MODE == CGD) {
      res = X[o] + outv;                     // feeds only next table
    } else if (MODE == CG0) {
      res = fmaxf(outv, 0.f);
      X[o] = res;
    } else {                                  // CGR / CGRL
      float val = outv + R[o];
      R[o] = val;
      res = fmaxf(val, 0.f);
      X[o] = res;
    }
    if (MODE != CGRL) {
      float t = dis[d] * res;
      float tp = __shfl_xor(t, 1, 64);
      if (!(lane & 1))
        Tout[(size_t)d * 32 + (lane >> 1)] = pack_bf16(t, tp);
    }
  }
}

// ------------------------------- final linear ------------------------------

__global__ __launch_bounds__(256) void k_fc(
    const float* __restrict__ X, const float* __restrict__ W,
    const float* __restrict__ b, float* __restrict__ out, int n) {
  __shared__ float Wl[640];
  __shared__ float bl[10];
  for (int i = threadIdx.x; i < 640; i += 256) Wl[i] = W[i];
  if (threadIdx.x < 10) bl[threadIdx.x] = b[threadIdx.x];
  __syncthreads();
  int r = blockIdx.x * blockDim.x + threadIdx.x;
  if (r >= n) return;
  float acc[10];
#pragma unroll
  for (int c = 0; c < 10; ++c) acc[c] = bl[c];
#pragma unroll
  for (int k = 0; k < 64; ++k) {
    float xv = X[(size_t)r * 64 + k];
#pragma unroll
    for (int c = 0; c < 10; ++c) acc[c] = fmaf(xv, Wl[k * 10 + c], acc[c]);
  }
#pragma unroll
  for (int c = 0; c < 10; ++c) out[(size_t)r * 10 + c] = acc[c];
}

// --------------------------------- launch ----------------------------------

extern "C" void kernel_launch(void* const* d_in, const int* in_sizes, int n_in,
                              void* d_out, int out_size, void* d_ws, size_t ws_size,
                              hipStream_t stream) {
  const float* x_in  = (const float*)d_in[0];
  const int*   ei    = (const int*)d_in[1];
  const float* gatW  = (const float*)d_in[2];
  const float* gatAs = (const float*)d_in[3];
  const float* gatAd = (const float*)d_in[4];
  const float* gatB  = (const float*)d_in[5];
  const float* gcnW  = (const float*)d_in[6];
  const float* gcnB  = (const float*)d_in[7];
  const float* fcW   = (const float*)d_in[8];
  const float* fcB   = (const float*)d_in[9];
  float* out = (float*)d_out;

  const int N = in_sizes[0] / 64;
  const int E = in_sizes[1] / 2;
  const int NB = (N + RNGB - 1) >> BSH;
  const int chunk = (E + GEB - 1) / GEB;

  char* ws = (char*)d_ws;
  size_t o = 0;
  auto alloc = [&](size_t bytes) -> char* {
    char* p = ws + o;
    o = (o + bytes + 255) & ~(size_t)255;
    return p;
  };
  int* offA    = (int*)alloc((size_t)(N + 1) * 4);
  int* offB    = (int*)alloc((size_t)(N + 1) * 4);
  float* dis   = (float*)alloc((size_t)N * 4);
  int* idxA    = (int*)alloc((size_t)E * 4);
  int* idxB    = (int*)alloc((size_t)E * 4);
  int2* pairsA = (int2*)alloc((size_t)E * 8);
  int2* pairsB = (int2*)alloc((size_t)E * 8);
  int* gHistA  = (int*)alloc((size_t)GEB * NB * 4);
  int* gHistB  = (int*)alloc((size_t)GEB * NB * 4);
  int* totA    = (int*)alloc((size_t)NB * 4);
  int* totB    = (int*)alloc((size_t)NB * 4);
  int* baseA   = (int*)alloc((size_t)NB * 4);
  int* baseB   = (int*)alloc((size_t)NB * 4);
  float* al    = (float*)alloc((size_t)N * 16 * 4);
  u32* B0      = (u32*)alloc((size_t)N * 32 * 4);   // bf16 table [N][64]
  u32* B1      = (u32*)alloc((size_t)N * 32 * 4);   // bf16 table [N][64]
  float* X     = (float*)alloc((size_t)N * 64 * 4);
  float* R     = (float*)alloc((size_t)N * 64 * 4);

  int nbN = (N + 255) / 256;
  int nbAgg = (N + 7) / 8;
  int nbG = (N + 63) / 64;

  // ---- CSR build: bucketed counting sort (NO neighbor sort) ----
  k_hist<<<GEB, 256, 0, stream>>>(ei, E, NB, chunk, gHistA, gHistB);
  k_colscan<<<NB, GEB, 0, stream>>>(gHistA, totA, NB);
  k_colscan<<<NB, GEB, 0, stream>>>(gHistB, totB, NB);
  k_bscan<<<1, 1024, 0, stream>>>(totA, totB, baseA, baseB, offA, offB, NB, N, E);
  k_scatter<<<GEB, 256, 0, stream>>>(ei, E, NB, chunk, gHistA, gHistB,
                                     baseA, baseB, pairsA, pairsB);
  k_bucket<0><<<NB, 256, 0, stream>>>(pairsA, baseA, totA, offA, idxA, nullptr, N);
  k_bucket<1><<<NB, 256, 0, stream>>>(pairsB, baseB, totB, offB, idxB, dis, N);

  // ---- random walk: 5 steps (fp32 in -> bf16 ping-pong), result in B0 ----
  k_rw<1><<<nbAgg, 256, 0, stream>>>(offA, idxA, x_in, nullptr, B0, N);
  k_rw<0><<<nbAgg, 256, 0, stream>>>(offA, idxA, nullptr, B0, B1, N);
  k_rw<0><<<nbAgg, 256, 0, stream>>>(offA, idxA, nullptr, B1, B0, N);
  k_rw<0><<<nbAgg, 256, 0, stream>>>(offA, idxA, nullptr, B0, B1, N);
  k_rw<0><<<nbAgg, 256, 0, stream>>>(offA, idxA, nullptr, B1, B0, N);

  // ---- GAT: projections into B1, then softmax agg -> T0 in B0 (B0 is free
  //      once gat_gemm has consumed it) + residual R ----
  k_gat_gemm<<<nbG, 256, 0, stream>>>(B0, gatW, gatAs, gatAd, B1, al, N);
  k_gat_agg<<<nbAgg, 256, 0, stream>>>(offB, idxB, B1, al, gatB, dis, B0, R, N);

  // ---- residual GCN: fused conv kernels, tables ping-pong B0/B1 ----
  u32* Tc = B0;
  u32* Ta = B1;
  for (int i = 0; i < 12; ++i) {
    if (i == 0)
      k_conv<CG0><<<nbAgg, 256, 0, stream>>>(offB, idxB, Tc, Ta, dis,
                                             gcnW, gcnB, nullptr, X, N);
    else if (i == 11)
      k_conv<CGRL><<<nbAgg, 256, 0, stream>>>(offB, idxB, Tc, nullptr, dis,
                                              gcnW + i * 4096, gcnB + i * 64, R, X, N);
    else
      k_conv<CGR><<<nbAgg, 256, 0, stream>>>(offB, idxB, Tc, Ta, dis,
                                             gcnW + i * 4096, gcnB + i * 64, R, X, N);
    { u32* t = Tc; Tc = Ta; Ta = t; }
    if (i < 11) {
      int j = (i == 0) ? 11 : i - 1;
      k_conv<CGD><<<nbAgg, 256, 0, stream>>>(offB, idxB, Tc, Ta, dis,
                                             gcnW + j * 4096, gcnB + j * 64, nullptr, X, N);
      u32* t = Tc; Tc = Ta; Ta = t;
    }
  }

  // ---- final linear ----
  k_fc<<<nbN, 256, 0, stream>>>(X, fcW, fcB, out, N);
}

// Round 12
// 1861.675 us; speedup vs baseline: 1.0589x; 1.0180x over previous
//
#include <hip/hip_runtime.h>

// ---------------------------------------------------------------------------
// LRA_GNN: random-walk -> 8-head GAT -> 12-layer residual GCN -> FC.
// Round 12: fused GCN conv, take 2. r11's fusion failed because lane=channel
// W-loads were per-lane VMEM (64 extra VMEM instr/node-pair starved the
// gathers: 3.35->2.3 TB/s). Now: block = 64 nodes; gather phase (proven r9
// dual-chain body, 16 nodes/wave) stages z=dis*(sum+self) into zs[64][65];
// __syncthreads; then k_gemm64's exact inner loop (lane=row, wave-uniform
// scalar W loads on SMEM pipe) + fused epilogue + bf16 table emission.
// ---------------------------------------------------------------------------

typedef unsigned int u32;

#define BSH 7              // bucket shift: 128 nodes per bucket
#define RNGB 128           // nodes per bucket
#define GEB 256            // edge-pass blocks

__device__ __forceinline__ float lrelu(float v) { return v > 0.f ? v : 0.2f * v; }
__device__ __forceinline__ float bf_lo(u32 w) { return __uint_as_float(w << 16); }
__device__ __forceinline__ float bf_hi(u32 w) { return __uint_as_float(w & 0xffff0000u); }
__device__ __forceinline__ u32 pack_bf16(float a, float b) {
  u32 ua = __float_as_uint(a); ua = ua + 0x7fffu + ((ua >> 16) & 1u);
  u32 ub = __float_as_uint(b); ub = ub + 0x7fffu + ((ub >> 16) & 1u);
  return (ua >> 16) | (ub & 0xffff0000u);
}
__device__ __forceinline__ void acc8(float* acc, uint4 q) {
  acc[0] += bf_lo(q.x); acc[1] += bf_hi(q.x);
  acc[2] += bf_lo(q.y); acc[3] += bf_hi(q.y);
  acc[4] += bf_lo(q.z); acc[5] += bf_hi(q.z);
  acc[6] += bf_lo(q.w); acc[7] += bf_hi(q.w);
}
__device__ __forceinline__ void fma8(float* acc, float p, uint4 q) {
  acc[0] = fmaf(p, bf_lo(q.x), acc[0]); acc[1] = fmaf(p, bf_hi(q.x), acc[1]);
  acc[2] = fmaf(p, bf_lo(q.y), acc[2]); acc[3] = fmaf(p, bf_hi(q.y), acc[3]);
  acc[4] = fmaf(p, bf_lo(q.z), acc[4]); acc[5] = fmaf(p, bf_hi(q.z), acc[5]);
  acc[6] = fmaf(p, bf_lo(q.w), acc[6]); acc[7] = fmaf(p, bf_hi(q.w), acc[7]);
}

// --------------------- CSR build via bucketed counting sort ----------------

__global__ __launch_bounds__(256) void k_hist(
    const int* __restrict__ ei, int E, int NB, int chunk,
    int* __restrict__ gHistA, int* __restrict__ gHistB) {
  __shared__ int hA[1024], hB[1024];
  for (int i = threadIdx.x; i < NB; i += 256) { hA[i] = 0; hB[i] = 0; }
  __syncthreads();
  int e0 = blockIdx.x * chunk;
  int e1 = min(E, e0 + chunk);
  for (int e = e0 + threadIdx.x; e < e1; e += 256) {
    int s = ei[e], d = ei[E + e];
    atomicAdd(&hA[s >> BSH], 1);
    atomicAdd(&hB[d >> BSH], 1);
  }
  __syncthreads();
  for (int i = threadIdx.x; i < NB; i += 256) {
    gHistA[blockIdx.x * NB + i] = hA[i];
    gHistB[blockIdx.x * NB + i] = hB[i];
  }
}

__global__ __launch_bounds__(256) void k_colscan(
    int* __restrict__ gHist, int* __restrict__ tot, int NB) {
  __shared__ int s[GEB];
  int b = blockIdx.x;
  int t = threadIdx.x;
  int v = gHist[t * NB + b];
  s[t] = v;
  __syncthreads();
  for (int d = 1; d < GEB; d <<= 1) {
    int u = (t >= d) ? s[t - d] : 0;
    __syncthreads();
    s[t] += u;
    __syncthreads();
  }
  gHist[t * NB + b] = s[t] - v;
  if (t == GEB - 1) tot[b] = s[t];
}

__global__ __launch_bounds__(1024) void k_bscan(
    const int* __restrict__ totA, const int* __restrict__ totB,
    int* __restrict__ baseA, int* __restrict__ baseB,
    int* __restrict__ offA, int* __restrict__ offB, int NB, int N, int E) {
  __shared__ int sa[1024], sb[1024];
  int t = threadIdx.x;
  int va = (t < NB) ? totA[t] : 0;
  int vb = (t < NB) ? totB[t] : 0;
  sa[t] = va; sb[t] = vb;
  __syncthreads();
  for (int d = 1; d < 1024; d <<= 1) {
    int ua = (t >= d) ? sa[t - d] : 0;
    int ub = (t >= d) ? sb[t - d] : 0;
    __syncthreads();
    sa[t] += ua; sb[t] += ub;
    __syncthreads();
  }
  if (t < NB) { baseA[t] = sa[t] - va; baseB[t] = sb[t] - vb; }
  if (t == 0) { offA[N] = E; offB[N] = E; }
}

__global__ __launch_bounds__(256) void k_scatter(
    const int* __restrict__ ei, int E, int NB, int chunk,
    const int* __restrict__ gHistA, const int* __restrict__ gHistB,
    const int* __restrict__ baseA, const int* __restrict__ baseB,
    int2* __restrict__ pairsA, int2* __restrict__ pairsB) {
  __shared__ int cA[1024], cB[1024];
  int g = blockIdx.x;
  for (int i = threadIdx.x; i < NB; i += 256) {
    cA[i] = baseA[i] + gHistA[g * NB + i];
    cB[i] = baseB[i] + gHistB[g * NB + i];
  }
  __syncthreads();
  int e0 = g * chunk;
  int e1 = min(E, e0 + chunk);
  for (int e = e0 + threadIdx.x; e < e1; e += 256) {
    int s = ei[e], d = ei[E + e];
    int pa = atomicAdd(&cA[s >> BSH], 1);
    pairsA[pa] = {s, d};
    int pb = atomicAdd(&cB[d >> BSH], 1);
    pairsB[pb] = {s, d};
  }
}

template <int KEY>
__global__ __launch_bounds__(256) void k_bucket(
    const int2* __restrict__ pairs, const int* __restrict__ base,
    const int* __restrict__ tot, int* __restrict__ off,
    int* __restrict__ idx, float* __restrict__ dis, int N) {
  __shared__ int cnt[RNGB], pfx[RNGB];
  int b = blockIdx.x;
  int node0 = b << BSH;
  int rng = min(RNGB, N - node0);
  int bstart = base[b], bcount = tot[b];
  for (int i = threadIdx.x; i < rng; i += 256) cnt[i] = 0;
  __syncthreads();
  for (int i = threadIdx.x; i < bcount; i += 256) {
    int2 p = pairs[bstart + i];
    int loc = (KEY == 0 ? p.x : p.y) - node0;
    atomicAdd(&cnt[loc], 1);
  }
  __syncthreads();
  if (threadIdx.x == 0) {
    int run = 0;
    for (int i = 0; i < rng; ++i) { pfx[i] = run; run += cnt[i]; }
  }
  __syncthreads();
  for (int i = threadIdx.x; i < rng; i += 256) {
    off[node0 + i] = bstart + pfx[i];
    if (KEY == 1) dis[node0 + i] = rsqrtf((float)(cnt[i] + 1));
  }
  __syncthreads();
  for (int i = threadIdx.x; i < bcount; i += 256) {
    int2 p = pairs[bstart + i];
    int loc = (KEY == 0 ? p.x : p.y) - node0;
    int pos = bstart + atomicAdd(&pfx[loc], 1);
    idx[pos] = (KEY == 0 ? p.y : p.x);
  }
}

// ------------------------- random-walk aggregation -------------------------

template <int FIRST>
__global__ __launch_bounds__(256) void k_rw(
    const int* __restrict__ off, const int* __restrict__ idx,
    const float* __restrict__ Hf, const u32* __restrict__ Hb,
    u32* __restrict__ Xb, int n) {
  int lane = threadIdx.x & 63;
  int wid = threadIdx.x >> 6;
  int d0 = blockIdx.x * 8 + wid * 2;
  if (d0 >= n) return;
  int d1 = d0 + 1;
  bool has1 = d1 < n;
  int rg = lane >> 3, cg = lane & 7;
  const uint4* H4b = (const uint4*)Hb;
  const float4* H4f = (const float4*)Hf;
  int beg0 = off[d0], end0 = off[d0 + 1];
  int beg1 = has1 ? off[d1] : 0, end1 = has1 ? off[d1 + 1] : 0;
  int cnt0 = end0 - beg0, cnt1 = end1 - beg1;
  int cmax = cnt0 > cnt1 ? cnt0 : cnt1;
  float acc0[8], acc1[8];
#pragma unroll
  for (int i = 0; i < 8; ++i) { acc0[i] = 0.f; acc1[i] = 0.f; }
  for (int base = 0; base < cmax; base += 64) {
    int c0 = cnt0 - base; if (c0 > 64) c0 = 64;
    int c1 = cnt1 - base; if (c1 > 64) c1 = 64;
    int sidx0 = (lane < c0) ? idx[beg0 + base + lane] : -1;
    int sidx1 = (lane < c1) ? idx[beg1 + base + lane] : -1;
    int hi = c0 > c1 ? c0 : c1;
    int nI = (hi + 7) >> 3;
    int j = 0;
    for (; j + 2 <= nI; j += 2) {
      int s00 = __shfl(sidx0, j * 8 + rg, 64);
      int s01 = __shfl(sidx0, j * 8 + 8 + rg, 64);
      int s10 = __shfl(sidx1, j * 8 + rg, 64);
      int s11 = __shfl(sidx1, j * 8 + 8 + rg, 64);
      size_t a00 = (size_t)(s00 >= 0 ? s00 : 0);
      size_t a01 = (size_t)(s01 >= 0 ? s01 : 0);
      size_t a10 = (size_t)(s10 >= 0 ? s10 : 0);
      size_t a11 = (size_t)(s11 >= 0 ? s11 : 0);
      if (FIRST) {
        float4 x00 = H4f[a00 * 16 + cg * 2], y00 = H4f[a00 * 16 + cg * 2 + 1];
        float4 x01 = H4f[a01 * 16 + cg * 2], y01 = H4f[a01 * 16 + cg * 2 + 1];
        float4 x10 = H4f[a10 * 16 + cg * 2], y10 = H4f[a10 * 16 + cg * 2 + 1];
        float4 x11 = H4f[a11 * 16 + cg * 2], y11 = H4f[a11 * 16 + cg * 2 + 1];
        if (s00 < 0) { x00 = {0,0,0,0}; y00 = {0,0,0,0}; }
        if (s01 < 0) { x01 = {0,0,0,0}; y01 = {0,0,0,0}; }
        if (s10 < 0) { x10 = {0,0,0,0}; y10 = {0,0,0,0}; }
        if (s11 < 0) { x11 = {0,0,0,0}; y11 = {0,0,0,0}; }
        acc0[0] += x00.x; acc0[1] += x00.y; acc0[2] += x00.z; acc0[3] += x00.w;
        acc0[4] += y00.x; acc0[5] += y00.y; acc0[6] += y00.z; acc0[7] += y00.w;
        acc0[0] += x01.x; acc0[1] += x01.y; acc0[2] += x01.z; acc0[3] += x01.w;
        acc0[4] += y01.x; acc0[5] += y01.y; acc0[6] += y01.z; acc0[7] += y01.w;
        acc1[0] += x10.x; acc1[1] += x10.y; acc1[2] += x10.z; acc1[3] += x10.w;
        acc1[4] += y10.x; acc1[5] += y10.y; acc1[6] += y10.z; acc1[7] += y10.w;
        acc1[0] += x11.x; acc1[1] += x11.y; acc1[2] += x11.z; acc1[3] += x11.w;
        acc1[4] += y11.x; acc1[5] += y11.y; acc1[6] += y11.z; acc1[7] += y11.w;
      } else {
        uint4 q00 = H4b[a00 * 8 + cg];
        uint4 q01 = H4b[a01 * 8 + cg];
        uint4 q10 = H4b[a10 * 8 + cg];
        uint4 q11 = H4b[a11 * 8 + cg];
        if (s00 < 0) q00 = {0u,0u,0u,0u};
        if (s01 < 0) q01 = {0u,0u,0u,0u};
        if (s10 < 0) q10 = {0u,0u,0u,0u};
        if (s11 < 0) q11 = {0u,0u,0u,0u};
        acc8(acc0, q00);
        acc8(acc0, q01);
        acc8(acc1, q10);
        acc8(acc1, q11);
      }
    }
    if (j < nI) {
      int s00 = __shfl(sidx0, j * 8 + rg, 64);
      int s10 = __shfl(sidx1, j * 8 + rg, 64);
      size_t a00 = (size_t)(s00 >= 0 ? s00 : 0);
      size_t a10 = (size_t)(s10 >= 0 ? s10 : 0);
      if (FIRST) {
        float4 x00 = H4f[a00 * 16 + cg * 2], y00 = H4f[a00 * 16 + cg * 2 + 1];
        float4 x10 = H4f[a10 * 16 + cg * 2], y10 = H4f[a10 * 16 + cg * 2 + 1];
        if (s00 < 0) { x00 = {0,0,0,0}; y00 = {0,0,0,0}; }
        if (s10 < 0) { x10 = {0,0,0,0}; y10 = {0,0,0,0}; }
        acc0[0] += x00.x; acc0[1] += x00.y; acc0[2] += x00.z; acc0[3] += x00.w;
        acc0[4] += y00.x; acc0[5] += y00.y; acc0[6] += y00.z; acc0[7] += y00.w;
        acc1[0] += x10.x; acc1[1] += x10.y; acc1[2] += x10.z; acc1[3] += x10.w;
        acc1[4] += y10.x; acc1[5] += y10.y; acc1[6] += y10.z; acc1[7] += y10.w;
      } else {
        uint4 q00 = H4b[a00 * 8 + cg];
        uint4 q10 = H4b[a10 * 8 + cg];
        if (s00 < 0) q00 = {0u,0u,0u,0u};
        if (s10 < 0) q10 = {0u,0u,0u,0u};
        acc8(acc0, q00);
        acc8(acc1, q10);
      }
    }
  }
#pragma unroll
  for (int m = 8; m < 64; m <<= 1)
#pragma unroll
    for (int i = 0; i < 8; ++i) {
      acc0[i] += __shfl_xor(acc0[i], m, 64);
      acc1[i] += __shfl_xor(acc1[i], m, 64);
    }
  if (rg != 0) return;
  uint4 o0 = {pack_bf16(acc0[0], acc0[1]), pack_bf16(acc0[2], acc0[3]),
              pack_bf16(acc0[4], acc0[5]), pack_bf16(acc0[6], acc0[7])};
  ((uint4*)Xb)[(size_t)d0 * 8 + cg] = o0;
  if (has1) {
    uint4 o1 = {pack_bf16(acc1[0], acc1[1]), pack_bf16(acc1[2], acc1[3]),
                pack_bf16(acc1[4], acc1[5]), pack_bf16(acc1[6], acc1[7])};
    ((uint4*)Xb)[(size_t)d1 * 8 + cg] = o1;
  }
}

// ------------------------------- GAT kernels -------------------------------

__global__ __launch_bounds__(256) void k_gat_gemm(
    const u32* __restrict__ Xb, const float* __restrict__ W,
    const float* __restrict__ asrc, const float* __restrict__ adst,
    u32* __restrict__ Hgb, float* __restrict__ al, int n) {
  __shared__ float Xs[64 * 65];
  int row0 = blockIdx.x * 64;
  for (int t = threadIdx.x; t < 512; t += 256) {
    int r = t >> 3, k8 = t & 7;
    int row = row0 + r;
    uint4 xw = (row < n) ? ((const uint4*)Xb)[(size_t)row * 8 + k8]
                         : uint4{0u, 0u, 0u, 0u};
    float* dst = &Xs[r * 65 + k8 * 8];
    dst[0] = bf_lo(xw.x); dst[1] = bf_hi(xw.x);
    dst[2] = bf_lo(xw.y); dst[3] = bf_hi(xw.y);
    dst[4] = bf_lo(xw.z); dst[5] = bf_hi(xw.z);
    dst[6] = bf_lo(xw.w); dst[7] = bf_hi(xw.w);
  }
  __syncthreads();
  int lane = threadIdx.x & 63;
  int w = __builtin_amdgcn_readfirstlane(threadIdx.x >> 6);
  int c0 = w * 16;
  int row = row0 + lane;
  float acc[16];
#pragma unroll
  for (int c = 0; c < 16; ++c) acc[c] = 0.f;
#pragma unroll 4
  for (int k = 0; k < 64; ++k) {
    float xk = Xs[lane * 65 + k];
#pragma unroll
    for (int c = 0; c < 16; ++c) {
      int gc = c0 + c;
      acc[c] = fmaf(xk, W[(gc >> 3) * 512 + k * 8 + (gc & 7)], acc[c]);
    }
  }
  if (row >= n) return;
  float s1a = 0.f, s2a = 0.f, s1b = 0.f, s2b = 0.f;
#pragma unroll
  for (int cc = 0; cc < 8; ++cc) {
    s1a = fmaf(acc[cc], asrc[c0 + cc], s1a);
    s2a = fmaf(acc[cc], adst[c0 + cc], s2a);
    s1b = fmaf(acc[8 + cc], asrc[c0 + 8 + cc], s1b);
    s2b = fmaf(acc[8 + cc], adst[c0 + 8 + cc], s2b);
  }
  float2* al2 = (float2*)al;
  al2[(size_t)row * 8 + w] = {s1a, s1b};
  al2[(size_t)row * 8 + 4 + w] = {s2a, s2b};
  uint4* H4 = (uint4*)Hgb;
  uint4 o0 = {pack_bf16(acc[0], acc[1]), pack_bf16(acc[2], acc[3]),
              pack_bf16(acc[4], acc[5]), pack_bf16(acc[6], acc[7])};
  uint4 o1 = {pack_bf16(acc[8], acc[9]), pack_bf16(acc[10], acc[11]),
              pack_bf16(acc[12], acc[13]), pack_bf16(acc[14], acc[15])};
  H4[(size_t)row * 8 + w * 2] = o0;
  H4[(size_t)row * 8 + w * 2 + 1] = o1;
}

__global__ __launch_bounds__(256) void k_gat_agg(
    const int* __restrict__ off, const int* __restrict__ idx,
    const u32* __restrict__ Hgb, const float* __restrict__ al,
    const float* __restrict__ bias, const float* __restrict__ dis,
    u32* __restrict__ Tout, float* __restrict__ R, int n) {
  int lane = threadIdx.x & 63;
  int wid = threadIdx.x >> 6;
  int d0 = blockIdx.x * 8 + wid * 2;
  if (d0 >= n) return;
  int d1 = d0 + 1;
  bool has1 = d1 < n;
  int rg = lane >> 3, cg = lane & 7;
  const uint4* H4b = (const uint4*)Hgb;
  float ald0 = al[(size_t)d0 * 16 + 8 + cg];
  float es0 = lrelu(al[(size_t)d0 * 16 + cg] + ald0);
  float ald1 = has1 ? al[(size_t)d1 * 16 + 8 + cg] : 0.f;
  float es1 = has1 ? lrelu(al[(size_t)d1 * 16 + cg] + ald1) : 0.f;
  int beg0 = off[d0], end0 = off[d0 + 1];
  int beg1 = has1 ? off[d1] : 0, end1 = has1 ? off[d1 + 1] : 0;
  int cnt0 = end0 - beg0, cnt1 = end1 - beg1;
  int cmax = cnt0 > cnt1 ? cnt0 : cnt1;
  float m0 = es0, m1 = es1;
  for (int base = 0; base < cmax; base += 64) {
    int c0 = cnt0 - base; if (c0 > 64) c0 = 64;
    int c1 = cnt1 - base; if (c1 > 64) c1 = 64;
    int sidx0 = (lane < c0) ? idx[beg0 + base + lane] : -1;
    int sidx1 = (lane < c1) ? idx[beg1 + base + lane] : -1;
    int hi = c0 > c1 ? c0 : c1;
    int nI = (hi + 7) >> 3;
    int j = 0;
    for (; j + 2 <= nI; j += 2) {
      int s00 = __shfl(sidx0, j * 8 + rg, 64);
      int s01 = __shfl(sidx0, j * 8 + 8 + rg, 64);
      int s10 = __shfl(sidx1, j * 8 + rg, 64);
      int s11 = __shfl(sidx1, j * 8 + 8 + rg, 64);
      float a00 = al[(size_t)(s00 >= 0 ? s00 : 0) * 16 + cg];
      float a01 = al[(size_t)(s01 >= 0 ? s01 : 0) * 16 + cg];
      float a10 = al[(size_t)(s10 >= 0 ? s10 : 0) * 16 + cg];
      float a11 = al[(size_t)(s11 >= 0 ? s11 : 0) * 16 + cg];
      if (s00 >= 0) m0 = fmaxf(m0, lrelu(a00 + ald0));
      if (s01 >= 0) m0 = fmaxf(m0, lrelu(a01 + ald0));
      if (s10 >= 0) m1 = fmaxf(m1, lrelu(a10 + ald1));
      if (s11 >= 0) m1 = fmaxf(m1, lrelu(a11 + ald1));
    }
    if (j < nI) {
      int s00 = __shfl(sidx0, j * 8 + rg, 64);
      int s10 = __shfl(sidx1, j * 8 + rg, 64);
      float a00 = al[(size_t)(s00 >= 0 ? s00 : 0) * 16 + cg];
      float a10 = al[(size_t)(s10 >= 0 ? s10 : 0) * 16 + cg];
      if (s00 >= 0) m0 = fmaxf(m0, lrelu(a00 + ald0));
      if (s10 >= 0) m1 = fmaxf(m1, lrelu(a10 + ald1));
    }
  }
#pragma unroll
  for (int mm = 8; mm < 64; mm <<= 1) {
    m0 = fmaxf(m0, __shfl_xor(m0, mm, 64));
    m1 = fmaxf(m1, __shfl_xor(m1, mm, 64));
  }
  float den0 = 0.f, den1 = 0.f;
  float acc0[8], acc1[8];
#pragma unroll
  for (int i = 0; i < 8; ++i) { acc0[i] = 0.f; acc1[i] = 0.f; }
  for (int base = 0; base < cmax; base += 64) {
    int c0 = cnt0 - base; if (c0 > 64) c0 = 64;
    int c1 = cnt1 - base; if (c1 > 64) c1 = 64;
    int sidx0 = (lane < c0) ? idx[beg0 + base + lane] : -1;
    int sidx1 = (lane < c1) ? idx[beg1 + base + lane] : -1;
    int hi = c0 > c1 ? c0 : c1;
    int nI = (hi + 7) >> 3;
    int j = 0;
    for (; j + 2 <= nI; j += 2) {
      int s00 = __shfl(sidx0, j * 8 + rg, 64);
      int s01 = __shfl(sidx0, j * 8 + 8 + rg, 64);
      int s10 = __shfl(sidx1, j * 8 + rg, 64);
      int s11 = __shfl(sidx1, j * 8 + 8 + rg, 64);
      size_t a00 = (size_t)(s00 >= 0 ? s00 : 0);
      size_t a01 = (size_t)(s01 >= 0 ? s01 : 0);
      size_t a10 = (size_t)(s10 >= 0 ? s10 : 0);
      size_t a11 = (size_t)(s11 >= 0 ? s11 : 0);
      float l00 = al[a00 * 16 + cg];
      float l01 = al[a01 * 16 + cg];
      float l10 = al[a10 * 16 + cg];
      float l11 = al[a11 * 16 + cg];
      uint4 q00 = H4b[a00 * 8 + cg];
      uint4 q01 = H4b[a01 * 8 + cg];
      uint4 q10 = H4b[a10 * 8 + cg];
      uint4 q11 = H4b[a11 * 8 + cg];
      float p00 = (s00 >= 0) ? __expf(lrelu(l00 + ald0) - m0) : 0.f;
      float p01 = (s01 >= 0) ? __expf(lrelu(l01 + ald0) - m0) : 0.f;
      float p10 = (s10 >= 0) ? __expf(lrelu(l10 + ald1) - m1) : 0.f;
      float p11 = (s11 >= 0) ? __expf(lrelu(l11 + ald1) - m1) : 0.f;
      den0 += p00; fma8(acc0, p00, q00);
      den0 += p01; fma8(acc0, p01, q01);
      den1 += p10; fma8(acc1, p10, q10);
      den1 += p11; fma8(acc1, p11, q11);
    }
    if (j < nI) {
      int s00 = __shfl(sidx0, j * 8 + rg, 64);
      int s10 = __shfl(sidx1, j * 8 + rg, 64);
      size_t a00 = (size_t)(s00 >= 0 ? s00 : 0);
      size_t a10 = (size_t)(s10 >= 0 ? s10 : 0);
      float l00 = al[a00 * 16 + cg];
      float l10 = al[a10 * 16 + cg];
      uint4 q00 = H4b[a00 * 8 + cg];
      uint4 q10 = H4b[a10 * 8 + cg];
      float p00 = (s00 >= 0) ? __expf(lrelu(l00 + ald0) - m0) : 0.f;
      float p10 = (s10 >= 0) ? __expf(lrelu(l10 + ald1) - m1) : 0.f;
      den0 += p00; fma8(acc0, p00, q00);
      den1 += p10; fma8(acc1, p10, q10);
    }
  }
#pragma unroll
  for (int mm = 8; mm < 64; mm <<= 1) {
#pragma unroll
    for (int i = 0; i < 8; ++i) {
      acc0[i] += __shfl_xor(acc0[i], mm, 64);
      acc1[i] += __shfl_xor(acc1[i], mm, 64);
    }
    den0 += __shfl_xor(den0, mm, 64);
    den1 += __shfl_xor(den1, mm, 64);
  }
  if (rg != 0) return;
#pragma unroll
  for (int nd = 0; nd < 2; ++nd) {
    if (nd == 1 && !has1) break;
    int d = nd == 0 ? d0 : d1;
    float* acc = nd == 0 ? acc0 : acc1;
    float es = nd == 0 ? es0 : es1;
    float m = nd == 0 ? m0 : m1;
    float den = nd == 0 ? den0 : den1;
    float pself = __expf(es - m);
    uint4 hw = H4b[(size_t)d * 8 + cg];
    float hs[8] = {bf_lo(hw.x), bf_hi(hw.x), bf_lo(hw.y), bf_hi(hw.y),
                   bf_lo(hw.z), bf_hi(hw.z), bf_lo(hw.w), bf_hi(hw.w)};
#pragma unroll
    for (int i = 0; i < 8; ++i) acc[i] = fmaf(pself, hs[i], acc[i]);
    den += pself;
    float inv = 1.f / den;
    float4 b0 = ((const float4*)bias)[cg * 2];
    float4 b1 = ((const float4*)bias)[cg * 2 + 1];
    float bv[8] = {b0.x, b0.y, b0.z, b0.w, b1.x, b1.y, b1.z, b1.w};
    float v[8];
#pragma unroll
    for (int i = 0; i < 8; ++i) v[i] = acc[i] * inv + bv[i];
    size_t o0 = (size_t)d * 16 + cg * 2;
    ((float4*)R)[o0] = {v[0], v[1], v[2], v[3]};
    ((float4*)R)[o0 + 1] = {v[4], v[5], v[6], v[7]};
    float dd = dis[d];
    uint4 tw = {pack_bf16(dd * v[0], dd * v[1]), pack_bf16(dd * v[2], dd * v[3]),
                pack_bf16(dd * v[4], dd * v[5]), pack_bf16(dd * v[6], dd * v[7])};
    ((uint4*)Tout)[(size_t)d * 8 + cg] = tw;
  }
}

// --------------------------- fused GCN conv kernel -------------------------
// Block = 64 nodes. Phase 1 (per wave, 16 nodes, 2 at a time): gather bf16
// table rows, reduce, z = dis*(sum+self) -> zs[64][65]. Phase 2 (k_gemm64
// structure): lane=row, wave w covers cols [16w,16w+16), scalar W loads.

enum { CG0 = 0, CGR = 1, CGRL = 2, CGD = 3 };

template <int MODE>
__global__ __launch_bounds__(256) void k_conv(
    const int* __restrict__ off, const int* __restrict__ idx,
    const u32* __restrict__ Tin, u32* __restrict__ Tout,
    const float* __restrict__ dis, const float* __restrict__ W,
    const float* __restrict__ bias, float* __restrict__ R,
    float* __restrict__ X, int n) {
  __shared__ float zs[64 * 65];
  int lane = threadIdx.x & 63;
  int wid = threadIdx.x >> 6;
  int rg = lane >> 3, cg = lane & 7;
  int node0 = blockIdx.x * 64;
  const uint4* T4 = (const uint4*)Tin;

  // ---- phase 1: gather 16 nodes per wave, 2 at a time ----
  for (int nd = 0; nd < 16; nd += 2) {
    int ni = wid * 16 + nd;
    int d0 = node0 + ni;
    int d1 = d0 + 1;
    bool has0 = d0 < n, has1 = d1 < n;
    int beg0 = has0 ? off[d0] : 0, end0 = has0 ? off[d0 + 1] : 0;
    int beg1 = has1 ? off[d1] : 0, end1 = has1 ? off[d1 + 1] : 0;
    int cnt0 = end0 - beg0, cnt1 = end1 - beg1;
    int cmax = cnt0 > cnt1 ? cnt0 : cnt1;
    float acc0[8], acc1[8];
#pragma unroll
    for (int i = 0; i < 8; ++i) { acc0[i] = 0.f; acc1[i] = 0.f; }
    for (int base = 0; base < cmax; base += 64) {
      int cA = cnt0 - base; if (cA > 64) cA = 64;
      int cB = cnt1 - base; if (cB > 64) cB = 64;
      int sidx0 = (lane < cA) ? idx[beg0 + base + lane] : -1;
      int sidx1 = (lane < cB) ? idx[beg1 + base + lane] : -1;
      int hi = cA > cB ? cA : cB;
      int nI = (hi + 7) >> 3;
      int j = 0;
      for (; j + 2 <= nI; j += 2) {
        int s00 = __shfl(sidx0, j * 8 + rg, 64);
        int s01 = __shfl(sidx0, j * 8 + 8 + rg, 64);
        int s10 = __shfl(sidx1, j * 8 + rg, 64);
        int s11 = __shfl(sidx1, j * 8 + 8 + rg, 64);
        size_t a00 = (size_t)(s00 >= 0 ? s00 : 0);
        size_t a01 = (size_t)(s01 >= 0 ? s01 : 0);
        size_t a10 = (size_t)(s10 >= 0 ? s10 : 0);
        size_t a11 = (size_t)(s11 >= 0 ? s11 : 0);
        uint4 q00 = T4[a00 * 8 + cg];
        uint4 q01 = T4[a01 * 8 + cg];
        uint4 q10 = T4[a10 * 8 + cg];
        uint4 q11 = T4[a11 * 8 + cg];
        if (s00 < 0) q00 = {0u,0u,0u,0u};
        if (s01 < 0) q01 = {0u,0u,0u,0u};
        if (s10 < 0) q10 = {0u,0u,0u,0u};
        if (s11 < 0) q11 = {0u,0u,0u,0u};
        acc8(acc0, q00);
        acc8(acc0, q01);
        acc8(acc1, q10);
        acc8(acc1, q11);
      }
      if (j < nI) {
        int s00 = __shfl(sidx0, j * 8 + rg, 64);
        int s10 = __shfl(sidx1, j * 8 + rg, 64);
        size_t a00 = (size_t)(s00 >= 0 ? s00 : 0);
        size_t a10 = (size_t)(s10 >= 0 ? s10 : 0);
        uint4 q00 = T4[a00 * 8 + cg];
        uint4 q10 = T4[a10 * 8 + cg];
        if (s00 < 0) q00 = {0u,0u,0u,0u};
        if (s10 < 0) q10 = {0u,0u,0u,0u};
        acc8(acc0, q00);
        acc8(acc1, q10);
      }
    }
#pragma unroll
    for (int m = 8; m < 64; m <<= 1)
#pragma unroll
      for (int i = 0; i < 8; ++i) {
        acc0[i] += __shfl_xor(acc0[i], m, 64);
        acc1[i] += __shfl_xor(acc1[i], m, 64);
      }
    if (rg == 0) {
      if (has0) {
        float dd = dis[d0];
        uint4 ts = T4[(size_t)d0 * 8 + cg];
        float* zp = &zs[ni * 65 + cg * 8];
        zp[0] = dd * (acc0[0] + bf_lo(ts.x)); zp[1] = dd * (acc0[1] + bf_hi(ts.x));
        zp[2] = dd * (acc0[2] + bf_lo(ts.y)); zp[3] = dd * (acc0[3] + bf_hi(ts.y));
        zp[4] = dd * (acc0[4] + bf_lo(ts.z)); zp[5] = dd * (acc0[5] + bf_hi(ts.z));
        zp[6] = dd * (acc0[6] + bf_lo(ts.w)); zp[7] = dd * (acc0[7] + bf_hi(ts.w));
      }
      if (has1) {
        float dd = dis[d1];
        uint4 ts = T4[(size_t)d1 * 8 + cg];
        float* zp = &zs[(ni + 1) * 65 + cg * 8];
        zp[0] = dd * (acc1[0] + bf_lo(ts.x)); zp[1] = dd * (acc1[1] + bf_hi(ts.x));
        zp[2] = dd * (acc1[2] + bf_lo(ts.y)); zp[3] = dd * (acc1[3] + bf_hi(ts.y));
        zp[4] = dd * (acc1[4] + bf_lo(ts.z)); zp[5] = dd * (acc1[5] + bf_hi(ts.z));
        zp[6] = dd * (acc1[6] + bf_lo(ts.w)); zp[7] = dd * (acc1[7] + bf_hi(ts.w));
      }
    }
  }
  __syncthreads();

  // ---- phase 2: 64x64 W-multiply, lane = row, scalar (SMEM) W loads ----
  int c0 = __builtin_amdgcn_readfirstlane(wid) * 16;
  int row = node0 + lane;
  float acc[16];
#pragma unroll
  for (int c = 0; c < 16; ++c) acc[c] = 0.f;
#pragma unroll 4
  for (int k = 0; k < 64; ++k) {
    float zk = zs[lane * 65 + k];
#pragma unroll
    for (int c = 0; c < 16; ++c)
      acc[c] = fmaf(zk, W[k * 64 + c0 + c], acc[c]);
  }
  if (row >= n) return;
  float res[16];
  size_t rb = (size_t)row * 16 + (c0 >> 2);  // float4 index into [N][64]
  if (MODE == CGD) {
#pragma unroll
    for (int q = 0; q < 4; ++q) {
      float4 xv = ((const float4*)X)[rb + q];
      res[q * 4 + 0] = xv.x + acc[q * 4 + 0] + bias[c0 + q * 4 + 0];
      res[q * 4 + 1] = xv.y + acc[q * 4 + 1] + bias[c0 + q * 4 + 1];
      res[q * 4 + 2] = xv.z + acc[q * 4 + 2] + bias[c0 + q * 4 + 2];
      res[q * 4 + 3] = xv.w + acc[q * 4 + 3] + bias[c0 + q * 4 + 3];
    }
  } else if (MODE == CG0) {
#pragma unroll
    for (int c = 0; c < 16; ++c) res[c] = fmaxf(acc[c] + bias[c0 + c], 0.f);
#pragma unroll
    for (int q = 0; q < 4; ++q)
      ((float4*)X)[rb + q] = {res[q * 4], res[q * 4 + 1], res[q * 4 + 2], res[q * 4 + 3]};
  } else {  // CGR / CGRL
#pragma unroll
    for (int q = 0; q < 4; ++q) {
      float4 rv = ((const float4*)R)[rb + q];
      float v0 = acc[q * 4 + 0] + bias[c0 + q * 4 + 0] + rv.x;
      float v1 = acc[q * 4 + 1] + bias[c0 + q * 4 + 1] + rv.y;
      float v2 = acc[q * 4 + 2] + bias[c0 + q * 4 + 2] + rv.z;
      float v3 = acc[q * 4 + 3] + bias[c0 + q * 4 + 3] + rv.w;
      if (MODE == CGR) ((float4*)R)[rb + q] = {v0, v1, v2, v3};
      res[q * 4 + 0] = fmaxf(v0, 0.f);
      res[q * 4 + 1] = fmaxf(v1, 0.f);
      res[q * 4 + 2] = fmaxf(v2, 0.f);
      res[q * 4 + 3] = fmaxf(v3, 0.f);
      ((float4*)X)[rb + q] = {res[q * 4], res[q * 4 + 1], res[q * 4 + 2], res[q * 4 + 3]};
    }
  }
  if (MODE != CGRL) {
    float sc = dis[row];
    uint4 t0 = {pack_bf16(sc * res[0], sc * res[1]), pack_bf16(sc * res[2], sc * res[3]),
                pack_bf16(sc * res[4], sc * res[5]), pack_bf16(sc * res[6], sc * res[7])};
    uint4 t1 = {pack_bf16(sc * res[8], sc * res[9]), pack_bf16(sc * res[10], sc * res[11]),
                pack_bf16(sc * res[12], sc * res[13]), pack_bf16(sc * res[14], sc * res[15])};
    ((uint4*)Tout)[(size_t)row * 8 + (c0 >> 3)] = t0;
    ((uint4*)Tout)[(size_t)row * 8 + (c0 >> 3) + 1] = t1;
  }
}

// ------------------------------- final linear ------------------------------

__global__ __launch_bounds__(256) void k_fc(
    const float* __restrict__ X, const float* __restrict__ W,
    const float* __restrict__ b, float* __restrict__ out, int n) {
  __shared__ float Wl[640];
  __shared__ float bl[10];
  for (int i = threadIdx.x; i < 640; i += 256) Wl[i] = W[i];
  if (threadIdx.x < 10) bl[threadIdx.x] = b[threadIdx.x];
  __syncthreads();
  int r = blockIdx.x * blockDim.x + threadIdx.x;
  if (r >= n) return;
  float acc[10];
#pragma unroll
  for (int c = 0; c < 10; ++c) acc[c] = bl[c];
#pragma unroll
  for (int k = 0; k < 64; ++k) {
    float xv = X[(size_t)r * 64 + k];
#pragma unroll
    for (int c = 0; c < 10; ++c) acc[c] = fmaf(xv, Wl[k * 10 + c], acc[c]);
  }
#pragma unroll
  for (int c = 0; c < 10; ++c) out[(size_t)r * 10 + c] = acc[c];
}

// --------------------------------- launch ----------------------------------

extern "C" void kernel_launch(void* const* d_in, const int* in_sizes, int n_in,
                              void* d_out, int out_size, void* d_ws, size_t ws_size,
                              hipStream_t stream) {
  const float* x_in  = (const float*)d_in[0];
  const int*   ei    = (const int*)d_in[1];
  const float* gatW  = (const float*)d_in[2];
  const float* gatAs = (const float*)d_in[3];
  const float* gatAd = (const float*)d_in[4];
  const float* gatB  = (const float*)d_in[5];
  const float* gcnW  = (const float*)d_in[6];
  const float* gcnB  = (const float*)d_in[7];
  const float* fcW   = (const float*)d_in[8];
  const float* fcB   = (const float*)d_in[9];
  float* out = (float*)d_out;

  const int N = in_sizes[0] / 64;
  const int E = in_sizes[1] / 2;
  const int NB = (N + RNGB - 1) >> BSH;
  const int chunk = (E + GEB - 1) / GEB;

  char* ws = (char*)d_ws;
  size_t o = 0;
  auto alloc = [&](size_t bytes) -> char* {
    char* p = ws + o;
    o = (o + bytes + 255) & ~(size_t)255;
    return p;
  };
  int* offA    = (int*)alloc((size_t)(N + 1) * 4);
  int* offB    = (int*)alloc((size_t)(N + 1) * 4);
  float* dis   = (float*)alloc((size_t)N * 4);
  int* idxA    = (int*)alloc((size_t)E * 4);
  int* idxB    = (int*)alloc((size_t)E * 4);
  int2* pairsA = (int2*)alloc((size_t)E * 8);
  int2* pairsB = (int2*)alloc((size_t)E * 8);
  int* gHistA  = (int*)alloc((size_t)GEB * NB * 4);
  int* gHistB  = (int*)alloc((size_t)GEB * NB * 4);
  int* totA    = (int*)alloc((size_t)NB * 4);
  int* totB    = (int*)alloc((size_t)NB * 4);
  int* baseA   = (int*)alloc((size_t)NB * 4);
  int* baseB   = (int*)alloc((size_t)NB * 4);
  float* al    = (float*)alloc((size_t)N * 16 * 4);
  u32* B0      = (u32*)alloc((size_t)N * 32 * 4);   // bf16 table [N][64]
  u32* B1      = (u32*)alloc((size_t)N * 32 * 4);   // bf16 table [N][64]
  float* X     = (float*)alloc((size_t)N * 64 * 4);
  float* R     = (float*)alloc((size_t)N * 64 * 4);

  int nbN = (N + 255) / 256;
  int nbAgg = (N + 7) / 8;
  int nbG = (N + 63) / 64;

  // ---- CSR build: bucketed counting sort ----
  k_hist<<<GEB, 256, 0, stream>>>(ei, E, NB, chunk, gHistA, gHistB);
  k_colscan<<<NB, GEB, 0, stream>>>(gHistA, totA, NB);
  k_colscan<<<NB, GEB, 0, stream>>>(gHistB, totB, NB);
  k_bscan<<<1, 1024, 0, stream>>>(totA, totB, baseA, baseB, offA, offB, NB, N, E);
  k_scatter<<<GEB, 256, 0, stream>>>(ei, E, NB, chunk, gHistA, gHistB,
                                     baseA, baseB, pairsA, pairsB);
  k_bucket<0><<<NB, 256, 0, stream>>>(pairsA, baseA, totA, offA, idxA, nullptr, N);
  k_bucket<1><<<NB, 256, 0, stream>>>(pairsB, baseB, totB, offB, idxB, dis, N);

  // ---- random walk: 5 steps (fp32 in -> bf16 ping-pong), result in B0 ----
  k_rw<1><<<nbAgg, 256, 0, stream>>>(offA, idxA, x_in, nullptr, B0, N);
  k_rw<0><<<nbAgg, 256, 0, stream>>>(offA, idxA, nullptr, B0, B1, N);
  k_rw<0><<<nbAgg, 256, 0, stream>>>(offA, idxA, nullptr, B1, B0, N);
  k_rw<0><<<nbAgg, 256, 0, stream>>>(offA, idxA, nullptr, B0, B1, N);
  k_rw<0><<<nbAgg, 256, 0, stream>>>(offA, idxA, nullptr, B1, B0, N);

  // ---- GAT ----
  k_gat_gemm<<<nbG, 256, 0, stream>>>(B0, gatW, gatAs, gatAd, B1, al, N);
  k_gat_agg<<<nbAgg, 256, 0, stream>>>(offB, idxB, B1, al, gatB, dis, B0, R, N);

  // ---- residual GCN: fused conv kernels, tables ping-pong B0/B1 ----
  u32* Tc = B0;
  u32* Ta = B1;
  for (int i = 0; i < 12; ++i) {
    if (i == 0)
      k_conv<CG0><<<nbG, 256, 0, stream>>>(offB, idxB, Tc, Ta, dis,
                                           gcnW, gcnB, nullptr, X, N);
    else if (i == 11)
      k_conv<CGRL><<<nbG, 256, 0, stream>>>(offB, idxB, Tc, nullptr, dis,
                                            gcnW + i * 4096, gcnB + i * 64, R, X, N);
    else
      k_conv<CGR><<<nbG, 256, 0, stream>>>(offB, idxB, Tc, Ta, dis,
                                           gcnW + i * 4096, gcnB + i * 64, R, X, N);
    { u32* t = Tc; Tc = Ta; Ta = t; }
    if (i < 11) {
      int j = (i == 0) ? 11 : i - 1;
      k_conv<CGD><<<nbG, 256, 0, stream>>>(offB, idxB, Tc, Ta, dis,
                                           gcnW + j * 4096, gcnB + j * 64, nullptr, X, N);
      u32* t = Tc; Tc = Ta; Ta = t;
    }
  }

  // ---- final linear ----
  k_fc<<<nbN, 256, 0, stream>>>(X, fcW, fcB, out, N);
}

// Round 13
// 1767.784 us; speedup vs baseline: 1.1152x; 1.0531x over previous
//
#include <hip/hip_runtime.h>

// ---------------------------------------------------------------------------
// LRA_GNN: random-walk -> 8-head GAT -> 12-layer residual GCN -> FC.
// Round 13: REVERT to r9 split design (best: 1776us) — fused conv (r11/r12)
// and sorted adjacency (r10) all regressed; aggs are at the per-XCD
// compulsory-fill floor (~100MB per agg at 3.35 TB/s fabric rate).
// One change vs r9: k_gat_agg uses ONLINE single-pass softmax (running max,
// lane-local rescale, (m,den,acc)-merging reduce) — removes the entire
// pass-1 al gather (~51MB fill).
// ---------------------------------------------------------------------------

typedef unsigned int u32;

#define BSH 7              // bucket shift: 128 nodes per bucket
#define RNGB 128           // nodes per bucket
#define GEB 256            // edge-pass blocks

__device__ __forceinline__ float lrelu(float v) { return v > 0.f ? v : 0.2f * v; }
__device__ __forceinline__ float bf_lo(u32 w) { return __uint_as_float(w << 16); }
__device__ __forceinline__ float bf_hi(u32 w) { return __uint_as_float(w & 0xffff0000u); }
__device__ __forceinline__ u32 pack_bf16(float a, float b) {
  u32 ua = __float_as_uint(a); ua = ua + 0x7fffu + ((ua >> 16) & 1u);
  u32 ub = __float_as_uint(b); ub = ub + 0x7fffu + ((ub >> 16) & 1u);
  return (ua >> 16) | (ub & 0xffff0000u);
}
__device__ __forceinline__ void acc8(float* acc, uint4 q) {
  acc[0] += bf_lo(q.x); acc[1] += bf_hi(q.x);
  acc[2] += bf_lo(q.y); acc[3] += bf_hi(q.y);
  acc[4] += bf_lo(q.z); acc[5] += bf_hi(q.z);
  acc[6] += bf_lo(q.w); acc[7] += bf_hi(q.w);
}
__device__ __forceinline__ void fma8(float* acc, float p, uint4 q) {
  acc[0] = fmaf(p, bf_lo(q.x), acc[0]); acc[1] = fmaf(p, bf_hi(q.x), acc[1]);
  acc[2] = fmaf(p, bf_lo(q.y), acc[2]); acc[3] = fmaf(p, bf_hi(q.y), acc[3]);
  acc[4] = fmaf(p, bf_lo(q.z), acc[4]); acc[5] = fmaf(p, bf_hi(q.z), acc[5]);
  acc[6] = fmaf(p, bf_lo(q.w), acc[6]); acc[7] = fmaf(p, bf_hi(q.w), acc[7]);
}

// --------------------- CSR build via bucketed counting sort ----------------

__global__ __launch_bounds__(256) void k_hist(
    const int* __restrict__ ei, int E, int NB, int chunk,
    int* __restrict__ gHistA, int* __restrict__ gHistB) {
  __shared__ int hA[1024], hB[1024];
  for (int i = threadIdx.x; i < NB; i += 256) { hA[i] = 0; hB[i] = 0; }
  __syncthreads();
  int e0 = blockIdx.x * chunk;
  int e1 = min(E, e0 + chunk);
  for (int e = e0 + threadIdx.x; e < e1; e += 256) {
    int s = ei[e], d = ei[E + e];
    atomicAdd(&hA[s >> BSH], 1);
    atomicAdd(&hB[d >> BSH], 1);
  }
  __syncthreads();
  for (int i = threadIdx.x; i < NB; i += 256) {
    gHistA[blockIdx.x * NB + i] = hA[i];
    gHistB[blockIdx.x * NB + i] = hB[i];
  }
}

__global__ __launch_bounds__(256) void k_colscan(
    int* __restrict__ gHist, int* __restrict__ tot, int NB) {
  __shared__ int s[GEB];
  int b = blockIdx.x;
  int t = threadIdx.x;
  int v = gHist[t * NB + b];
  s[t] = v;
  __syncthreads();
  for (int d = 1; d < GEB; d <<= 1) {
    int u = (t >= d) ? s[t - d] : 0;
    __syncthreads();
    s[t] += u;
    __syncthreads();
  }
  gHist[t * NB + b] = s[t] - v;
  if (t == GEB - 1) tot[b] = s[t];
}

__global__ __launch_bounds__(1024) void k_bscan(
    const int* __restrict__ totA, const int* __restrict__ totB,
    int* __restrict__ baseA, int* __restrict__ baseB,
    int* __restrict__ offA, int* __restrict__ offB, int NB, int N, int E) {
  __shared__ int sa[1024], sb[1024];
  int t = threadIdx.x;
  int va = (t < NB) ? totA[t] : 0;
  int vb = (t < NB) ? totB[t] : 0;
  sa[t] = va; sb[t] = vb;
  __syncthreads();
  for (int d = 1; d < 1024; d <<= 1) {
    int ua = (t >= d) ? sa[t - d] : 0;
    int ub = (t >= d) ? sb[t - d] : 0;
    __syncthreads();
    sa[t] += ua; sb[t] += ub;
    __syncthreads();
  }
  if (t < NB) { baseA[t] = sa[t] - va; baseB[t] = sb[t] - vb; }
  if (t == 0) { offA[N] = E; offB[N] = E; }
}

__global__ __launch_bounds__(256) void k_scatter(
    const int* __restrict__ ei, int E, int NB, int chunk,
    const int* __restrict__ gHistA, const int* __restrict__ gHistB,
    const int* __restrict__ baseA, const int* __restrict__ baseB,
    int2* __restrict__ pairsA, int2* __restrict__ pairsB) {
  __shared__ int cA[1024], cB[1024];
  int g = blockIdx.x;
  for (int i = threadIdx.x; i < NB; i += 256) {
    cA[i] = baseA[i] + gHistA[g * NB + i];
    cB[i] = baseB[i] + gHistB[g * NB + i];
  }
  __syncthreads();
  int e0 = g * chunk;
  int e1 = min(E, e0 + chunk);
  for (int e = e0 + threadIdx.x; e < e1; e += 256) {
    int s = ei[e], d = ei[E + e];
    int pa = atomicAdd(&cA[s >> BSH], 1);
    pairsA[pa] = {s, d};
    int pb = atomicAdd(&cB[d >> BSH], 1);
    pairsB[pb] = {s, d};
  }
}

template <int KEY>
__global__ __launch_bounds__(256) void k_bucket(
    const int2* __restrict__ pairs, const int* __restrict__ base,
    const int* __restrict__ tot, int* __restrict__ off,
    int* __restrict__ idx, float* __restrict__ dis, int N) {
  __shared__ int cnt[RNGB], pfx[RNGB];
  int b = blockIdx.x;
  int node0 = b << BSH;
  int rng = min(RNGB, N - node0);
  int bstart = base[b], bcount = tot[b];
  for (int i = threadIdx.x; i < rng; i += 256) cnt[i] = 0;
  __syncthreads();
  for (int i = threadIdx.x; i < bcount; i += 256) {
    int2 p = pairs[bstart + i];
    int loc = (KEY == 0 ? p.x : p.y) - node0;
    atomicAdd(&cnt[loc], 1);
  }
  __syncthreads();
  if (threadIdx.x == 0) {
    int run = 0;
    for (int i = 0; i < rng; ++i) { pfx[i] = run; run += cnt[i]; }
  }
  __syncthreads();
  for (int i = threadIdx.x; i < rng; i += 256) {
    off[node0 + i] = bstart + pfx[i];
    if (KEY == 1) dis[node0 + i] = rsqrtf((float)(cnt[i] + 1));
  }
  __syncthreads();
  for (int i = threadIdx.x; i < bcount; i += 256) {
    int2 p = pairs[bstart + i];
    int loc = (KEY == 0 ? p.x : p.y) - node0;
    int pos = bstart + atomicAdd(&pfx[loc], 1);
    idx[pos] = (KEY == 0 ? p.y : p.x);
  }
}

// --------------------------------- GEMMs -----------------------------------

__global__ __launch_bounds__(256) void k_gemm64(
    const float* __restrict__ X, const float* __restrict__ W,
    const float* __restrict__ dis, u32* __restrict__ Hb, int n) {
  __shared__ float Xs[64 * 65];
  int row0 = blockIdx.x * 64;
  for (int t = threadIdx.x; t < 1024; t += 256) {
    int r = t >> 4, k4 = t & 15;
    int row = row0 + r;
    float4 v = (row < n) ? ((const float4*)X)[(size_t)row * 16 + k4]
                         : float4{0.f, 0.f, 0.f, 0.f};
    float* dst = &Xs[r * 65 + k4 * 4];
    dst[0] = v.x; dst[1] = v.y; dst[2] = v.z; dst[3] = v.w;
  }
  __syncthreads();
  int lane = threadIdx.x & 63;
  int w = __builtin_amdgcn_readfirstlane(threadIdx.x >> 6);
  int c0 = w * 16;
  int row = row0 + lane;
  float acc[16];
#pragma unroll
  for (int c = 0; c < 16; ++c) acc[c] = 0.f;
#pragma unroll 4
  for (int k = 0; k < 64; ++k) {
    float xk = Xs[lane * 65 + k];
#pragma unroll
    for (int c = 0; c < 16; ++c)
      acc[c] = fmaf(xk, W[k * 64 + c0 + c], acc[c]);
  }
  if (row >= n) return;
  float sc = dis[row];
  uint4* H4 = (uint4*)Hb;
  uint4 o0 = {pack_bf16(acc[0] * sc, acc[1] * sc), pack_bf16(acc[2] * sc, acc[3] * sc),
              pack_bf16(acc[4] * sc, acc[5] * sc), pack_bf16(acc[6] * sc, acc[7] * sc)};
  uint4 o1 = {pack_bf16(acc[8] * sc, acc[9] * sc), pack_bf16(acc[10] * sc, acc[11] * sc),
              pack_bf16(acc[12] * sc, acc[13] * sc), pack_bf16(acc[14] * sc, acc[15] * sc)};
  H4[(size_t)row * 8 + w * 2] = o0;
  H4[(size_t)row * 8 + w * 2 + 1] = o1;
}

__global__ __launch_bounds__(256) void k_gat_gemm(
    const u32* __restrict__ Xb, const float* __restrict__ W,
    const float* __restrict__ asrc, const float* __restrict__ adst,
    u32* __restrict__ Hgb, float* __restrict__ al, int n) {
  __shared__ float Xs[64 * 65];
  int row0 = blockIdx.x * 64;
  for (int t = threadIdx.x; t < 512; t += 256) {
    int r = t >> 3, k8 = t & 7;
    int row = row0 + r;
    uint4 xw = (row < n) ? ((const uint4*)Xb)[(size_t)row * 8 + k8]
                         : uint4{0u, 0u, 0u, 0u};
    float* dst = &Xs[r * 65 + k8 * 8];
    dst[0] = bf_lo(xw.x); dst[1] = bf_hi(xw.x);
    dst[2] = bf_lo(xw.y); dst[3] = bf_hi(xw.y);
    dst[4] = bf_lo(xw.z); dst[5] = bf_hi(xw.z);
    dst[6] = bf_lo(xw.w); dst[7] = bf_hi(xw.w);
  }
  __syncthreads();
  int lane = threadIdx.x & 63;
  int w = __builtin_amdgcn_readfirstlane(threadIdx.x >> 6);
  int c0 = w * 16;
  int row = row0 + lane;
  float acc[16];
#pragma unroll
  for (int c = 0; c < 16; ++c) acc[c] = 0.f;
#pragma unroll 4
  for (int k = 0; k < 64; ++k) {
    float xk = Xs[lane * 65 + k];
#pragma unroll
    for (int c = 0; c < 16; ++c) {
      int gc = c0 + c;
      acc[c] = fmaf(xk, W[(gc >> 3) * 512 + k * 8 + (gc & 7)], acc[c]);
    }
  }
  if (row >= n) return;
  float s1a = 0.f, s2a = 0.f, s1b = 0.f, s2b = 0.f;
#pragma unroll
  for (int cc = 0; cc < 8; ++cc) {
    s1a = fmaf(acc[cc], asrc[c0 + cc], s1a);
    s2a = fmaf(acc[cc], adst[c0 + cc], s2a);
    s1b = fmaf(acc[8 + cc], asrc[c0 + 8 + cc], s1b);
    s2b = fmaf(acc[8 + cc], adst[c0 + 8 + cc], s2b);
  }
  float2* al2 = (float2*)al;
  al2[(size_t)row * 8 + w] = {s1a, s1b};
  al2[(size_t)row * 8 + 4 + w] = {s2a, s2b};
  uint4* H4 = (uint4*)Hgb;
  uint4 o0 = {pack_bf16(acc[0], acc[1]), pack_bf16(acc[2], acc[3]),
              pack_bf16(acc[4], acc[5]), pack_bf16(acc[6], acc[7])};
  uint4 o1 = {pack_bf16(acc[8], acc[9]), pack_bf16(acc[10], acc[11]),
              pack_bf16(acc[12], acc[13]), pack_bf16(acc[14], acc[15])};
  H4[(size_t)row * 8 + w * 2] = o0;
  H4[(size_t)row * 8 + w * 2 + 1] = o1;
}

// ------------------------------ aggregations -------------------------------

enum { MODE_RW1 = 0, MODE_RW = 1, MODE_G0 = 2, MODE_GR = 3, MODE_GD = 4 };

// Two destination nodes per wave (d0=even, d1=odd). lane = (rg 0..7, cg 0..7).
template <int MODE>
__global__ __launch_bounds__(256) void k_agg(
    const int* __restrict__ off, const int* __restrict__ idx,
    const float* __restrict__ Hf, const u32* __restrict__ Hb,
    const float* __restrict__ dis, const float* __restrict__ bias,
    float* __restrict__ R, float* __restrict__ Xf, u32* __restrict__ Xb,
    int n) {
  int lane = threadIdx.x & 63;
  int wid = threadIdx.x >> 6;
  int d0 = blockIdx.x * 8 + wid * 2;
  if (d0 >= n) return;
  int d1 = d0 + 1;
  bool has1 = d1 < n;
  int rg = lane >> 3, cg = lane & 7;
  const uint4* H4b = (const uint4*)Hb;
  const float4* H4f = (const float4*)Hf;
  int beg0 = off[d0], end0 = off[d0 + 1];
  int beg1 = has1 ? off[d1] : 0, end1 = has1 ? off[d1 + 1] : 0;
  int cnt0 = end0 - beg0, cnt1 = end1 - beg1;
  int cmax = cnt0 > cnt1 ? cnt0 : cnt1;
  float acc0[8], acc1[8];
#pragma unroll
  for (int i = 0; i < 8; ++i) { acc0[i] = 0.f; acc1[i] = 0.f; }
  for (int base = 0; base < cmax; base += 64) {
    int c0 = cnt0 - base; if (c0 > 64) c0 = 64;
    int c1 = cnt1 - base; if (c1 > 64) c1 = 64;
    int sidx0 = (lane < c0) ? idx[beg0 + base + lane] : -1;
    int sidx1 = (lane < c1) ? idx[beg1 + base + lane] : -1;
    int hi = c0 > c1 ? c0 : c1;
    int nI = (hi + 7) >> 3;
    int j = 0;
    for (; j + 2 <= nI; j += 2) {
      int s00 = __shfl(sidx0, j * 8 + rg, 64);
      int s01 = __shfl(sidx0, j * 8 + 8 + rg, 64);
      int s10 = __shfl(sidx1, j * 8 + rg, 64);
      int s11 = __shfl(sidx1, j * 8 + 8 + rg, 64);
      size_t a00 = (size_t)(s00 >= 0 ? s00 : 0);
      size_t a01 = (size_t)(s01 >= 0 ? s01 : 0);
      size_t a10 = (size_t)(s10 >= 0 ? s10 : 0);
      size_t a11 = (size_t)(s11 >= 0 ? s11 : 0);
      if (MODE == MODE_RW1) {
        float4 x00 = H4f[a00 * 16 + cg * 2], y00 = H4f[a00 * 16 + cg * 2 + 1];
        float4 x01 = H4f[a01 * 16 + cg * 2], y01 = H4f[a01 * 16 + cg * 2 + 1];
        float4 x10 = H4f[a10 * 16 + cg * 2], y10 = H4f[a10 * 16 + cg * 2 + 1];
        float4 x11 = H4f[a11 * 16 + cg * 2], y11 = H4f[a11 * 16 + cg * 2 + 1];
        if (s00 < 0) { x00 = {0,0,0,0}; y00 = {0,0,0,0}; }
        if (s01 < 0) { x01 = {0,0,0,0}; y01 = {0,0,0,0}; }
        if (s10 < 0) { x10 = {0,0,0,0}; y10 = {0,0,0,0}; }
        if (s11 < 0) { x11 = {0,0,0,0}; y11 = {0,0,0,0}; }
        acc0[0] += x00.x; acc0[1] += x00.y; acc0[2] += x00.z; acc0[3] += x00.w;
        acc0[4] += y00.x; acc0[5] += y00.y; acc0[6] += y00.z; acc0[7] += y00.w;
        acc0[0] += x01.x; acc0[1] += x01.y; acc0[2] += x01.z; acc0[3] += x01.w;
        acc0[4] += y01.x; acc0[5] += y01.y; acc0[6] += y01.z; acc0[7] += y01.w;
        acc1[0] += x10.x; acc1[1] += x10.y; acc1[2] += x10.z; acc1[3] += x10.w;
        acc1[4] += y10.x; acc1[5] += y10.y; acc1[6] += y10.z; acc1[7] += y10.w;
        acc1[0] += x11.x; acc1[1] += x11.y; acc1[2] += x11.z; acc1[3] += x11.w;
        acc1[4] += y11.x; acc1[5] += y11.y; acc1[6] += y11.z; acc1[7] += y11.w;
      } else {
        uint4 q00 = H4b[a00 * 8 + cg];
        uint4 q01 = H4b[a01 * 8 + cg];
        uint4 q10 = H4b[a10 * 8 + cg];
        uint4 q11 = H4b[a11 * 8 + cg];
        if (s00 < 0) q00 = {0u,0u,0u,0u};
        if (s01 < 0) q01 = {0u,0u,0u,0u};
        if (s10 < 0) q10 = {0u,0u,0u,0u};
        if (s11 < 0) q11 = {0u,0u,0u,0u};
        acc8(acc0, q00);
        acc8(acc0, q01);
        acc8(acc1, q10);
        acc8(acc1, q11);
      }
    }
    if (j < nI) {
      int s00 = __shfl(sidx0, j * 8 + rg, 64);
      int s10 = __shfl(sidx1, j * 8 + rg, 64);
      size_t a00 = (size_t)(s00 >= 0 ? s00 : 0);
      size_t a10 = (size_t)(s10 >= 0 ? s10 : 0);
      if (MODE == MODE_RW1) {
        float4 x00 = H4f[a00 * 16 + cg * 2], y00 = H4f[a00 * 16 + cg * 2 + 1];
        float4 x10 = H4f[a10 * 16 + cg * 2], y10 = H4f[a10 * 16 + cg * 2 + 1];
        if (s00 < 0) { x00 = {0,0,0,0}; y00 = {0,0,0,0}; }
        if (s10 < 0) { x10 = {0,0,0,0}; y10 = {0,0,0,0}; }
        acc0[0] += x00.x; acc0[1] += x00.y; acc0[2] += x00.z; acc0[3] += x00.w;
        acc0[4] += y00.x; acc0[5] += y00.y; acc0[6] += y00.z; acc0[7] += y00.w;
        acc1[0] += x10.x; acc1[1] += x10.y; acc1[2] += x10.z; acc1[3] += x10.w;
        acc1[4] += y10.x; acc1[5] += y10.y; acc1[6] += y10.z; acc1[7] += y10.w;
      } else {
        uint4 q00 = H4b[a00 * 8 + cg];
        uint4 q10 = H4b[a10 * 8 + cg];
        if (s00 < 0) q00 = {0u,0u,0u,0u};
        if (s10 < 0) q10 = {0u,0u,0u,0u};
        acc8(acc0, q00);
        acc8(acc1, q10);
      }
    }
  }
#pragma unroll
  for (int m = 8; m < 64; m <<= 1)
#pragma unroll
    for (int i = 0; i < 8; ++i) {
      acc0[i] += __shfl_xor(acc0[i], m, 64);
      acc1[i] += __shfl_xor(acc1[i], m, 64);
    }
  if (rg != 0) return;
#pragma unroll
  for (int nd = 0; nd < 2; ++nd) {
    int d = nd == 0 ? d0 : d1;
    if (nd == 1 && !has1) break;
    float* acc = nd == 0 ? acc0 : acc1;
    if (MODE == MODE_RW1 || MODE == MODE_RW) {
      uint4 o = {pack_bf16(acc[0], acc[1]), pack_bf16(acc[2], acc[3]),
                 pack_bf16(acc[4], acc[5]), pack_bf16(acc[6], acc[7])};
      ((uint4*)Xb)[(size_t)d * 8 + cg] = o;
      continue;
    }
    float ddv = dis[d];
    uint4 hw = H4b[(size_t)d * 8 + cg];
    float hs[8] = {bf_lo(hw.x), bf_hi(hw.x), bf_lo(hw.y), bf_hi(hw.y),
                   bf_lo(hw.z), bf_hi(hw.z), bf_lo(hw.w), bf_hi(hw.w)};
    float4 b0 = ((const float4*)bias)[cg * 2];
    float4 b1 = ((const float4*)bias)[cg * 2 + 1];
    float bv[8] = {b0.x, b0.y, b0.z, b0.w, b1.x, b1.y, b1.z, b1.w};
    float v[8];
#pragma unroll
    for (int i = 0; i < 8; ++i) v[i] = ddv * (acc[i] + hs[i]) + bv[i];
    float4* X4 = (float4*)Xf;
    size_t o0 = (size_t)d * 16 + cg * 2;
    if (MODE == MODE_GR) {
      float4* R4 = (float4*)R;
      float4 r0 = R4[o0], r1 = R4[o0 + 1];
      v[0] += r0.x; v[1] += r0.y; v[2] += r0.z; v[3] += r0.w;
      v[4] += r1.x; v[5] += r1.y; v[6] += r1.z; v[7] += r1.w;
      R4[o0] = {v[0], v[1], v[2], v[3]};
      R4[o0 + 1] = {v[4], v[5], v[6], v[7]};
      X4[o0] = {fmaxf(v[0], 0.f), fmaxf(v[1], 0.f), fmaxf(v[2], 0.f), fmaxf(v[3], 0.f)};
      X4[o0 + 1] = {fmaxf(v[4], 0.f), fmaxf(v[5], 0.f), fmaxf(v[6], 0.f), fmaxf(v[7], 0.f)};
    } else if (MODE == MODE_GD) {
      float4 x0 = X4[o0], x1 = X4[o0 + 1];
      X4[o0] = {x0.x + v[0], x0.y + v[1], x0.z + v[2], x0.w + v[3]};
      X4[o0 + 1] = {x1.x + v[4], x1.y + v[5], x1.z + v[6], x1.w + v[7]};
    } else {  // MODE_G0
      X4[o0] = {fmaxf(v[0], 0.f), fmaxf(v[1], 0.f), fmaxf(v[2], 0.f), fmaxf(v[3], 0.f)};
      X4[o0 + 1] = {fmaxf(v[4], 0.f), fmaxf(v[5], 0.f), fmaxf(v[6], 0.f), fmaxf(v[7], 0.f)};
    }
  }
}

// GAT softmax aggregation: ONLINE single-pass softmax, two nodes per wave.
__global__ __launch_bounds__(256) void k_gat_agg(
    const int* __restrict__ off, const int* __restrict__ idx,
    const u32* __restrict__ Hgb, const float* __restrict__ al,
    const float* __restrict__ bias, float* __restrict__ X,
    float* __restrict__ R, int n) {
  int lane = threadIdx.x & 63;
  int wid = threadIdx.x >> 6;
  int d0 = blockIdx.x * 8 + wid * 2;
  if (d0 >= n) return;
  int d1 = d0 + 1;
  bool has1 = d1 < n;
  int rg = lane >> 3, cg = lane & 7;
  const uint4* H4b = (const uint4*)Hgb;
  float ald0 = al[(size_t)d0 * 16 + 8 + cg];
  float es0 = lrelu(al[(size_t)d0 * 16 + cg] + ald0);
  float ald1 = has1 ? al[(size_t)d1 * 16 + 8 + cg] : 0.f;
  float es1 = has1 ? lrelu(al[(size_t)d1 * 16 + cg] + ald1) : 0.f;
  int beg0 = off[d0], end0 = off[d0 + 1];
  int beg1 = has1 ? off[d1] : 0, end1 = has1 ? off[d1 + 1] : 0;
  int cnt0 = end0 - beg0, cnt1 = end1 - beg1;
  int cmax = cnt0 > cnt1 ? cnt0 : cnt1;
  const float NEG = -3.0e38f;
  float m0 = es0, m1 = es1;        // running max (per-lane; self as floor)
  float den0 = 0.f, den1 = 0.f;
  float acc0[8], acc1[8];
#pragma unroll
  for (int i = 0; i < 8; ++i) { acc0[i] = 0.f; acc1[i] = 0.f; }
  for (int base = 0; base < cmax; base += 64) {
    int c0 = cnt0 - base; if (c0 > 64) c0 = 64;
    int c1 = cnt1 - base; if (c1 > 64) c1 = 64;
    int sidx0 = (lane < c0) ? idx[beg0 + base + lane] : -1;
    int sidx1 = (lane < c1) ? idx[beg1 + base + lane] : -1;
    int hi = c0 > c1 ? c0 : c1;
    int nI = (hi + 7) >> 3;
    int j = 0;
    for (; j + 2 <= nI; j += 2) {
      int s00 = __shfl(sidx0, j * 8 + rg, 64);
      int s01 = __shfl(sidx0, j * 8 + 8 + rg, 64);
      int s10 = __shfl(sidx1, j * 8 + rg, 64);
      int s11 = __shfl(sidx1, j * 8 + 8 + rg, 64);
      size_t a00 = (size_t)(s00 >= 0 ? s00 : 0);
      size_t a01 = (size_t)(s01 >= 0 ? s01 : 0);
      size_t a10 = (size_t)(s10 >= 0 ? s10 : 0);
      size_t a11 = (size_t)(s11 >= 0 ? s11 : 0);
      float l00 = al[a00 * 16 + cg];
      float l01 = al[a01 * 16 + cg];
      float l10 = al[a10 * 16 + cg];
      float l11 = al[a11 * 16 + cg];
      uint4 q00 = H4b[a00 * 8 + cg];
      uint4 q01 = H4b[a01 * 8 + cg];
      uint4 q10 = H4b[a10 * 8 + cg];
      uint4 q11 = H4b[a11 * 8 + cg];
      float e00 = (s00 >= 0) ? lrelu(l00 + ald0) : NEG;
      float e01 = (s01 >= 0) ? lrelu(l01 + ald0) : NEG;
      float e10 = (s10 >= 0) ? lrelu(l10 + ald1) : NEG;
      float e11 = (s11 >= 0) ? lrelu(l11 + ald1) : NEG;
      float ml0 = fmaxf(e00, e01);
      if (ml0 > m0) {
        float sc = __expf(m0 - ml0);
        den0 *= sc;
#pragma unroll
        for (int i = 0; i < 8; ++i) acc0[i] *= sc;
        m0 = ml0;
      }
      float p00 = (s00 >= 0) ? __expf(e00 - m0) : 0.f;
      float p01 = (s01 >= 0) ? __expf(e01 - m0) : 0.f;
      den0 += p00; fma8(acc0, p00, q00);
      den0 += p01; fma8(acc0, p01, q01);
      float ml1 = fmaxf(e10, e11);
      if (ml1 > m1) {
        float sc = __expf(m1 - ml1);
        den1 *= sc;
#pragma unroll
        for (int i = 0; i < 8; ++i) acc1[i] *= sc;
        m1 = ml1;
      }
      float p10 = (s10 >= 0) ? __expf(e10 - m1) : 0.f;
      float p11 = (s11 >= 0) ? __expf(e11 - m1) : 0.f;
      den1 += p10; fma8(acc1, p10, q10);
      den1 += p11; fma8(acc1, p11, q11);
    }
    if (j < nI) {
      int s00 = __shfl(sidx0, j * 8 + rg, 64);
      int s10 = __shfl(sidx1, j * 8 + rg, 64);
      size_t a00 = (size_t)(s00 >= 0 ? s00 : 0);
      size_t a10 = (size_t)(s10 >= 0 ? s10 : 0);
      float l00 = al[a00 * 16 + cg];
      float l10 = al[a10 * 16 + cg];
      uint4 q00 = H4b[a00 * 8 + cg];
      uint4 q10 = H4b[a10 * 8 + cg];
      float e00 = (s00 >= 0) ? lrelu(l00 + ald0) : NEG;
      float e10 = (s10 >= 0) ? lrelu(l10 + ald1) : NEG;
      if (e00 > m0) {
        float sc = __expf(m0 - e00);
        den0 *= sc;
#pragma unroll
        for (int i = 0; i < 8; ++i) acc0[i] *= sc;
        m0 = e00;
      }
      float p00 = (s00 >= 0) ? __expf(e00 - m0) : 0.f;
      den0 += p00; fma8(acc0, p00, q00);
      if (e10 > m1) {
        float sc = __expf(m1 - e10);
        den1 *= sc;
#pragma unroll
        for (int i = 0; i < 8; ++i) acc1[i] *= sc;
        m1 = e10;
      }
      float p10 = (s10 >= 0) ? __expf(e10 - m1) : 0.f;
      den1 += p10; fma8(acc1, p10, q10);
    }
  }
  // cross-lane merge of (m, den, acc) across rowgroups (xor 8,16,32)
#pragma unroll
  for (int mm = 8; mm < 64; mm <<= 1) {
    float mo0 = __shfl_xor(m0, mm, 64);
    float do0 = __shfl_xor(den0, mm, 64);
    float mo1 = __shfl_xor(m1, mm, 64);
    float do1 = __shfl_xor(den1, mm, 64);
    float ao0[8], ao1[8];
#pragma unroll
    for (int i = 0; i < 8; ++i) {
      ao0[i] = __shfl_xor(acc0[i], mm, 64);
      ao1[i] = __shfl_xor(acc1[i], mm, 64);
    }
    float mn0 = fmaxf(m0, mo0);
    float sA0 = __expf(m0 - mn0), sB0 = __expf(mo0 - mn0);
    den0 = den0 * sA0 + do0 * sB0;
#pragma unroll
    for (int i = 0; i < 8; ++i) acc0[i] = acc0[i] * sA0 + ao0[i] * sB0;
    m0 = mn0;
    float mn1 = fmaxf(m1, mo1);
    float sA1 = __expf(m1 - mn1), sB1 = __expf(mo1 - mn1);
    den1 = den1 * sA1 + do1 * sB1;
#pragma unroll
    for (int i = 0; i < 8; ++i) acc1[i] = acc1[i] * sA1 + ao1[i] * sB1;
    m1 = mn1;
  }
  if (rg != 0) return;
#pragma unroll
  for (int nd = 0; nd < 2; ++nd) {
    if (nd == 1 && !has1) break;
    int d = nd == 0 ? d0 : d1;
    float* acc = nd == 0 ? acc0 : acc1;
    float es = nd == 0 ? es0 : es1;
    float m = nd == 0 ? m0 : m1;
    float den = nd == 0 ? den0 : den1;
    float pself = __expf(es - m);   // m >= es by construction
    uint4 hw = H4b[(size_t)d * 8 + cg];
    float hs[8] = {bf_lo(hw.x), bf_hi(hw.x), bf_lo(hw.y), bf_hi(hw.y),
                   bf_lo(hw.z), bf_hi(hw.z), bf_lo(hw.w), bf_hi(hw.w)};
#pragma unroll
    for (int i = 0; i < 8; ++i) acc[i] = fmaf(pself, hs[i], acc[i]);
    den += pself;
    float inv = 1.f / den;
    float4 b0 = ((const float4*)bias)[cg * 2];
    float4 b1 = ((const float4*)bias)[cg * 2 + 1];
    float bv[8] = {b0.x, b0.y, b0.z, b0.w, b1.x, b1.y, b1.z, b1.w};
    float v[8];
#pragma unroll
    for (int i = 0; i < 8; ++i) v[i] = acc[i] * inv + bv[i];
    size_t o0 = (size_t)d * 16 + cg * 2;
    ((float4*)X)[o0] = {v[0], v[1], v[2], v[3]};
    ((float4*)X)[o0 + 1] = {v[4], v[5], v[6], v[7]};
    ((float4*)R)[o0] = {v[0], v[1], v[2], v[3]};
    ((float4*)R)[o0 + 1] = {v[4], v[5], v[6], v[7]};
  }
}

// ------------------------------- final linear ------------------------------

__global__ __launch_bounds__(256) void k_fc(
    const float* __restrict__ X, const float* __restrict__ W,
    const float* __restrict__ b, float* __restrict__ out, int n) {
  __shared__ float Wl[640];
  __shared__ float bl[10];
  for (int i = threadIdx.x; i < 640; i += 256) Wl[i] = W[i];
  if (threadIdx.x < 10) bl[threadIdx.x] = b[threadIdx.x];
  __syncthreads();
  int r = blockIdx.x * blockDim.x + threadIdx.x;
  if (r >= n) return;
  float acc[10];
#pragma unroll
  for (int c = 0; c < 10; ++c) acc[c] = bl[c];
#pragma unroll
  for (int k = 0; k < 64; ++k) {
    float xv = X[(size_t)r * 64 + k];
#pragma unroll
    for (int c = 0; c < 10; ++c) acc[c] = fmaf(xv, Wl[k * 10 + c], acc[c]);
  }
#pragma unroll
  for (int c = 0; c < 10; ++c) out[(size_t)r * 10 + c] = acc[c];
}

// --------------------------------- launch ----------------------------------

extern "C" void kernel_launch(void* const* d_in, const int* in_sizes, int n_in,
                              void* d_out, int out_size, void* d_ws, size_t ws_size,
                              hipStream_t stream) {
  const float* x_in  = (const float*)d_in[0];
  const int*   ei    = (const int*)d_in[1];
  const float* gatW  = (const float*)d_in[2];
  const float* gatAs = (const float*)d_in[3];
  const float* gatAd = (const float*)d_in[4];
  const float* gatB  = (const float*)d_in[5];
  const float* gcnW  = (const float*)d_in[6];
  const float* gcnB  = (const float*)d_in[7];
  const float* fcW   = (const float*)d_in[8];
  const float* fcB   = (const float*)d_in[9];
  float* out = (float*)d_out;

  const int N = in_sizes[0] / 64;
  const int E = in_sizes[1] / 2;
  const int NB = (N + RNGB - 1) >> BSH;
  const int chunk = (E + GEB - 1) / GEB;

  char* ws = (char*)d_ws;
  size_t o = 0;
  auto alloc = [&](size_t bytes) -> char* {
    char* p = ws + o;
    o = (o + bytes + 255) & ~(size_t)255;
    return p;
  };
  int* offA    = (int*)alloc((size_t)(N + 1) * 4);
  int* offB    = (int*)alloc((size_t)(N + 1) * 4);
  float* dis   = (float*)alloc((size_t)N * 4);
  int* idxA    = (int*)alloc((size_t)E * 4);
  int* idxB    = (int*)alloc((size_t)E * 4);
  int2* pairsA = (int2*)alloc((size_t)E * 8);
  int2* pairsB = (int2*)alloc((size_t)E * 8);
  int* gHistA  = (int*)alloc((size_t)GEB * NB * 4);
  int* gHistB  = (int*)alloc((size_t)GEB * NB * 4);
  int* totA    = (int*)alloc((size_t)NB * 4);
  int* totB    = (int*)alloc((size_t)NB * 4);
  int* baseA   = (int*)alloc((size_t)NB * 4);
  int* baseB   = (int*)alloc((size_t)NB * 4);
  float* al    = (float*)alloc((size_t)N * 16 * 4);
  u32* B0      = (u32*)alloc((size_t)N * 32 * 4);
  u32* B1      = (u32*)alloc((size_t)N * 32 * 4);
  float* X     = (float*)alloc((size_t)N * 64 * 4);
  float* R     = (float*)alloc((size_t)N * 64 * 4);

  int nbN = (N + 255) / 256;
  int nbAgg = (N + 7) / 8;
  int nbG = (N + 63) / 64;

  // ---- CSR build: bucketed counting sort ----
  k_hist<<<GEB, 256, 0, stream>>>(ei, E, NB, chunk, gHistA, gHistB);
  k_colscan<<<NB, GEB, 0, stream>>>(gHistA, totA, NB);
  k_colscan<<<NB, GEB, 0, stream>>>(gHistB, totB, NB);
  k_bscan<<<1, 1024, 0, stream>>>(totA, totB, baseA, baseB, offA, offB, NB, N, E);
  k_scatter<<<GEB, 256, 0, stream>>>(ei, E, NB, chunk, gHistA, gHistB,
                                     baseA, baseB, pairsA, pairsB);
  k_bucket<0><<<NB, 256, 0, stream>>>(pairsA, baseA, totA, offA, idxA, nullptr, N);
  k_bucket<1><<<NB, 256, 0, stream>>>(pairsB, baseB, totB, offB, idxB, dis, N);

  // ---- random walk: 5 steps (fp32 in -> bf16 ping-pong) ----
  k_agg<MODE_RW1><<<nbAgg, 256, 0, stream>>>(offA, idxA, x_in, nullptr, nullptr, nullptr, nullptr, nullptr, B0, N);
  k_agg<MODE_RW><<<nbAgg, 256, 0, stream>>>(offA, idxA, nullptr, B0, nullptr, nullptr, nullptr, nullptr, B1, N);
  k_agg<MODE_RW><<<nbAgg, 256, 0, stream>>>(offA, idxA, nullptr, B1, nullptr, nullptr, nullptr, nullptr, B0, N);
  k_agg<MODE_RW><<<nbAgg, 256, 0, stream>>>(offA, idxA, nullptr, B0, nullptr, nullptr, nullptr, nullptr, B1, N);
  k_agg<MODE_RW><<<nbAgg, 256, 0, stream>>>(offA, idxA, nullptr, B1, nullptr, nullptr, nullptr, nullptr, B0, N);

  // ---- GAT ----
  k_gat_gemm<<<nbG, 256, 0, stream>>>(B0, gatW, gatAs, gatAd, B1, al, N);
  k_gat_agg<<<nbAgg, 256, 0, stream>>>(offB, idxB, B1, al, gatB, X, R, N);

  // ---- residual GCN ----
  for (int i = 0; i < 12; ++i) {
    k_gemm64<<<nbG, 256, 0, stream>>>(X, gcnW + i * 4096, dis, B0, N);
    if (i == 0)
      k_agg<MODE_G0><<<nbAgg, 256, 0, stream>>>(offB, idxB, nullptr, B0, dis, gcnB + i * 64, nullptr, X, nullptr, N);
    else
      k_agg<MODE_GR><<<nbAgg, 256, 0, stream>>>(offB, idxB, nullptr, B0, dis, gcnB + i * 64, R, X, nullptr, N);
    if (i < 11) {
      int j = (i == 0) ? 11 : i - 1;
      k_gemm64<<<nbG, 256, 0, stream>>>(X, gcnW + j * 4096, dis, B0, N);
      k_agg<MODE_GD><<<nbAgg, 256, 0, stream>>>(offB, idxB, nullptr, B0, dis, gcnB + j * 64, nullptr, X, nullptr, N);
    }
  }

  // ---- final linear ----
  k_fc<<<nbN, 256, 0, stream>>>(X, fcW, fcB, out, N);
}

// Round 14
// 1739.728 us; speedup vs baseline: 1.1331x; 1.0161x over previous
//
#include <hip/hip_runtime.h>

// ---------------------------------------------------------------------------
// LRA_GNN: random-walk -> 8-head GAT -> 12-layer residual GCN -> FC.
// Round 14: eliminate redundant fp32 X traffic. GR-mode aggs write only R
// (pre-relu); consumers recompute relu(R): GD-conv GEMM reads R+relu during
// LDS staging (SRC_RRELU), GD agg epilogue reads relu(R), k_fc applies relu.
// Bit-exact vs r13 (same fp32 value, relu recomputed). Saves ~300MB writes.
// Base: r13 (split kernels, online-softmax GAT, 2-node/wave aggs).
// ---------------------------------------------------------------------------

typedef unsigned int u32;

#define BSH 7              // bucket shift: 128 nodes per bucket
#define RNGB 128           // nodes per bucket
#define GEB 256            // edge-pass blocks

__device__ __forceinline__ float lrelu(float v) { return v > 0.f ? v : 0.2f * v; }
__device__ __forceinline__ float bf_lo(u32 w) { return __uint_as_float(w << 16); }
__device__ __forceinline__ float bf_hi(u32 w) { return __uint_as_float(w & 0xffff0000u); }
__device__ __forceinline__ u32 pack_bf16(float a, float b) {
  u32 ua = __float_as_uint(a); ua = ua + 0x7fffu + ((ua >> 16) & 1u);
  u32 ub = __float_as_uint(b); ub = ub + 0x7fffu + ((ub >> 16) & 1u);
  return (ua >> 16) | (ub & 0xffff0000u);
}
__device__ __forceinline__ void acc8(float* acc, uint4 q) {
  acc[0] += bf_lo(q.x); acc[1] += bf_hi(q.x);
  acc[2] += bf_lo(q.y); acc[3] += bf_hi(q.y);
  acc[4] += bf_lo(q.z); acc[5] += bf_hi(q.z);
  acc[6] += bf_lo(q.w); acc[7] += bf_hi(q.w);
}
__device__ __forceinline__ void fma8(float* acc, float p, uint4 q) {
  acc[0] = fmaf(p, bf_lo(q.x), acc[0]); acc[1] = fmaf(p, bf_hi(q.x), acc[1]);
  acc[2] = fmaf(p, bf_lo(q.y), acc[2]); acc[3] = fmaf(p, bf_hi(q.y), acc[3]);
  acc[4] = fmaf(p, bf_lo(q.z), acc[4]); acc[5] = fmaf(p, bf_hi(q.z), acc[5]);
  acc[6] = fmaf(p, bf_lo(q.w), acc[6]); acc[7] = fmaf(p, bf_hi(q.w), acc[7]);
}

// --------------------- CSR build via bucketed counting sort ----------------

__global__ __launch_bounds__(256) void k_hist(
    const int* __restrict__ ei, int E, int NB, int chunk,
    int* __restrict__ gHistA, int* __restrict__ gHistB) {
  __shared__ int hA[1024], hB[1024];
  for (int i = threadIdx.x; i < NB; i += 256) { hA[i] = 0; hB[i] = 0; }
  __syncthreads();
  int e0 = blockIdx.x * chunk;
  int e1 = min(E, e0 + chunk);
  for (int e = e0 + threadIdx.x; e < e1; e += 256) {
    int s = ei[e], d = ei[E + e];
    atomicAdd(&hA[s >> BSH], 1);
    atomicAdd(&hB[d >> BSH], 1);
  }
  __syncthreads();
  for (int i = threadIdx.x; i < NB; i += 256) {
    gHistA[blockIdx.x * NB + i] = hA[i];
    gHistB[blockIdx.x * NB + i] = hB[i];
  }
}

__global__ __launch_bounds__(256) void k_colscan(
    int* __restrict__ gHist, int* __restrict__ tot, int NB) {
  __shared__ int s[GEB];
  int b = blockIdx.x;
  int t = threadIdx.x;
  int v = gHist[t * NB + b];
  s[t] = v;
  __syncthreads();
  for (int d = 1; d < GEB; d <<= 1) {
    int u = (t >= d) ? s[t - d] : 0;
    __syncthreads();
    s[t] += u;
    __syncthreads();
  }
  gHist[t * NB + b] = s[t] - v;
  if (t == GEB - 1) tot[b] = s[t];
}

__global__ __launch_bounds__(1024) void k_bscan(
    const int* __restrict__ totA, const int* __restrict__ totB,
    int* __restrict__ baseA, int* __restrict__ baseB,
    int* __restrict__ offA, int* __restrict__ offB, int NB, int N, int E) {
  __shared__ int sa[1024], sb[1024];
  int t = threadIdx.x;
  int va = (t < NB) ? totA[t] : 0;
  int vb = (t < NB) ? totB[t] : 0;
  sa[t] = va; sb[t] = vb;
  __syncthreads();
  for (int d = 1; d < 1024; d <<= 1) {
    int ua = (t >= d) ? sa[t - d] : 0;
    int ub = (t >= d) ? sb[t - d] : 0;
    __syncthreads();
    sa[t] += ua; sb[t] += ub;
    __syncthreads();
  }
  if (t < NB) { baseA[t] = sa[t] - va; baseB[t] = sb[t] - vb; }
  if (t == 0) { offA[N] = E; offB[N] = E; }
}

__global__ __launch_bounds__(256) void k_scatter(
    const int* __restrict__ ei, int E, int NB, int chunk,
    const int* __restrict__ gHistA, const int* __restrict__ gHistB,
    const int* __restrict__ baseA, const int* __restrict__ baseB,
    int2* __restrict__ pairsA, int2* __restrict__ pairsB) {
  __shared__ int cA[1024], cB[1024];
  int g = blockIdx.x;
  for (int i = threadIdx.x; i < NB; i += 256) {
    cA[i] = baseA[i] + gHistA[g * NB + i];
    cB[i] = baseB[i] + gHistB[g * NB + i];
  }
  __syncthreads();
  int e0 = g * chunk;
  int e1 = min(E, e0 + chunk);
  for (int e = e0 + threadIdx.x; e < e1; e += 256) {
    int s = ei[e], d = ei[E + e];
    int pa = atomicAdd(&cA[s >> BSH], 1);
    pairsA[pa] = {s, d};
    int pb = atomicAdd(&cB[d >> BSH], 1);
    pairsB[pb] = {s, d};
  }
}

template <int KEY>
__global__ __launch_bounds__(256) void k_bucket(
    const int2* __restrict__ pairs, const int* __restrict__ base,
    const int* __restrict__ tot, int* __restrict__ off,
    int* __restrict__ idx, float* __restrict__ dis, int N) {
  __shared__ int cnt[RNGB], pfx[RNGB];
  int b = blockIdx.x;
  int node0 = b << BSH;
  int rng = min(RNGB, N - node0);
  int bstart = base[b], bcount = tot[b];
  for (int i = threadIdx.x; i < rng; i += 256) cnt[i] = 0;
  __syncthreads();
  for (int i = threadIdx.x; i < bcount; i += 256) {
    int2 p = pairs[bstart + i];
    int loc = (KEY == 0 ? p.x : p.y) - node0;
    atomicAdd(&cnt[loc], 1);
  }
  __syncthreads();
  if (threadIdx.x == 0) {
    int run = 0;
    for (int i = 0; i < rng; ++i) { pfx[i] = run; run += cnt[i]; }
  }
  __syncthreads();
  for (int i = threadIdx.x; i < rng; i += 256) {
    off[node0 + i] = bstart + pfx[i];
    if (KEY == 1) dis[node0 + i] = rsqrtf((float)(cnt[i] + 1));
  }
  __syncthreads();
  for (int i = threadIdx.x; i < bcount; i += 256) {
    int2 p = pairs[bstart + i];
    int loc = (KEY == 0 ? p.x : p.y) - node0;
    int pos = bstart + atomicAdd(&pfx[loc], 1);
    idx[pos] = (KEY == 0 ? p.y : p.x);
  }
}

// --------------------------------- GEMMs -----------------------------------

// SRC==0: read X directly. SRC==1: read R, apply relu during LDS staging.
template <int SRC>
__global__ __launch_bounds__(256) void k_gemm64(
    const float* __restrict__ X, const float* __restrict__ W,
    const float* __restrict__ dis, u32* __restrict__ Hb, int n) {
  __shared__ float Xs[64 * 65];
  int row0 = blockIdx.x * 64;
  for (int t = threadIdx.x; t < 1024; t += 256) {
    int r = t >> 4, k4 = t & 15;
    int row = row0 + r;
    float4 v = (row < n) ? ((const float4*)X)[(size_t)row * 16 + k4]
                         : float4{0.f, 0.f, 0.f, 0.f};
    if (SRC == 1) {
      v.x = fmaxf(v.x, 0.f); v.y = fmaxf(v.y, 0.f);
      v.z = fmaxf(v.z, 0.f); v.w = fmaxf(v.w, 0.f);
    }
    float* dst = &Xs[r * 65 + k4 * 4];
    dst[0] = v.x; dst[1] = v.y; dst[2] = v.z; dst[3] = v.w;
  }
  __syncthreads();
  int lane = threadIdx.x & 63;
  int w = __builtin_amdgcn_readfirstlane(threadIdx.x >> 6);
  int c0 = w * 16;
  int row = row0 + lane;
  float acc[16];
#pragma unroll
  for (int c = 0; c < 16; ++c) acc[c] = 0.f;
#pragma unroll 4
  for (int k = 0; k < 64; ++k) {
    float xk = Xs[lane * 65 + k];
#pragma unroll
    for (int c = 0; c < 16; ++c)
      acc[c] = fmaf(xk, W[k * 64 + c0 + c], acc[c]);
  }
  if (row >= n) return;
  float sc = dis[row];
  uint4* H4 = (uint4*)Hb;
  uint4 o0 = {pack_bf16(acc[0] * sc, acc[1] * sc), pack_bf16(acc[2] * sc, acc[3] * sc),
              pack_bf16(acc[4] * sc, acc[5] * sc), pack_bf16(acc[6] * sc, acc[7] * sc)};
  uint4 o1 = {pack_bf16(acc[8] * sc, acc[9] * sc), pack_bf16(acc[10] * sc, acc[11] * sc),
              pack_bf16(acc[12] * sc, acc[13] * sc), pack_bf16(acc[14] * sc, acc[15] * sc)};
  H4[(size_t)row * 8 + w * 2] = o0;
  H4[(size_t)row * 8 + w * 2 + 1] = o1;
}

__global__ __launch_bounds__(256) void k_gat_gemm(
    const u32* __restrict__ Xb, const float* __restrict__ W,
    const float* __restrict__ asrc, const float* __restrict__ adst,
    u32* __restrict__ Hgb, float* __restrict__ al, int n) {
  __shared__ float Xs[64 * 65];
  int row0 = blockIdx.x * 64;
  for (int t = threadIdx.x; t < 512; t += 256) {
    int r = t >> 3, k8 = t & 7;
    int row = row0 + r;
    uint4 xw = (row < n) ? ((const uint4*)Xb)[(size_t)row * 8 + k8]
                         : uint4{0u, 0u, 0u, 0u};
    float* dst = &Xs[r * 65 + k8 * 8];
    dst[0] = bf_lo(xw.x); dst[1] = bf_hi(xw.x);
    dst[2] = bf_lo(xw.y); dst[3] = bf_hi(xw.y);
    dst[4] = bf_lo(xw.z); dst[5] = bf_hi(xw.z);
    dst[6] = bf_lo(xw.w); dst[7] = bf_hi(xw.w);
  }
  __syncthreads();
  int lane = threadIdx.x & 63;
  int w = __builtin_amdgcn_readfirstlane(threadIdx.x >> 6);
  int c0 = w * 16;
  int row = row0 + lane;
  float acc[16];
#pragma unroll
  for (int c = 0; c < 16; ++c) acc[c] = 0.f;
#pragma unroll 4
  for (int k = 0; k < 64; ++k) {
    float xk = Xs[lane * 65 + k];
#pragma unroll
    for (int c = 0; c < 16; ++c) {
      int gc = c0 + c;
      acc[c] = fmaf(xk, W[(gc >> 3) * 512 + k * 8 + (gc & 7)], acc[c]);
    }
  }
  if (row >= n) return;
  float s1a = 0.f, s2a = 0.f, s1b = 0.f, s2b = 0.f;
#pragma unroll
  for (int cc = 0; cc < 8; ++cc) {
    s1a = fmaf(acc[cc], asrc[c0 + cc], s1a);
    s2a = fmaf(acc[cc], adst[c0 + cc], s2a);
    s1b = fmaf(acc[8 + cc], asrc[c0 + 8 + cc], s1b);
    s2b = fmaf(acc[8 + cc], adst[c0 + 8 + cc], s2b);
  }
  float2* al2 = (float2*)al;
  al2[(size_t)row * 8 + w] = {s1a, s1b};
  al2[(size_t)row * 8 + 4 + w] = {s2a, s2b};
  uint4* H4 = (uint4*)Hgb;
  uint4 o0 = {pack_bf16(acc[0], acc[1]), pack_bf16(acc[2], acc[3]),
              pack_bf16(acc[4], acc[5]), pack_bf16(acc[6], acc[7])};
  uint4 o1 = {pack_bf16(acc[8], acc[9]), pack_bf16(acc[10], acc[11]),
              pack_bf16(acc[12], acc[13]), pack_bf16(acc[14], acc[15])};
  H4[(size_t)row * 8 + w * 2] = o0;
  H4[(size_t)row * 8 + w * 2 + 1] = o1;
}

// ------------------------------ aggregations -------------------------------

// MODE_RW1: fp32 gather -> bf16 out. MODE_RW: bf16 gather -> bf16 out.
// MODE_G0: x=relu(val) -> X. MODE_GR: val+=R, R=val (NO X write).
// MODE_GD_X: X += val (X read).  MODE_GD_R: X = relu(R) + val (R read).
enum { MODE_RW1 = 0, MODE_RW = 1, MODE_G0 = 2, MODE_GR = 3,
       MODE_GD_X = 4, MODE_GD_R = 5 };

template <int MODE>
__global__ __launch_bounds__(256) void k_agg(
    const int* __restrict__ off, const int* __restrict__ idx,
    const float* __restrict__ Hf, const u32* __restrict__ Hb,
    const float* __restrict__ dis, const float* __restrict__ bias,
    float* __restrict__ R, float* __restrict__ Xf, u32* __restrict__ Xb,
    int n) {
  int lane = threadIdx.x & 63;
  int wid = threadIdx.x >> 6;
  int d0 = blockIdx.x * 8 + wid * 2;
  if (d0 >= n) return;
  int d1 = d0 + 1;
  bool has1 = d1 < n;
  int rg = lane >> 3, cg = lane & 7;
  const uint4* H4b = (const uint4*)Hb;
  const float4* H4f = (const float4*)Hf;
  int beg0 = off[d0], end0 = off[d0 + 1];
  int beg1 = has1 ? off[d1] : 0, end1 = has1 ? off[d1 + 1] : 0;
  int cnt0 = end0 - beg0, cnt1 = end1 - beg1;
  int cmax = cnt0 > cnt1 ? cnt0 : cnt1;
  float acc0[8], acc1[8];
#pragma unroll
  for (int i = 0; i < 8; ++i) { acc0[i] = 0.f; acc1[i] = 0.f; }
  for (int base = 0; base < cmax; base += 64) {
    int c0 = cnt0 - base; if (c0 > 64) c0 = 64;
    int c1 = cnt1 - base; if (c1 > 64) c1 = 64;
    int sidx0 = (lane < c0) ? idx[beg0 + base + lane] : -1;
    int sidx1 = (lane < c1) ? idx[beg1 + base + lane] : -1;
    int hi = c0 > c1 ? c0 : c1;
    int nI = (hi + 7) >> 3;
    int j = 0;
    for (; j + 2 <= nI; j += 2) {
      int s00 = __shfl(sidx0, j * 8 + rg, 64);
      int s01 = __shfl(sidx0, j * 8 + 8 + rg, 64);
      int s10 = __shfl(sidx1, j * 8 + rg, 64);
      int s11 = __shfl(sidx1, j * 8 + 8 + rg, 64);
      size_t a00 = (size_t)(s00 >= 0 ? s00 : 0);
      size_t a01 = (size_t)(s01 >= 0 ? s01 : 0);
      size_t a10 = (size_t)(s10 >= 0 ? s10 : 0);
      size_t a11 = (size_t)(s11 >= 0 ? s11 : 0);
      if (MODE == MODE_RW1) {
        float4 x00 = H4f[a00 * 16 + cg * 2], y00 = H4f[a00 * 16 + cg * 2 + 1];
        float4 x01 = H4f[a01 * 16 + cg * 2], y01 = H4f[a01 * 16 + cg * 2 + 1];
        float4 x10 = H4f[a10 * 16 + cg * 2], y10 = H4f[a10 * 16 + cg * 2 + 1];
        float4 x11 = H4f[a11 * 16 + cg * 2], y11 = H4f[a11 * 16 + cg * 2 + 1];
        if (s00 < 0) { x00 = {0,0,0,0}; y00 = {0,0,0,0}; }
        if (s01 < 0) { x01 = {0,0,0,0}; y01 = {0,0,0,0}; }
        if (s10 < 0) { x10 = {0,0,0,0}; y10 = {0,0,0,0}; }
        if (s11 < 0) { x11 = {0,0,0,0}; y11 = {0,0,0,0}; }
        acc0[0] += x00.x; acc0[1] += x00.y; acc0[2] += x00.z; acc0[3] += x00.w;
        acc0[4] += y00.x; acc0[5] += y00.y; acc0[6] += y00.z; acc0[7] += y00.w;
        acc0[0] += x01.x; acc0[1] += x01.y; acc0[2] += x01.z; acc0[3] += x01.w;
        acc0[4] += y01.x; acc0[5] += y01.y; acc0[6] += y01.z; acc0[7] += y01.w;
        acc1[0] += x10.x; acc1[1] += x10.y; acc1[2] += x10.z; acc1[3] += x10.w;
        acc1[4] += y10.x; acc1[5] += y10.y; acc1[6] += y10.z; acc1[7] += y10.w;
        acc1[0] += x11.x; acc1[1] += x11.y; acc1[2] += x11.z; acc1[3] += x11.w;
        acc1[4] += y11.x; acc1[5] += y11.y; acc1[6] += y11.z; acc1[7] += y11.w;
      } else {
        uint4 q00 = H4b[a00 * 8 + cg];
        uint4 q01 = H4b[a01 * 8 + cg];
        uint4 q10 = H4b[a10 * 8 + cg];
        uint4 q11 = H4b[a11 * 8 + cg];
        if (s00 < 0) q00 = {0u,0u,0u,0u};
        if (s01 < 0) q01 = {0u,0u,0u,0u};
        if (s10 < 0) q10 = {0u,0u,0u,0u};
        if (s11 < 0) q11 = {0u,0u,0u,0u};
        acc8(acc0, q00);
        acc8(acc0, q01);
        acc8(acc1, q10);
        acc8(acc1, q11);
      }
    }
    if (j < nI) {
      int s00 = __shfl(sidx0, j * 8 + rg, 64);
      int s10 = __shfl(sidx1, j * 8 + rg, 64);
      size_t a00 = (size_t)(s00 >= 0 ? s00 : 0);
      size_t a10 = (size_t)(s10 >= 0 ? s10 : 0);
      if (MODE == MODE_RW1) {
        float4 x00 = H4f[a00 * 16 + cg * 2], y00 = H4f[a00 * 16 + cg * 2 + 1];
        float4 x10 = H4f[a10 * 16 + cg * 2], y10 = H4f[a10 * 16 + cg * 2 + 1];
        if (s00 < 0) { x00 = {0,0,0,0}; y00 = {0,0,0,0}; }
        if (s10 < 0) { x10 = {0,0,0,0}; y10 = {0,0,0,0}; }
        acc0[0] += x00.x; acc0[1] += x00.y; acc0[2] += x00.z; acc0[3] += x00.w;
        acc0[4] += y00.x; acc0[5] += y00.y; acc0[6] += y00.z; acc0[7] += y00.w;
        acc1[0] += x10.x; acc1[1] += x10.y; acc1[2] += x10.z; acc1[3] += x10.w;
        acc1[4] += y10.x; acc1[5] += y10.y; acc1[6] += y10.z; acc1[7] += y10.w;
      } else {
        uint4 q00 = H4b[a00 * 8 + cg];
        uint4 q10 = H4b[a10 * 8 + cg];
        if (s00 < 0) q00 = {0u,0u,0u,0u};
        if (s10 < 0) q10 = {0u,0u,0u,0u};
        acc8(acc0, q00);
        acc8(acc1, q10);
      }
    }
  }
#pragma unroll
  for (int m = 8; m < 64; m <<= 1)
#pragma unroll
    for (int i = 0; i < 8; ++i) {
      acc0[i] += __shfl_xor(acc0[i], m, 64);
      acc1[i] += __shfl_xor(acc1[i], m, 64);
    }
  if (rg != 0) return;
#pragma unroll
  for (int nd = 0; nd < 2; ++nd) {
    int d = nd == 0 ? d0 : d1;
    if (nd == 1 && !has1) break;
    float* acc = nd == 0 ? acc0 : acc1;
    if (MODE == MODE_RW1 || MODE == MODE_RW) {
      uint4 o = {pack_bf16(acc[0], acc[1]), pack_bf16(acc[2], acc[3]),
                 pack_bf16(acc[4], acc[5]), pack_bf16(acc[6], acc[7])};
      ((uint4*)Xb)[(size_t)d * 8 + cg] = o;
      continue;
    }
    float ddv = dis[d];
    uint4 hw = H4b[(size_t)d * 8 + cg];
    float hs[8] = {bf_lo(hw.x), bf_hi(hw.x), bf_lo(hw.y), bf_hi(hw.y),
                   bf_lo(hw.z), bf_hi(hw.z), bf_lo(hw.w), bf_hi(hw.w)};
    float4 b0 = ((const float4*)bias)[cg * 2];
    float4 b1 = ((const float4*)bias)[cg * 2 + 1];
    float bv[8] = {b0.x, b0.y, b0.z, b0.w, b1.x, b1.y, b1.z, b1.w};
    float v[8];
#pragma unroll
    for (int i = 0; i < 8; ++i) v[i] = ddv * (acc[i] + hs[i]) + bv[i];
    float4* X4 = (float4*)Xf;
    float4* R4 = (float4*)R;
    size_t o0 = (size_t)d * 16 + cg * 2;
    if (MODE == MODE_GR) {
      float4 r0 = R4[o0], r1 = R4[o0 + 1];
      v[0] += r0.x; v[1] += r0.y; v[2] += r0.z; v[3] += r0.w;
      v[4] += r1.x; v[5] += r1.y; v[6] += r1.z; v[7] += r1.w;
      R4[o0] = {v[0], v[1], v[2], v[3]};
      R4[o0 + 1] = {v[4], v[5], v[6], v[7]};
      // X intentionally NOT written; consumers use relu(R).
    } else if (MODE == MODE_GD_X) {
      float4 x0 = X4[o0], x1 = X4[o0 + 1];
      X4[o0] = {x0.x + v[0], x0.y + v[1], x0.z + v[2], x0.w + v[3]};
      X4[o0 + 1] = {x1.x + v[4], x1.y + v[5], x1.z + v[6], x1.w + v[7]};
    } else if (MODE == MODE_GD_R) {
      float4 r0 = R4[o0], r1 = R4[o0 + 1];
      X4[o0] = {fmaxf(r0.x, 0.f) + v[0], fmaxf(r0.y, 0.f) + v[1],
                fmaxf(r0.z, 0.f) + v[2], fmaxf(r0.w, 0.f) + v[3]};
      X4[o0 + 1] = {fmaxf(r1.x, 0.f) + v[4], fmaxf(r1.y, 0.f) + v[5],
                    fmaxf(r1.z, 0.f) + v[6], fmaxf(r1.w, 0.f) + v[7]};
    } else {  // MODE_G0
      X4[o0] = {fmaxf(v[0], 0.f), fmaxf(v[1], 0.f), fmaxf(v[2], 0.f), fmaxf(v[3], 0.f)};
      X4[o0 + 1] = {fmaxf(v[4], 0.f), fmaxf(v[5], 0.f), fmaxf(v[6], 0.f), fmaxf(v[7], 0.f)};
    }
  }
}

// GAT softmax aggregation: ONLINE single-pass softmax, two nodes per wave.
__global__ __launch_bounds__(256) void k_gat_agg(
    const int* __restrict__ off, const int* __restrict__ idx,
    const u32* __restrict__ Hgb, const float* __restrict__ al,
    const float* __restrict__ bias, float* __restrict__ X,
    float* __restrict__ R, int n) {
  int lane = threadIdx.x & 63;
  int wid = threadIdx.x >> 6;
  int d0 = blockIdx.x * 8 + wid * 2;
  if (d0 >= n) return;
  int d1 = d0 + 1;
  bool has1 = d1 < n;
  int rg = lane >> 3, cg = lane & 7;
  const uint4* H4b = (const uint4*)Hgb;
  float ald0 = al[(size_t)d0 * 16 + 8 + cg];
  float es0 = lrelu(al[(size_t)d0 * 16 + cg] + ald0);
  float ald1 = has1 ? al[(size_t)d1 * 16 + 8 + cg] : 0.f;
  float es1 = has1 ? lrelu(al[(size_t)d1 * 16 + cg] + ald1) : 0.f;
  int beg0 = off[d0], end0 = off[d0 + 1];
  int beg1 = has1 ? off[d1] : 0, end1 = has1 ? off[d1 + 1] : 0;
  int cnt0 = end0 - beg0, cnt1 = end1 - beg1;
  int cmax = cnt0 > cnt1 ? cnt0 : cnt1;
  const float NEG = -3.0e38f;
  float m0 = es0, m1 = es1;
  float den0 = 0.f, den1 = 0.f;
  float acc0[8], acc1[8];
#pragma unroll
  for (int i = 0; i < 8; ++i) { acc0[i] = 0.f; acc1[i] = 0.f; }
  for (int base = 0; base < cmax; base += 64) {
    int c0 = cnt0 - base; if (c0 > 64) c0 = 64;
    int c1 = cnt1 - base; if (c1 > 64) c1 = 64;
    int sidx0 = (lane < c0) ? idx[beg0 + base + lane] : -1;
    int sidx1 = (lane < c1) ? idx[beg1 + base + lane] : -1;
    int hi = c0 > c1 ? c0 : c1;
    int nI = (hi + 7) >> 3;
    int j = 0;
    for (; j + 2 <= nI; j += 2) {
      int s00 = __shfl(sidx0, j * 8 + rg, 64);
      int s01 = __shfl(sidx0, j * 8 + 8 + rg, 64);
      int s10 = __shfl(sidx1, j * 8 + rg, 64);
      int s11 = __shfl(sidx1, j * 8 + 8 + rg, 64);
      size_t a00 = (size_t)(s00 >= 0 ? s00 : 0);
      size_t a01 = (size_t)(s01 >= 0 ? s01 : 0);
      size_t a10 = (size_t)(s10 >= 0 ? s10 : 0);
      size_t a11 = (size_t)(s11 >= 0 ? s11 : 0);
      float l00 = al[a00 * 16 + cg];
      float l01 = al[a01 * 16 + cg];
      float l10 = al[a10 * 16 + cg];
      float l11 = al[a11 * 16 + cg];
      uint4 q00 = H4b[a00 * 8 + cg];
      uint4 q01 = H4b[a01 * 8 + cg];
      uint4 q10 = H4b[a10 * 8 + cg];
      uint4 q11 = H4b[a11 * 8 + cg];
      float e00 = (s00 >= 0) ? lrelu(l00 + ald0) : NEG;
      float e01 = (s01 >= 0) ? lrelu(l01 + ald0) : NEG;
      float e10 = (s10 >= 0) ? lrelu(l10 + ald1) : NEG;
      float e11 = (s11 >= 0) ? lrelu(l11 + ald1) : NEG;
      float ml0 = fmaxf(e00, e01);
      if (ml0 > m0) {
        float sc = __expf(m0 - ml0);
        den0 *= sc;
#pragma unroll
        for (int i = 0; i < 8; ++i) acc0[i] *= sc;
        m0 = ml0;
      }
      float p00 = (s00 >= 0) ? __expf(e00 - m0) : 0.f;
      float p01 = (s01 >= 0) ? __expf(e01 - m0) : 0.f;
      den0 += p00; fma8(acc0, p00, q00);
      den0 += p01; fma8(acc0, p01, q01);
      float ml1 = fmaxf(e10, e11);
      if (ml1 > m1) {
        float sc = __expf(m1 - ml1);
        den1 *= sc;
#pragma unroll
        for (int i = 0; i < 8; ++i) acc1[i] *= sc;
        m1 = ml1;
      }
      float p10 = (s10 >= 0) ? __expf(e10 - m1) : 0.f;
      float p11 = (s11 >= 0) ? __expf(e11 - m1) : 0.f;
      den1 += p10; fma8(acc1, p10, q10);
      den1 += p11; fma8(acc1, p11, q11);
    }
    if (j < nI) {
      int s00 = __shfl(sidx0, j * 8 + rg, 64);
      int s10 = __shfl(sidx1, j * 8 + rg, 64);
      size_t a00 = (size_t)(s00 >= 0 ? s00 : 0);
      size_t a10 = (size_t)(s10 >= 0 ? s10 : 0);
      float l00 = al[a00 * 16 + cg];
      float l10 = al[a10 * 16 + cg];
      uint4 q00 = H4b[a00 * 8 + cg];
      uint4 q10 = H4b[a10 * 8 + cg];
      float e00 = (s00 >= 0) ? lrelu(l00 + ald0) : NEG;
      float e10 = (s10 >= 0) ? lrelu(l10 + ald1) : NEG;
      if (e00 > m0) {
        float sc = __expf(m0 - e00);
        den0 *= sc;
#pragma unroll
        for (int i = 0; i < 8; ++i) acc0[i] *= sc;
        m0 = e00;
      }
      float p00 = (s00 >= 0) ? __expf(e00 - m0) : 0.f;
      den0 += p00; fma8(acc0, p00, q00);
      if (e10 > m1) {
        float sc = __expf(m1 - e10);
        den1 *= sc;
#pragma unroll
        for (int i = 0; i < 8; ++i) acc1[i] *= sc;
        m1 = e10;
      }
      float p10 = (s10 >= 0) ? __expf(e10 - m1) : 0.f;
      den1 += p10; fma8(acc1, p10, q10);
    }
  }
#pragma unroll
  for (int mm = 8; mm < 64; mm <<= 1) {
    float mo0 = __shfl_xor(m0, mm, 64);
    float do0 = __shfl_xor(den0, mm, 64);
    float mo1 = __shfl_xor(m1, mm, 64);
    float do1 = __shfl_xor(den1, mm, 64);
    float ao0[8], ao1[8];
#pragma unroll
    for (int i = 0; i < 8; ++i) {
      ao0[i] = __shfl_xor(acc0[i], mm, 64);
      ao1[i] = __shfl_xor(acc1[i], mm, 64);
    }
    float mn0 = fmaxf(m0, mo0);
    float sA0 = __expf(m0 - mn0), sB0 = __expf(mo0 - mn0);
    den0 = den0 * sA0 + do0 * sB0;
#pragma unroll
    for (int i = 0; i < 8; ++i) acc0[i] = acc0[i] * sA0 + ao0[i] * sB0;
    m0 = mn0;
    float mn1 = fmaxf(m1, mo1);
    float sA1 = __expf(m1 - mn1), sB1 = __expf(mo1 - mn1);
    den1 = den1 * sA1 + do1 * sB1;
#pragma unroll
    for (int i = 0; i < 8; ++i) acc1[i] = acc1[i] * sA1 + ao1[i] * sB1;
    m1 = mn1;
  }
  if (rg != 0) return;
#pragma unroll
  for (int nd = 0; nd < 2; ++nd) {
    if (nd == 1 && !has1) break;
    int d = nd == 0 ? d0 : d1;
    float* acc = nd == 0 ? acc0 : acc1;
    float es = nd == 0 ? es0 : es1;
    float m = nd == 0 ? m0 : m1;
    float den = nd == 0 ? den0 : den1;
    float pself = __expf(es - m);
    uint4 hw = H4b[(size_t)d * 8 + cg];
    float hs[8] = {bf_lo(hw.x), bf_hi(hw.x), bf_lo(hw.y), bf_hi(hw.y),
                   bf_lo(hw.z), bf_hi(hw.z), bf_lo(hw.w), bf_hi(hw.w)};
#pragma unroll
    for (int i = 0; i < 8; ++i) acc[i] = fmaf(pself, hs[i], acc[i]);
    den += pself;
    float inv = 1.f / den;
    float4 b0 = ((const float4*)bias)[cg * 2];
    float4 b1 = ((const float4*)bias)[cg * 2 + 1];
    float bv[8] = {b0.x, b0.y, b0.z, b0.w, b1.x, b1.y, b1.z, b1.w};
    float v[8];
#pragma unroll
    for (int i = 0; i < 8; ++i) v[i] = acc[i] * inv + bv[i];
    size_t o0 = (size_t)d * 16 + cg * 2;
    ((float4*)X)[o0] = {v[0], v[1], v[2], v[3]};
    ((float4*)X)[o0 + 1] = {v[4], v[5], v[6], v[7]};
    ((float4*)R)[o0] = {v[0], v[1], v[2], v[3]};
    ((float4*)R)[o0 + 1] = {v[4], v[5], v[6], v[7]};
  }
}

// ------------------------------- final linear ------------------------------

// Reads R and applies relu (final x = relu(R_final)).
__global__ __launch_bounds__(256) void k_fc(
    const float* __restrict__ Rm, const float* __restrict__ W,
    const float* __restrict__ b, float* __restrict__ out, int n) {
  __shared__ float Wl[640];
  __shared__ float bl[10];
  for (int i = threadIdx.x; i < 640; i += 256) Wl[i] = W[i];
  if (threadIdx.x < 10) bl[threadIdx.x] = b[threadIdx.x];
  __syncthreads();
  int r = blockIdx.x * blockDim.x + threadIdx.x;
  if (r >= n) return;
  float acc[10];
#pragma unroll
  for (int c = 0; c < 10; ++c) acc[c] = bl[c];
#pragma unroll
  for (int k = 0; k < 64; ++k) {
    float xv = fmaxf(Rm[(size_t)r * 64 + k], 0.f);
#pragma unroll
    for (int c = 0; c < 10; ++c) acc[c] = fmaf(xv, Wl[k * 10 + c], acc[c]);
  }
#pragma unroll
  for (int c = 0; c < 10; ++c) out[(size_t)r * 10 + c] = acc[c];
}

// --------------------------------- launch ----------------------------------

extern "C" void kernel_launch(void* const* d_in, const int* in_sizes, int n_in,
                              void* d_out, int out_size, void* d_ws, size_t ws_size,
                              hipStream_t stream) {
  const float* x_in  = (const float*)d_in[0];
  const int*   ei    = (const int*)d_in[1];
  const float* gatW  = (const float*)d_in[2];
  const float* gatAs = (const float*)d_in[3];
  const float* gatAd = (const float*)d_in[4];
  const float* gatB  = (const float*)d_in[5];
  const float* gcnW  = (const float*)d_in[6];
  const float* gcnB  = (const float*)d_in[7];
  const float* fcW   = (const float*)d_in[8];
  const float* fcB   = (const float*)d_in[9];
  float* out = (float*)d_out;

  const int N = in_sizes[0] / 64;
  const int E = in_sizes[1] / 2;
  const int NB = (N + RNGB - 1) >> BSH;
  const int chunk = (E + GEB - 1) / GEB;

  char* ws = (char*)d_ws;
  size_t o = 0;
  auto alloc = [&](size_t bytes) -> char* {
    char* p = ws + o;
    o = (o + bytes + 255) & ~(size_t)255;
    return p;
  };
  int* offA    = (int*)alloc((size_t)(N + 1) * 4);
  int* offB    = (int*)alloc((size_t)(N + 1) * 4);
  float* dis   = (float*)alloc((size_t)N * 4);
  int* idxA    = (int*)alloc((size_t)E * 4);
  int* idxB    = (int*)alloc((size_t)E * 4);
  int2* pairsA = (int2*)alloc((size_t)E * 8);
  int2* pairsB = (int2*)alloc((size_t)E * 8);
  int* gHistA  = (int*)alloc((size_t)GEB * NB * 4);
  int* gHistB  = (int*)alloc((size_t)GEB * NB * 4);
  int* totA    = (int*)alloc((size_t)NB * 4);
  int* totB    = (int*)alloc((size_t)NB * 4);
  int* baseA   = (int*)alloc((size_t)NB * 4);
  int* baseB   = (int*)alloc((size_t)NB * 4);
  float* al    = (float*)alloc((size_t)N * 16 * 4);
  u32* B0      = (u32*)alloc((size_t)N * 32 * 4);
  u32* B1      = (u32*)alloc((size_t)N * 32 * 4);
  float* X     = (float*)alloc((size_t)N * 64 * 4);
  float* R     = (float*)alloc((size_t)N * 64 * 4);

  int nbN = (N + 255) / 256;
  int nbAgg = (N + 7) / 8;
  int nbG = (N + 63) / 64;

  // ---- CSR build: bucketed counting sort ----
  k_hist<<<GEB, 256, 0, stream>>>(ei, E, NB, chunk, gHistA, gHistB);
  k_colscan<<<NB, GEB, 0, stream>>>(gHistA, totA, NB);
  k_colscan<<<NB, GEB, 0, stream>>>(gHistB, totB, NB);
  k_bscan<<<1, 1024, 0, stream>>>(totA, totB, baseA, baseB, offA, offB, NB, N, E);
  k_scatter<<<GEB, 256, 0, stream>>>(ei, E, NB, chunk, gHistA, gHistB,
                                     baseA, baseB, pairsA, pairsB);
  k_bucket<0><<<NB, 256, 0, stream>>>(pairsA, baseA, totA, offA, idxA, nullptr, N);
  k_bucket<1><<<NB, 256, 0, stream>>>(pairsB, baseB, totB, offB, idxB, dis, N);

  // ---- random walk: 5 steps (fp32 in -> bf16 ping-pong) ----
  k_agg<MODE_RW1><<<nbAgg, 256, 0, stream>>>(offA, idxA, x_in, nullptr, nullptr, nullptr, nullptr, nullptr, B0, N);
  k_agg<MODE_RW><<<nbAgg, 256, 0, stream>>>(offA, idxA, nullptr, B0, nullptr, nullptr, nullptr, nullptr, B1, N);
  k_agg<MODE_RW><<<nbAgg, 256, 0, stream>>>(offA, idxA, nullptr, B1, nullptr, nullptr, nullptr, nullptr, B0, N);
  k_agg<MODE_RW><<<nbAgg, 256, 0, stream>>>(offA, idxA, nullptr, B0, nullptr, nullptr, nullptr, nullptr, B1, N);
  k_agg<MODE_RW><<<nbAgg, 256, 0, stream>>>(offA, idxA, nullptr, B1, nullptr, nullptr, nullptr, nullptr, B0, N);

  // ---- GAT ----
  k_gat_gemm<<<nbG, 256, 0, stream>>>(B0, gatW, gatAs, gatAd, B1, al, N);
  k_gat_agg<<<nbAgg, 256, 0, stream>>>(offB, idxB, B1, al, gatB, X, R, N);

  // ---- residual GCN ----
  // i=0: GEMM<X>(X_gat) -> G0 (writes X). GD j=11: GEMM<X>(X) -> GD_X.
  // i>=1: GEMM<X>(X from GD) -> GR (writes R only).
  //       GD j=i-1: GEMM<RRELU>(R) -> GD_R (X = relu(R) + val).
  for (int i = 0; i < 12; ++i) {
    if (i == 0) {
      k_gemm64<0><<<nbG, 256, 0, stream>>>(X, gcnW, dis, B0, N);
      k_agg<MODE_G0><<<nbAgg, 256, 0, stream>>>(offB, idxB, nullptr, B0, dis, gcnB, nullptr, X, nullptr, N);
    } else {
      k_gemm64<0><<<nbG, 256, 0, stream>>>(X, gcnW + i * 4096, dis, B0, N);
      k_agg<MODE_GR><<<nbAgg, 256, 0, stream>>>(offB, idxB, nullptr, B0, dis, gcnB + i * 64, R, nullptr, nullptr, N);
    }
    if (i < 11) {
      int j = (i == 0) ? 11 : i - 1;
      if (i == 0) {
        k_gemm64<0><<<nbG, 256, 0, stream>>>(X, gcnW + j * 4096, dis, B0, N);
        k_agg<MODE_GD_X><<<nbAgg, 256, 0, stream>>>(offB, idxB, nullptr, B0, dis, gcnB + j * 64, nullptr, X, nullptr, N);
      } else {
        k_gemm64<1><<<nbG, 256, 0, stream>>>(R, gcnW + j * 4096, dis, B0, N);
        k_agg<MODE_GD_R><<<nbAgg, 256, 0, stream>>>(offB, idxB, nullptr, B0, dis, gcnB + j * 64, R, X, nullptr, N);
      }
    }
  }

  // ---- final linear: x = relu(R_final) ----
  k_fc<<<nbN, 256, 0, stream>>>(R, fcW, fcB, out, N);
}

// Round 15
// 1735.764 us; speedup vs baseline: 1.1357x; 1.0023x over previous
//
#include <hip/hip_runtime.h>

// ---------------------------------------------------------------------------
// LRA_GNN: random-walk -> 8-head GAT -> 12-layer residual GCN -> FC.
// Round 15: (a) split GAT logits into alS[N][8] / alD[N][8] — the per-
// neighbor gather touches only the 3.2MB alS table (L2-resident per XCD)
// instead of the interleaved 6.4MB array; bit-exact. (b) merge colscan and
// bucket launch pairs (runtime key), 61 -> 59 dispatches.
// Base: r14 (split kernels, online-softmax GAT, R-only residual chain).
// ---------------------------------------------------------------------------

typedef unsigned int u32;

#define BSH 7              // bucket shift: 128 nodes per bucket
#define RNGB 128           // nodes per bucket
#define GEB 256            // edge-pass blocks

__device__ __forceinline__ float lrelu(float v) { return v > 0.f ? v : 0.2f * v; }
__device__ __forceinline__ float bf_lo(u32 w) { return __uint_as_float(w << 16); }
__device__ __forceinline__ float bf_hi(u32 w) { return __uint_as_float(w & 0xffff0000u); }
__device__ __forceinline__ u32 pack_bf16(float a, float b) {
  u32 ua = __float_as_uint(a); ua = ua + 0x7fffu + ((ua >> 16) & 1u);
  u32 ub = __float_as_uint(b); ub = ub + 0x7fffu + ((ub >> 16) & 1u);
  return (ua >> 16) | (ub & 0xffff0000u);
}
__device__ __forceinline__ void acc8(float* acc, uint4 q) {
  acc[0] += bf_lo(q.x); acc[1] += bf_hi(q.x);
  acc[2] += bf_lo(q.y); acc[3] += bf_hi(q.y);
  acc[4] += bf_lo(q.z); acc[5] += bf_hi(q.z);
  acc[6] += bf_lo(q.w); acc[7] += bf_hi(q.w);
}
__device__ __forceinline__ void fma8(float* acc, float p, uint4 q) {
  acc[0] = fmaf(p, bf_lo(q.x), acc[0]); acc[1] = fmaf(p, bf_hi(q.x), acc[1]);
  acc[2] = fmaf(p, bf_lo(q.y), acc[2]); acc[3] = fmaf(p, bf_hi(q.y), acc[3]);
  acc[4] = fmaf(p, bf_lo(q.z), acc[4]); acc[5] = fmaf(p, bf_hi(q.z), acc[5]);
  acc[6] = fmaf(p, bf_lo(q.w), acc[6]); acc[7] = fmaf(p, bf_hi(q.w), acc[7]);
}

// --------------------- CSR build via bucketed counting sort ----------------

__global__ __launch_bounds__(256) void k_hist(
    const int* __restrict__ ei, int E, int NB, int chunk,
    int* __restrict__ gHistA, int* __restrict__ gHistB) {
  __shared__ int hA[1024], hB[1024];
  for (int i = threadIdx.x; i < NB; i += 256) { hA[i] = 0; hB[i] = 0; }
  __syncthreads();
  int e0 = blockIdx.x * chunk;
  int e1 = min(E, e0 + chunk);
  for (int e = e0 + threadIdx.x; e < e1; e += 256) {
    int s = ei[e], d = ei[E + e];
    atomicAdd(&hA[s >> BSH], 1);
    atomicAdd(&hB[d >> BSH], 1);
  }
  __syncthreads();
  for (int i = threadIdx.x; i < NB; i += 256) {
    gHistA[blockIdx.x * NB + i] = hA[i];
    gHistB[blockIdx.x * NB + i] = hB[i];
  }
}

// merged A/B column scan: grid = 2*NB
__global__ __launch_bounds__(256) void k_colscan(
    int* __restrict__ gHistA, int* __restrict__ totA,
    int* __restrict__ gHistB, int* __restrict__ totB, int NB) {
  __shared__ int s[GEB];
  int b = blockIdx.x;
  int* gHist = (b < NB) ? gHistA : gHistB;
  int* tot = (b < NB) ? totA : totB;
  int col = (b < NB) ? b : b - NB;
  int t = threadIdx.x;
  int v = gHist[t * NB + col];
  s[t] = v;
  __syncthreads();
  for (int d = 1; d < GEB; d <<= 1) {
    int u = (t >= d) ? s[t - d] : 0;
    __syncthreads();
    s[t] += u;
    __syncthreads();
  }
  gHist[t * NB + col] = s[t] - v;
  if (t == GEB - 1) tot[col] = s[t];
}

__global__ __launch_bounds__(1024) void k_bscan(
    const int* __restrict__ totA, const int* __restrict__ totB,
    int* __restrict__ baseA, int* __restrict__ baseB,
    int* __restrict__ offA, int* __restrict__ offB, int NB, int N, int E) {
  __shared__ int sa[1024], sb[1024];
  int t = threadIdx.x;
  int va = (t < NB) ? totA[t] : 0;
  int vb = (t < NB) ? totB[t] : 0;
  sa[t] = va; sb[t] = vb;
  __syncthreads();
  for (int d = 1; d < 1024; d <<= 1) {
    int ua = (t >= d) ? sa[t - d] : 0;
    int ub = (t >= d) ? sb[t - d] : 0;
    __syncthreads();
    sa[t] += ua; sb[t] += ub;
    __syncthreads();
  }
  if (t < NB) { baseA[t] = sa[t] - va; baseB[t] = sb[t] - vb; }
  if (t == 0) { offA[N] = E; offB[N] = E; }
}

__global__ __launch_bounds__(256) void k_scatter(
    const int* __restrict__ ei, int E, int NB, int chunk,
    const int* __restrict__ gHistA, const int* __restrict__ gHistB,
    const int* __restrict__ baseA, const int* __restrict__ baseB,
    int2* __restrict__ pairsA, int2* __restrict__ pairsB) {
  __shared__ int cA[1024], cB[1024];
  int g = blockIdx.x;
  for (int i = threadIdx.x; i < NB; i += 256) {
    cA[i] = baseA[i] + gHistA[g * NB + i];
    cB[i] = baseB[i] + gHistB[g * NB + i];
  }
  __syncthreads();
  int e0 = g * chunk;
  int e1 = min(E, e0 + chunk);
  for (int e = e0 + threadIdx.x; e < e1; e += 256) {
    int s = ei[e], d = ei[E + e];
    int pa = atomicAdd(&cA[s >> BSH], 1);
    pairsA[pa] = {s, d};
    int pb = atomicAdd(&cB[d >> BSH], 1);
    pairsB[pb] = {s, d};
  }
}

// merged A/B bucket finalize: grid = 2*NB (runtime key)
__global__ __launch_bounds__(256) void k_bucket(
    const int2* __restrict__ pairsA, const int2* __restrict__ pairsB,
    const int* __restrict__ baseA, const int* __restrict__ baseB,
    const int* __restrict__ totA, const int* __restrict__ totB,
    int* __restrict__ offA, int* __restrict__ offB,
    int* __restrict__ idxA, int* __restrict__ idxB,
    float* __restrict__ dis, int N, int NB) {
  __shared__ int cnt[RNGB], pfx[RNGB];
  int blk = blockIdx.x;
  int key = (blk >= NB) ? 1 : 0;
  int b = key ? blk - NB : blk;
  const int2* pairs = key ? pairsB : pairsA;
  const int* base = key ? baseB : baseA;
  const int* tot = key ? totB : totA;
  int* off = key ? offB : offA;
  int* idx = key ? idxB : idxA;
  int node0 = b << BSH;
  int rng = min(RNGB, N - node0);
  int bstart = base[b], bcount = tot[b];
  for (int i = threadIdx.x; i < rng; i += 256) cnt[i] = 0;
  __syncthreads();
  for (int i = threadIdx.x; i < bcount; i += 256) {
    int2 p = pairs[bstart + i];
    int loc = (key == 0 ? p.x : p.y) - node0;
    atomicAdd(&cnt[loc], 1);
  }
  __syncthreads();
  if (threadIdx.x == 0) {
    int run = 0;
    for (int i = 0; i < rng; ++i) { pfx[i] = run; run += cnt[i]; }
  }
  __syncthreads();
  for (int i = threadIdx.x; i < rng; i += 256) {
    off[node0 + i] = bstart + pfx[i];
    if (key == 1) dis[node0 + i] = rsqrtf((float)(cnt[i] + 1));
  }
  __syncthreads();
  for (int i = threadIdx.x; i < bcount; i += 256) {
    int2 p = pairs[bstart + i];
    int loc = (key == 0 ? p.x : p.y) - node0;
    int pos = bstart + atomicAdd(&pfx[loc], 1);
    idx[pos] = (key == 0 ? p.y : p.x);
  }
}

// --------------------------------- GEMMs -----------------------------------

// SRC==0: read X directly. SRC==1: read R, apply relu during LDS staging.
template <int SRC>
__global__ __launch_bounds__(256) void k_gemm64(
    const float* __restrict__ X, const float* __restrict__ W,
    const float* __restrict__ dis, u32* __restrict__ Hb, int n) {
  __shared__ float Xs[64 * 65];
  int row0 = blockIdx.x * 64;
  for (int t = threadIdx.x; t < 1024; t += 256) {
    int r = t >> 4, k4 = t & 15;
    int row = row0 + r;
    float4 v = (row < n) ? ((const float4*)X)[(size_t)row * 16 + k4]
                         : float4{0.f, 0.f, 0.f, 0.f};
    if (SRC == 1) {
      v.x = fmaxf(v.x, 0.f); v.y = fmaxf(v.y, 0.f);
      v.z = fmaxf(v.z, 0.f); v.w = fmaxf(v.w, 0.f);
    }
    float* dst = &Xs[r * 65 + k4 * 4];
    dst[0] = v.x; dst[1] = v.y; dst[2] = v.z; dst[3] = v.w;
  }
  __syncthreads();
  int lane = threadIdx.x & 63;
  int w = __builtin_amdgcn_readfirstlane(threadIdx.x >> 6);
  int c0 = w * 16;
  int row = row0 + lane;
  float acc[16];
#pragma unroll
  for (int c = 0; c < 16; ++c) acc[c] = 0.f;
#pragma unroll 4
  for (int k = 0; k < 64; ++k) {
    float xk = Xs[lane * 65 + k];
#pragma unroll
    for (int c = 0; c < 16; ++c)
      acc[c] = fmaf(xk, W[k * 64 + c0 + c], acc[c]);
  }
  if (row >= n) return;
  float sc = dis[row];
  uint4* H4 = (uint4*)Hb;
  uint4 o0 = {pack_bf16(acc[0] * sc, acc[1] * sc), pack_bf16(acc[2] * sc, acc[3] * sc),
              pack_bf16(acc[4] * sc, acc[5] * sc), pack_bf16(acc[6] * sc, acc[7] * sc)};
  uint4 o1 = {pack_bf16(acc[8] * sc, acc[9] * sc), pack_bf16(acc[10] * sc, acc[11] * sc),
              pack_bf16(acc[12] * sc, acc[13] * sc), pack_bf16(acc[14] * sc, acc[15] * sc)};
  H4[(size_t)row * 8 + w * 2] = o0;
  H4[(size_t)row * 8 + w * 2 + 1] = o1;
}

__global__ __launch_bounds__(256) void k_gat_gemm(
    const u32* __restrict__ Xb, const float* __restrict__ W,
    const float* __restrict__ asrc, const float* __restrict__ adst,
    u32* __restrict__ Hgb, float* __restrict__ alS, float* __restrict__ alD,
    int n) {
  __shared__ float Xs[64 * 65];
  int row0 = blockIdx.x * 64;
  for (int t = threadIdx.x; t < 512; t += 256) {
    int r = t >> 3, k8 = t & 7;
    int row = row0 + r;
    uint4 xw = (row < n) ? ((const uint4*)Xb)[(size_t)row * 8 + k8]
                         : uint4{0u, 0u, 0u, 0u};
    float* dst = &Xs[r * 65 + k8 * 8];
    dst[0] = bf_lo(xw.x); dst[1] = bf_hi(xw.x);
    dst[2] = bf_lo(xw.y); dst[3] = bf_hi(xw.y);
    dst[4] = bf_lo(xw.z); dst[5] = bf_hi(xw.z);
    dst[6] = bf_lo(xw.w); dst[7] = bf_hi(xw.w);
  }
  __syncthreads();
  int lane = threadIdx.x & 63;
  int w = __builtin_amdgcn_readfirstlane(threadIdx.x >> 6);
  int c0 = w * 16;
  int row = row0 + lane;
  float acc[16];
#pragma unroll
  for (int c = 0; c < 16; ++c) acc[c] = 0.f;
#pragma unroll 4
  for (int k = 0; k < 64; ++k) {
    float xk = Xs[lane * 65 + k];
#pragma unroll
    for (int c = 0; c < 16; ++c) {
      int gc = c0 + c;
      acc[c] = fmaf(xk, W[(gc >> 3) * 512 + k * 8 + (gc & 7)], acc[c]);
    }
  }
  if (row >= n) return;
  float s1a = 0.f, s2a = 0.f, s1b = 0.f, s2b = 0.f;
#pragma unroll
  for (int cc = 0; cc < 8; ++cc) {
    s1a = fmaf(acc[cc], asrc[c0 + cc], s1a);
    s2a = fmaf(acc[cc], adst[c0 + cc], s2a);
    s1b = fmaf(acc[8 + cc], asrc[c0 + 8 + cc], s1b);
    s2b = fmaf(acc[8 + cc], adst[c0 + 8 + cc], s2b);
  }
  ((float2*)alS)[(size_t)row * 4 + w] = {s1a, s1b};   // alS[row][2w, 2w+1]
  ((float2*)alD)[(size_t)row * 4 + w] = {s2a, s2b};   // alD[row][2w, 2w+1]
  uint4* H4 = (uint4*)Hgb;
  uint4 o0 = {pack_bf16(acc[0], acc[1]), pack_bf16(acc[2], acc[3]),
              pack_bf16(acc[4], acc[5]), pack_bf16(acc[6], acc[7])};
  uint4 o1 = {pack_bf16(acc[8], acc[9]), pack_bf16(acc[10], acc[11]),
              pack_bf16(acc[12], acc[13]), pack_bf16(acc[14], acc[15])};
  H4[(size_t)row * 8 + w * 2] = o0;
  H4[(size_t)row * 8 + w * 2 + 1] = o1;
}

// ------------------------------ aggregations -------------------------------

enum { MODE_RW1 = 0, MODE_RW = 1, MODE_G0 = 2, MODE_GR = 3,
       MODE_GD_X = 4, MODE_GD_R = 5 };

template <int MODE>
__global__ __launch_bounds__(256) void k_agg(
    const int* __restrict__ off, const int* __restrict__ idx,
    const float* __restrict__ Hf, const u32* __restrict__ Hb,
    const float* __restrict__ dis, const float* __restrict__ bias,
    float* __restrict__ R, float* __restrict__ Xf, u32* __restrict__ Xb,
    int n) {
  int lane = threadIdx.x & 63;
  int wid = threadIdx.x >> 6;
  int d0 = blockIdx.x * 8 + wid * 2;
  if (d0 >= n) return;
  int d1 = d0 + 1;
  bool has1 = d1 < n;
  int rg = lane >> 3, cg = lane & 7;
  const uint4* H4b = (const uint4*)Hb;
  const float4* H4f = (const float4*)Hf;
  int beg0 = off[d0], end0 = off[d0 + 1];
  int beg1 = has1 ? off[d1] : 0, end1 = has1 ? off[d1 + 1] : 0;
  int cnt0 = end0 - beg0, cnt1 = end1 - beg1;
  int cmax = cnt0 > cnt1 ? cnt0 : cnt1;
  float acc0[8], acc1[8];
#pragma unroll
  for (int i = 0; i < 8; ++i) { acc0[i] = 0.f; acc1[i] = 0.f; }
  for (int base = 0; base < cmax; base += 64) {
    int c0 = cnt0 - base; if (c0 > 64) c0 = 64;
    int c1 = cnt1 - base; if (c1 > 64) c1 = 64;
    int sidx0 = (lane < c0) ? idx[beg0 + base + lane] : -1;
    int sidx1 = (lane < c1) ? idx[beg1 + base + lane] : -1;
    int hi = c0 > c1 ? c0 : c1;
    int nI = (hi + 7) >> 3;
    int j = 0;
    for (; j + 2 <= nI; j += 2) {
      int s00 = __shfl(sidx0, j * 8 + rg, 64);
      int s01 = __shfl(sidx0, j * 8 + 8 + rg, 64);
      int s10 = __shfl(sidx1, j * 8 + rg, 64);
      int s11 = __shfl(sidx1, j * 8 + 8 + rg, 64);
      size_t a00 = (size_t)(s00 >= 0 ? s00 : 0);
      size_t a01 = (size_t)(s01 >= 0 ? s01 : 0);
      size_t a10 = (size_t)(s10 >= 0 ? s10 : 0);
      size_t a11 = (size_t)(s11 >= 0 ? s11 : 0);
      if (MODE == MODE_RW1) {
        float4 x00 = H4f[a00 * 16 + cg * 2], y00 = H4f[a00 * 16 + cg * 2 + 1];
        float4 x01 = H4f[a01 * 16 + cg * 2], y01 = H4f[a01 * 16 + cg * 2 + 1];
        float4 x10 = H4f[a10 * 16 + cg * 2], y10 = H4f[a10 * 16 + cg * 2 + 1];
        float4 x11 = H4f[a11 * 16 + cg * 2], y11 = H4f[a11 * 16 + cg * 2 + 1];
        if (s00 < 0) { x00 = {0,0,0,0}; y00 = {0,0,0,0}; }
        if (s01 < 0) { x01 = {0,0,0,0}; y01 = {0,0,0,0}; }
        if (s10 < 0) { x10 = {0,0,0,0}; y10 = {0,0,0,0}; }
        if (s11 < 0) { x11 = {0,0,0,0}; y11 = {0,0,0,0}; }
        acc0[0] += x00.x; acc0[1] += x00.y; acc0[2] += x00.z; acc0[3] += x00.w;
        acc0[4] += y00.x; acc0[5] += y00.y; acc0[6] += y00.z; acc0[7] += y00.w;
        acc0[0] += x01.x; acc0[1] += x01.y; acc0[2] += x01.z; acc0[3] += x01.w;
        acc0[4] += y01.x; acc0[5] += y01.y; acc0[6] += y01.z; acc0[7] += y01.w;
        acc1[0] += x10.x; acc1[1] += x10.y; acc1[2] += x10.z; acc1[3] += x10.w;
        acc1[4] += y10.x; acc1[5] += y10.y; acc1[6] += y10.z; acc1[7] += y10.w;
        acc1[0] += x11.x; acc1[1] += x11.y; acc1[2] += x11.z; acc1[3] += x11.w;
        acc1[4] += y11.x; acc1[5] += y11.y; acc1[6] += y11.z; acc1[7] += y11.w;
      } else {
        uint4 q00 = H4b[a00 * 8 + cg];
        uint4 q01 = H4b[a01 * 8 + cg];
        uint4 q10 = H4b[a10 * 8 + cg];
        uint4 q11 = H4b[a11 * 8 + cg];
        if (s00 < 0) q00 = {0u,0u,0u,0u};
        if (s01 < 0) q01 = {0u,0u,0u,0u};
        if (s10 < 0) q10 = {0u,0u,0u,0u};
        if (s11 < 0) q11 = {0u,0u,0u,0u};
        acc8(acc0, q00);
        acc8(acc0, q01);
        acc8(acc1, q10);
        acc8(acc1, q11);
      }
    }
    if (j < nI) {
      int s00 = __shfl(sidx0, j * 8 + rg, 64);
      int s10 = __shfl(sidx1, j * 8 + rg, 64);
      size_t a00 = (size_t)(s00 >= 0 ? s00 : 0);
      size_t a10 = (size_t)(s10 >= 0 ? s10 : 0);
      if (MODE == MODE_RW1) {
        float4 x00 = H4f[a00 * 16 + cg * 2], y00 = H4f[a00 * 16 + cg * 2 + 1];
        float4 x10 = H4f[a10 * 16 + cg * 2], y10 = H4f[a10 * 16 + cg * 2 + 1];
        if (s00 < 0) { x00 = {0,0,0,0}; y00 = {0,0,0,0}; }
        if (s10 < 0) { x10 = {0,0,0,0}; y10 = {0,0,0,0}; }
        acc0[0] += x00.x; acc0[1] += x00.y; acc0[2] += x00.z; acc0[3] += x00.w;
        acc0[4] += y00.x; acc0[5] += y00.y; acc0[6] += y00.z; acc0[7] += y00.w;
        acc1[0] += x10.x; acc1[1] += x10.y; acc1[2] += x10.z; acc1[3] += x10.w;
        acc1[4] += y10.x; acc1[5] += y10.y; acc1[6] += y10.z; acc1[7] += y10.w;
      } else {
        uint4 q00 = H4b[a00 * 8 + cg];
        uint4 q10 = H4b[a10 * 8 + cg];
        if (s00 < 0) q00 = {0u,0u,0u,0u};
        if (s10 < 0) q10 = {0u,0u,0u,0u};
        acc8(acc0, q00);
        acc8(acc1, q10);
      }
    }
  }
#pragma unroll
  for (int m = 8; m < 64; m <<= 1)
#pragma unroll
    for (int i = 0; i < 8; ++i) {
      acc0[i] += __shfl_xor(acc0[i], m, 64);
      acc1[i] += __shfl_xor(acc1[i], m, 64);
    }
  if (rg != 0) return;
#pragma unroll
  for (int nd = 0; nd < 2; ++nd) {
    int d = nd == 0 ? d0 : d1;
    if (nd == 1 && !has1) break;
    float* acc = nd == 0 ? acc0 : acc1;
    if (MODE == MODE_RW1 || MODE == MODE_RW) {
      uint4 o = {pack_bf16(acc[0], acc[1]), pack_bf16(acc[2], acc[3]),
                 pack_bf16(acc[4], acc[5]), pack_bf16(acc[6], acc[7])};
      ((uint4*)Xb)[(size_t)d * 8 + cg] = o;
      continue;
    }
    float ddv = dis[d];
    uint4 hw = H4b[(size_t)d * 8 + cg];
    float hs[8] = {bf_lo(hw.x), bf_hi(hw.x), bf_lo(hw.y), bf_hi(hw.y),
                   bf_lo(hw.z), bf_hi(hw.z), bf_lo(hw.w), bf_hi(hw.w)};
    float4 b0 = ((const float4*)bias)[cg * 2];
    float4 b1 = ((const float4*)bias)[cg * 2 + 1];
    float bv[8] = {b0.x, b0.y, b0.z, b0.w, b1.x, b1.y, b1.z, b1.w};
    float v[8];
#pragma unroll
    for (int i = 0; i < 8; ++i) v[i] = ddv * (acc[i] + hs[i]) + bv[i];
    float4* X4 = (float4*)Xf;
    float4* R4 = (float4*)R;
    size_t o0 = (size_t)d * 16 + cg * 2;
    if (MODE == MODE_GR) {
      float4 r0 = R4[o0], r1 = R4[o0 + 1];
      v[0] += r0.x; v[1] += r0.y; v[2] += r0.z; v[3] += r0.w;
      v[4] += r1.x; v[5] += r1.y; v[6] += r1.z; v[7] += r1.w;
      R4[o0] = {v[0], v[1], v[2], v[3]};
      R4[o0 + 1] = {v[4], v[5], v[6], v[7]};
    } else if (MODE == MODE_GD_X) {
      float4 x0 = X4[o0], x1 = X4[o0 + 1];
      X4[o0] = {x0.x + v[0], x0.y + v[1], x0.z + v[2], x0.w + v[3]};
      X4[o0 + 1] = {x1.x + v[4], x1.y + v[5], x1.z + v[6], x1.w + v[7]};
    } else if (MODE == MODE_GD_R) {
      float4 r0 = R4[o0], r1 = R4[o0 + 1];
      X4[o0] = {fmaxf(r0.x, 0.f) + v[0], fmaxf(r0.y, 0.f) + v[1],
                fmaxf(r0.z, 0.f) + v[2], fmaxf(r0.w, 0.f) + v[3]};
      X4[o0 + 1] = {fmaxf(r1.x, 0.f) + v[4], fmaxf(r1.y, 0.f) + v[5],
                    fmaxf(r1.z, 0.f) + v[6], fmaxf(r1.w, 0.f) + v[7]};
    } else {  // MODE_G0
      X4[o0] = {fmaxf(v[0], 0.f), fmaxf(v[1], 0.f), fmaxf(v[2], 0.f), fmaxf(v[3], 0.f)};
      X4[o0 + 1] = {fmaxf(v[4], 0.f), fmaxf(v[5], 0.f), fmaxf(v[6], 0.f), fmaxf(v[7], 0.f)};
    }
  }
}

// GAT softmax aggregation: ONLINE single-pass softmax; gathers from the
// 3.2MB alS table only (L2-resident); alD read once per destination.
__global__ __launch_bounds__(256) void k_gat_agg(
    const int* __restrict__ off, const int* __restrict__ idx,
    const u32* __restrict__ Hgb, const float* __restrict__ alS,
    const float* __restrict__ alD, const float* __restrict__ bias,
    float* __restrict__ X, float* __restrict__ R, int n) {
  int lane = threadIdx.x & 63;
  int wid = threadIdx.x >> 6;
  int d0 = blockIdx.x * 8 + wid * 2;
  if (d0 >= n) return;
  int d1 = d0 + 1;
  bool has1 = d1 < n;
  int rg = lane >> 3, cg = lane & 7;
  const uint4* H4b = (const uint4*)Hgb;
  float ald0 = alD[(size_t)d0 * 8 + cg];
  float es0 = lrelu(alS[(size_t)d0 * 8 + cg] + ald0);
  float ald1 = has1 ? alD[(size_t)d1 * 8 + cg] : 0.f;
  float es1 = has1 ? lrelu(alS[(size_t)d1 * 8 + cg] + ald1) : 0.f;
  int beg0 = off[d0], end0 = off[d0 + 1];
  int beg1 = has1 ? off[d1] : 0, end1 = has1 ? off[d1 + 1] : 0;
  int cnt0 = end0 - beg0, cnt1 = end1 - beg1;
  int cmax = cnt0 > cnt1 ? cnt0 : cnt1;
  const float NEG = -3.0e38f;
  float m0 = es0, m1 = es1;
  float den0 = 0.f, den1 = 0.f;
  float acc0[8], acc1[8];
#pragma unroll
  for (int i = 0; i < 8; ++i) { acc0[i] = 0.f; acc1[i] = 0.f; }
  for (int base = 0; base < cmax; base += 64) {
    int c0 = cnt0 - base; if (c0 > 64) c0 = 64;
    int c1 = cnt1 - base; if (c1 > 64) c1 = 64;
    int sidx0 = (lane < c0) ? idx[beg0 + base + lane] : -1;
    int sidx1 = (lane < c1) ? idx[beg1 + base + lane] : -1;
    int hi = c0 > c1 ? c0 : c1;
    int nI = (hi + 7) >> 3;
    int j = 0;
    for (; j + 2 <= nI; j += 2) {
      int s00 = __shfl(sidx0, j * 8 + rg, 64);
      int s01 = __shfl(sidx0, j * 8 + 8 + rg, 64);
      int s10 = __shfl(sidx1, j * 8 + rg, 64);
      int s11 = __shfl(sidx1, j * 8 + 8 + rg, 64);
      size_t a00 = (size_t)(s00 >= 0 ? s00 : 0);
      size_t a01 = (size_t)(s01 >= 0 ? s01 : 0);
      size_t a10 = (size_t)(s10 >= 0 ? s10 : 0);
      size_t a11 = (size_t)(s11 >= 0 ? s11 : 0);
      float l00 = alS[a00 * 8 + cg];
      float l01 = alS[a01 * 8 + cg];
      float l10 = alS[a10 * 8 + cg];
      float l11 = alS[a11 * 8 + cg];
      uint4 q00 = H4b[a00 * 8 + cg];
      uint4 q01 = H4b[a01 * 8 + cg];
      uint4 q10 = H4b[a10 * 8 + cg];
      uint4 q11 = H4b[a11 * 8 + cg];
      float e00 = (s00 >= 0) ? lrelu(l00 + ald0) : NEG;
      float e01 = (s01 >= 0) ? lrelu(l01 + ald0) : NEG;
      float e10 = (s10 >= 0) ? lrelu(l10 + ald1) : NEG;
      float e11 = (s11 >= 0) ? lrelu(l11 + ald1) : NEG;
      float ml0 = fmaxf(e00, e01);
      if (ml0 > m0) {
        float sc = __expf(m0 - ml0);
        den0 *= sc;
#pragma unroll
        for (int i = 0; i < 8; ++i) acc0[i] *= sc;
        m0 = ml0;
      }
      float p00 = (s00 >= 0) ? __expf(e00 - m0) : 0.f;
      float p01 = (s01 >= 0) ? __expf(e01 - m0) : 0.f;
      den0 += p00; fma8(acc0, p00, q00);
      den0 += p01; fma8(acc0, p01, q01);
      float ml1 = fmaxf(e10, e11);
      if (ml1 > m1) {
        float sc = __expf(m1 - ml1);
        den1 *= sc;
#pragma unroll
        for (int i = 0; i < 8; ++i) acc1[i] *= sc;
        m1 = ml1;
      }
      float p10 = (s10 >= 0) ? __expf(e10 - m1) : 0.f;
      float p11 = (s11 >= 0) ? __expf(e11 - m1) : 0.f;
      den1 += p10; fma8(acc1, p10, q10);
      den1 += p11; fma8(acc1, p11, q11);
    }
    if (j < nI) {
      int s00 = __shfl(sidx0, j * 8 + rg, 64);
      int s10 = __shfl(sidx1, j * 8 + rg, 64);
      size_t a00 = (size_t)(s00 >= 0 ? s00 : 0);
      size_t a10 = (size_t)(s10 >= 0 ? s10 : 0);
      float l00 = alS[a00 * 8 + cg];
      float l10 = alS[a10 * 8 + cg];
      uint4 q00 = H4b[a00 * 8 + cg];
      uint4 q10 = H4b[a10 * 8 + cg];
      float e00 = (s00 >= 0) ? lrelu(l00 + ald0) : NEG;
      float e10 = (s10 >= 0) ? lrelu(l10 + ald1) : NEG;
      if (e00 > m0) {
        float sc = __expf(m0 - e00);
        den0 *= sc;
#pragma unroll
        for (int i = 0; i < 8; ++i) acc0[i] *= sc;
        m0 = e00;
      }
      float p00 = (s00 >= 0) ? __expf(e00 - m0) : 0.f;
      den0 += p00; fma8(acc0, p00, q00);
      if (e10 > m1) {
        float sc = __expf(m1 - e10);
        den1 *= sc;
#pragma unroll
        for (int i = 0; i < 8; ++i) acc1[i] *= sc;
        m1 = e10;
      }
      float p10 = (s10 >= 0) ? __expf(e10 - m1) : 0.f;
      den1 += p10; fma8(acc1, p10, q10);
    }
  }
#pragma unroll
  for (int mm = 8; mm < 64; mm <<= 1) {
    float mo0 = __shfl_xor(m0, mm, 64);
    float do0 = __shfl_xor(den0, mm, 64);
    float mo1 = __shfl_xor(m1, mm, 64);
    float do1 = __shfl_xor(den1, mm, 64);
    float ao0[8], ao1[8];
#pragma unroll
    for (int i = 0; i < 8; ++i) {
      ao0[i] = __shfl_xor(acc0[i], mm, 64);
      ao1[i] = __shfl_xor(acc1[i], mm, 64);
    }
    float mn0 = fmaxf(m0, mo0);
    float sA0 = __expf(m0 - mn0), sB0 = __expf(mo0 - mn0);
    den0 = den0 * sA0 + do0 * sB0;
#pragma unroll
    for (int i = 0; i < 8; ++i) acc0[i] = acc0[i] * sA0 + ao0[i] * sB0;
    m0 = mn0;
    float mn1 = fmaxf(m1, mo1);
    float sA1 = __expf(m1 - mn1), sB1 = __expf(mo1 - mn1);
    den1 = den1 * sA1 + do1 * sB1;
#pragma unroll
    for (int i = 0; i < 8; ++i) acc1[i] = acc1[i] * sA1 + ao1[i] * sB1;
    m1 = mn1;
  }
  if (rg != 0) return;
#pragma unroll
  for (int nd = 0; nd < 2; ++nd) {
    if (nd == 1 && !has1) break;
    int d = nd == 0 ? d0 : d1;
    float* acc = nd == 0 ? acc0 : acc1;
    float es = nd == 0 ? es0 : es1;
    float m = nd == 0 ? m0 : m1;
    float den = nd == 0 ? den0 : den1;
    float pself = __expf(es - m);
    uint4 hw = H4b[(size_t)d * 8 + cg];
    float hs[8] = {bf_lo(hw.x), bf_hi(hw.x), bf_lo(hw.y), bf_hi(hw.y),
                   bf_lo(hw.z), bf_hi(hw.z), bf_lo(hw.w), bf_hi(hw.w)};
#pragma unroll
    for (int i = 0; i < 8; ++i) acc[i] = fmaf(pself, hs[i], acc[i]);
    den += pself;
    float inv = 1.f / den;
    float4 b0 = ((const float4*)bias)[cg * 2];
    float4 b1 = ((const float4*)bias)[cg * 2 + 1];
    float bv[8] = {b0.x, b0.y, b0.z, b0.w, b1.x, b1.y, b1.z, b1.w};
    float v[8];
#pragma unroll
    for (int i = 0; i < 8; ++i) v[i] = acc[i] * inv + bv[i];
    size_t o0 = (size_t)d * 16 + cg * 2;
    ((float4*)X)[o0] = {v[0], v[1], v[2], v[3]};
    ((float4*)X)[o0 + 1] = {v[4], v[5], v[6], v[7]};
    ((float4*)R)[o0] = {v[0], v[1], v[2], v[3]};
    ((float4*)R)[o0 + 1] = {v[4], v[5], v[6], v[7]};
  }
}

// ------------------------------- final linear ------------------------------

__global__ __launch_bounds__(256) void k_fc(
    const float* __restrict__ Rm, const float* __restrict__ W,
    const float* __restrict__ b, float* __restrict__ out, int n) {
  __shared__ float Wl[640];
  __shared__ float bl[10];
  for (int i = threadIdx.x; i < 640; i += 256) Wl[i] = W[i];
  if (threadIdx.x < 10) bl[threadIdx.x] = b[threadIdx.x];
  __syncthreads();
  int r = blockIdx.x * blockDim.x + threadIdx.x;
  if (r >= n) return;
  float acc[10];
#pragma unroll
  for (int c = 0; c < 10; ++c) acc[c] = bl[c];
#pragma unroll
  for (int k = 0; k < 64; ++k) {
    float xv = fmaxf(Rm[(size_t)r * 64 + k], 0.f);
#pragma unroll
    for (int c = 0; c < 10; ++c) acc[c] = fmaf(xv, Wl[k * 10 + c], acc[c]);
  }
#pragma unroll
  for (int c = 0; c < 10; ++c) out[(size_t)r * 10 + c] = acc[c];
}

// --------------------------------- launch ----------------------------------

extern "C" void kernel_launch(void* const* d_in, const int* in_sizes, int n_in,
                              void* d_out, int out_size, void* d_ws, size_t ws_size,
                              hipStream_t stream) {
  const float* x_in  = (const float*)d_in[0];
  const int*   ei    = (const int*)d_in[1];
  const float* gatW  = (const float*)d_in[2];
  const float* gatAs = (const float*)d_in[3];
  const float* gatAd = (const float*)d_in[4];
  const float* gatB  = (const float*)d_in[5];
  const float* gcnW  = (const float*)d_in[6];
  const float* gcnB  = (const float*)d_in[7];
  const float* fcW   = (const float*)d_in[8];
  const float* fcB   = (const float*)d_in[9];
  float* out = (float*)d_out;

  const int N = in_sizes[0] / 64;
  const int E = in_sizes[1] / 2;
  const int NB = (N + RNGB - 1) >> BSH;
  const int chunk = (E + GEB - 1) / GEB;

  char* ws = (char*)d_ws;
  size_t o = 0;
  auto alloc = [&](size_t bytes) -> char* {
    char* p = ws + o;
    o = (o + bytes + 255) & ~(size_t)255;
    return p;
  };
  int* offA    = (int*)alloc((size_t)(N + 1) * 4);
  int* offB    = (int*)alloc((size_t)(N + 1) * 4);
  float* dis   = (float*)alloc((size_t)N * 4);
  int* idxA    = (int*)alloc((size_t)E * 4);
  int* idxB    = (int*)alloc((size_t)E * 4);
  int2* pairsA = (int2*)alloc((size_t)E * 8);
  int2* pairsB = (int2*)alloc((size_t)E * 8);
  int* gHistA  = (int*)alloc((size_t)GEB * NB * 4);
  int* gHistB  = (int*)alloc((size_t)GEB * NB * 4);
  int* totA    = (int*)alloc((size_t)NB * 4);
  int* totB    = (int*)alloc((size_t)NB * 4);
  int* baseA   = (int*)alloc((size_t)NB * 4);
  int* baseB   = (int*)alloc((size_t)NB * 4);
  float* alS   = (float*)alloc((size_t)N * 8 * 4);
  float* alD   = (float*)alloc((size_t)N * 8 * 4);
  u32* B0      = (u32*)alloc((size_t)N * 32 * 4);
  u32* B1      = (u32*)alloc((size_t)N * 32 * 4);
  float* X     = (float*)alloc((size_t)N * 64 * 4);
  float* R     = (float*)alloc((size_t)N * 64 * 4);

  int nbN = (N + 255) / 256;
  int nbAgg = (N + 7) / 8;
  int nbG = (N + 63) / 64;

  // ---- CSR build: bucketed counting sort (merged A/B launches) ----
  k_hist<<<GEB, 256, 0, stream>>>(ei, E, NB, chunk, gHistA, gHistB);
  k_colscan<<<2 * NB, GEB, 0, stream>>>(gHistA, totA, gHistB, totB, NB);
  k_bscan<<<1, 1024, 0, stream>>>(totA, totB, baseA, baseB, offA, offB, NB, N, E);
  k_scatter<<<GEB, 256, 0, stream>>>(ei, E, NB, chunk, gHistA, gHistB,
                                     baseA, baseB, pairsA, pairsB);
  k_bucket<<<2 * NB, 256, 0, stream>>>(pairsA, pairsB, baseA, baseB, totA, totB,
                                       offA, offB, idxA, idxB, dis, N, NB);

  // ---- random walk: 5 steps (fp32 in -> bf16 ping-pong) ----
  k_agg<MODE_RW1><<<nbAgg, 256, 0, stream>>>(offA, idxA, x_in, nullptr, nullptr, nullptr, nullptr, nullptr, B0, N);
  k_agg<MODE_RW><<<nbAgg, 256, 0, stream>>>(offA, idxA, nullptr, B0, nullptr, nullptr, nullptr, nullptr, B1, N);
  k_agg<MODE_RW><<<nbAgg, 256, 0, stream>>>(offA, idxA, nullptr, B1, nullptr, nullptr, nullptr, nullptr, B0, N);
  k_agg<MODE_RW><<<nbAgg, 256, 0, stream>>>(offA, idxA, nullptr, B0, nullptr, nullptr, nullptr, nullptr, B1, N);
  k_agg<MODE_RW><<<nbAgg, 256, 0, stream>>>(offA, idxA, nullptr, B1, nullptr, nullptr, nullptr, nullptr, B0, N);

  // ---- GAT ----
  k_gat_gemm<<<nbG, 256, 0, stream>>>(B0, gatW, gatAs, gatAd, B1, alS, alD, N);
  k_gat_agg<<<nbAgg, 256, 0, stream>>>(offB, idxB, B1, alS, alD, gatB, X, R, N);

  // ---- residual GCN ----
  for (int i = 0; i < 12; ++i) {
    if (i == 0) {
      k_gemm64<0><<<nbG, 256, 0, stream>>>(X, gcnW, dis, B0, N);
      k_agg<MODE_G0><<<nbAgg, 256, 0, stream>>>(offB, idxB, nullptr, B0, dis, gcnB, nullptr, X, nullptr, N);
    } else {
      k_gemm64<0><<<nbG, 256, 0, stream>>>(X, gcnW + i * 4096, dis, B0, N);
      k_agg<MODE_GR><<<nbAgg, 256, 0, stream>>>(offB, idxB, nullptr, B0, dis, gcnB + i * 64, R, nullptr, nullptr, N);
    }
    if (i < 11) {
      int j = (i == 0) ? 11 : i - 1;
      if (i == 0) {
        k_gemm64<0><<<nbG, 256, 0, stream>>>(X, gcnW + j * 4096, dis, B0, N);
        k_agg<MODE_GD_X><<<nbAgg, 256, 0, stream>>>(offB, idxB, nullptr, B0, dis, gcnB + j * 64, nullptr, X, nullptr, N);
      } else {
        k_gemm64<1><<<nbG, 256, 0, stream>>>(R, gcnW + j * 4096, dis, B0, N);
        k_agg<MODE_GD_R><<<nbAgg, 256, 0, stream>>>(offB, idxB, nullptr, B0, dis, gcnB + j * 64, R, X, nullptr, N);
      }
    }
  }

  // ---- final linear: x = relu(R_final) ----
  k_fc<<<nbN, 256, 0, stream>>>(R, fcW, fcB, out, N);
}